// Round 16
// baseline (324.684 us; speedup 1.0000x reference)
//
#include <hip/hip_runtime.h>
#include <math.h>

// Problem constants
static constexpr int B  = 2;
static constexpr int S  = 512;
static constexpr int D  = 256;
static constexpr int N  = 16;
static constexpr int DI = 512;
static constexpr int CHUNK = 32;
static constexpr int NCHUNK = S / CHUNK;   // 16
static constexpr int DN = DI * N;          // 8192

typedef unsigned int uint32;
typedef unsigned short ushort16;
using bf16x8 = __attribute__((ext_vector_type(8))) short;
using f32x4  = __attribute__((ext_vector_type(4))) float;

__device__ __forceinline__ ushort16 f2bf(float f) {
    uint32 u = __float_as_uint(f);
    u = (u + 0x7fffu + ((u >> 16) & 1u)) >> 16;   // RNE
    return (ushort16)u;
}
__device__ __forceinline__ float bflo(uint32 u) { return __uint_as_float(u << 16); }
__device__ __forceinline__ float bfhi(uint32 u) { return __uint_as_float(u & 0xffff0000u); }
__device__ __forceinline__ float bf2f(ushort16 u) { return __uint_as_float(((uint32)u) << 16); }
__device__ __forceinline__ uint32 pk2(float a, float b) {
    return (uint32)(ushort16)f2bf(a) | ((uint32)(ushort16)f2bf(b) << 16);
}
// DPP row-rotate within 16-lane rows (VALU pipe, no LDS)
template<int K>
__device__ __forceinline__ float rork(float x) {
    return __uint_as_float((uint32)__builtin_amdgcn_mov_dpp(
        (int)__float_as_uint(x), 0x120 + K, 0xf, 0xf, false));
}
// histT tiled layout: elem (b, dn, s) -> ((b*(S/32) + s/32)*DN + dn)*32 + s%32
__device__ __forceinline__ size_t htIdx(int b, int dn, int sb) {
    return ((size_t)(b * (S / 32) + sb) * DN + dn) * 32;
}

// ---------------- LayerNorm: one wave per row, bf16 output ----------------
__global__ void ln_k(const float* __restrict__ x, const float* __restrict__ w,
                     const float* __restrict__ bias, ushort16* __restrict__ xnb) {
    int row = blockIdx.x;
    int lane = threadIdx.x;
    float4 v = *(const float4*)(x + row * D + lane * 4);
    float s = v.x + v.y + v.z + v.w;
    float q = v.x * v.x + v.y * v.y + v.z * v.z + v.w * v.w;
    for (int m = 1; m < 64; m <<= 1) { s += __shfl_xor(s, m); q += __shfl_xor(q, m); }
    float mu  = s * (1.0f / D);
    float var = q * (1.0f / D) - mu * mu;
    float rs  = rsqrtf(var + 1e-5f);
    float4 wv = *(const float4*)(w + lane * 4);
    float4 bv = *(const float4*)(bias + lane * 4);
    float4 o;
    o.x = (v.x - mu) * rs * wv.x + bv.x;
    o.y = (v.y - mu) * rs * wv.y + bv.y;
    o.z = (v.z - mu) * rs * wv.z + bv.z;
    o.w = (v.w - mu) * rs * wv.w + bv.w;
    uint2 pk;
    pk.x = pk2(o.x, o.y);
    pk.y = pk2(o.z, o.w);
    *(uint2*)(xnb + row * D + lane * 4) = pk;
}

// ------- bf16 MFMA GEMM, W in f32 (converted during staging) -------
template<int MODE>
__global__ __launch_bounds__(256) void gemmb_k(const ushort16* __restrict__ A,
                                               const float* __restrict__ W,
                                               const float* __restrict__ res,
                                               float* __restrict__ C,
                                               ushort16* __restrict__ xpb,
                                               float* __restrict__ zs,
                                               int M, int Nc, int K) {
    __shared__ __align__(16) short As[64 * 40];
    __shared__ __align__(16) short Ws[64 * 40];
    int tid = threadIdx.x;
    int l = tid & 63, wid = tid >> 6;
    int wm = wid & 1, wn = wid >> 1;
    int row0 = blockIdx.y * 64, col0 = blockIdx.x * 64;
    int r = tid >> 2, kseg = (tid & 3) * 8;
    f32x4 acc[2][2] = {};
    for (int k0 = 0; k0 < K; k0 += 32) {
        *(uint4*)&As[r * 40 + kseg] = *(const uint4*)(A + (size_t)(row0 + r) * K + k0 + kseg);
        {
            const float* wrow = W + (size_t)(col0 + r) * K + k0 + kseg;
            float4 w0 = *(const float4*)wrow;
            float4 w1 = *(const float4*)(wrow + 4);
            uint4 q;
            q.x = pk2(w0.x, w0.y); q.y = pk2(w0.z, w0.w);
            q.z = pk2(w1.x, w1.y); q.w = pk2(w1.z, w1.w);
            *(uint4*)&Ws[r * 40 + kseg] = q;
        }
        __syncthreads();
        bf16x8 aF[2], bF[2];
        #pragma unroll
        for (int am = 0; am < 2; ++am)
            aF[am] = *(const bf16x8*)&As[(wm * 32 + am * 16 + (l & 15)) * 40 + (l >> 4) * 8];
        #pragma unroll
        for (int bn = 0; bn < 2; ++bn)
            bF[bn] = *(const bf16x8*)&Ws[(wn * 32 + bn * 16 + (l & 15)) * 40 + (l >> 4) * 8];
        #pragma unroll
        for (int am = 0; am < 2; ++am)
            #pragma unroll
            for (int bn = 0; bn < 2; ++bn)
                acc[am][bn] = __builtin_amdgcn_mfma_f32_16x16x32_bf16(aF[am], bF[bn], acc[am][bn], 0, 0, 0);
        __syncthreads();
    }
    #pragma unroll
    for (int am = 0; am < 2; ++am)
        #pragma unroll
        for (int bn = 0; bn < 2; ++bn) {
            int cc = col0 + wn * 32 + bn * 16 + (l & 15);
            #pragma unroll
            for (int reg = 0; reg < 4; ++reg) {
                int rr = row0 + wm * 32 + am * 16 + (l >> 4) * 4 + reg;
                float v = acc[am][bn][reg];
                if (MODE == 0) {
                    if (res) v += res[(size_t)rr * Nc + cc];
                    C[(size_t)rr * Nc + cc] = v;
                } else {
                    int b = rr >> 9, t = rr & (S - 1);
                    if (cc < DI)
                        xpb[((size_t)(b * (S + 3) + 3 + t)) * DI + cc] = f2bf(v);
                    else
                        zs[((size_t)(b * S + t)) * DI + (cc - DI)] = v / (1.0f + __expf(-v));
                }
            }
        }
}

// ---------------- Causal conv via bf16 MFMA + bias + silu ----------------
__global__ __launch_bounds__(256) void convm_k(const ushort16* __restrict__ xpb,
                                               const float* __restrict__ conv_w,
                                               const float* __restrict__ conv_b,
                                               float* __restrict__ x_act) {
    __shared__ __align__(16) short AxS[35 * 40];
    __shared__ __align__(16) short WbS[4 * 32 * 40];
    int tid = threadIdx.x;
    int l = tid & 63, wid = tid >> 6;
    int wm = wid & 1, wn = wid >> 1;
    int o0 = blockIdx.x * 32;
    int mt = blockIdx.y;
    int b = mt >> 4, tl0 = (mt & 15) * 32;
    f32x4 acc = {0.f, 0.f, 0.f, 0.f};

    for (int k0 = 0; k0 < DI; k0 += 32) {
        if (tid < 140) {
            int rr = tid >> 2, seg = tid & 3;
            uint4 v = *(const uint4*)(xpb + ((size_t)(b * (S + 3) + tl0 + rr)) * DI + k0 + seg * 8);
            *(uint4*)&AxS[rr * 40 + seg * 8] = v;
        }
        #pragma unroll
        for (int it = 0; it < 4; ++it) {
            int p = it * 256 + tid;
            int o = p >> 5, i = p & 31;
            float4 w4 = *(const float4*)(conv_w + ((size_t)(o0 + o) * DI + (k0 + i)) * 4);
            WbS[(0 * 32 + o) * 40 + i] = (short)f2bf(w4.x);
            WbS[(1 * 32 + o) * 40 + i] = (short)f2bf(w4.y);
            WbS[(2 * 32 + o) * 40 + i] = (short)f2bf(w4.z);
            WbS[(3 * 32 + o) * 40 + i] = (short)f2bf(w4.w);
        }
        __syncthreads();
        #pragma unroll
        for (int k = 0; k < 4; ++k) {
            bf16x8 aF = *(const bf16x8*)&AxS[(wm * 16 + (l & 15) + k) * 40 + (l >> 4) * 8];
            bf16x8 bF = *(const bf16x8*)&WbS[(k * 32 + wn * 16 + (l & 15)) * 40 + (l >> 4) * 8];
            acc = __builtin_amdgcn_mfma_f32_16x16x32_bf16(aF, bF, acc, 0, 0, 0);
        }
        __syncthreads();
    }
    int oc = o0 + wn * 16 + (l & 15);
    float bia = conv_b[oc];
    #pragma unroll
    for (int reg = 0; reg < 4; ++reg) {
        int m = wm * 16 + (l >> 4) * 4 + reg;
        float v = acc[reg] + bia;
        x_act[((size_t)(b * S + tl0 + m)) * DI + oc] = v / (1.0f + __expf(-v));
    }
}

// ------- ssm (33 outputs) + E epilogue -------
__global__ void ssmE_k(const float* __restrict__ x_act, const float* __restrict__ W_xp,
                       const float* __restrict__ W_dt, const float* __restrict__ b_dt,
                       float* __restrict__ Bm, float* __restrict__ Cm,
                       float* __restrict__ E) {
    int row = blockIdx.x * 4 + (threadIdx.x >> 6);
    int lane = threadIdx.x & 63;
    const float* xr = x_act + (size_t)row * DI + lane * 8;
    float4 v0 = *(const float4*)xr;
    float4 v1 = *(const float4*)(xr + 4);
    float dtr = 0.0f;
    for (int j = 0; j < 2 * N + 1; ++j) {
        const float* wr = W_xp + (size_t)j * DI + lane * 8;
        float4 w0 = *(const float4*)wr;
        float4 w1 = *(const float4*)(wr + 4);
        float acc = v0.x * w0.x + v0.y * w0.y + v0.z * w0.z + v0.w * w0.w
                  + v1.x * w1.x + v1.y * w1.y + v1.z * w1.z + v1.w * w1.w;
        for (int m = 1; m < 64; m <<= 1) acc += __shfl_xor(acc, m);
        if (j == 0) dtr = acc;
        if (lane == 0) {
            if (j >= 1 && j < 1 + N) Bm[(size_t)row * N + (j - 1)] = acc;
            else if (j >= 1 + N)     Cm[(size_t)row * N + (j - 1 - N)] = acc;
        }
    }
    int d0 = lane * 8;
    float4 w0 = *(const float4*)(W_dt + d0);
    float4 w1 = *(const float4*)(W_dt + d0 + 4);
    float4 q0 = *(const float4*)(b_dt + d0);
    float4 q1 = *(const float4*)(b_dt + d0 + 4);
    float4 e0, e1;
    e0.x = 1.0f / (1.0f + __expf(dtr * w0.x + q0.x));
    e0.y = 1.0f / (1.0f + __expf(dtr * w0.y + q0.y));
    e0.z = 1.0f / (1.0f + __expf(dtr * w0.z + q0.z));
    e0.w = 1.0f / (1.0f + __expf(dtr * w0.w + q0.w));
    e1.x = 1.0f / (1.0f + __expf(dtr * w1.x + q1.x));
    e1.y = 1.0f / (1.0f + __expf(dtr * w1.y + q1.y));
    e1.z = 1.0f / (1.0f + __expf(dtr * w1.z + q1.z));
    e1.w = 1.0f / (1.0f + __expf(dtr * w1.w + q1.w));
    *(float4*)(E + (size_t)row * DI + d0) = e0;
    *(float4*)(E + (size_t)row * DI + d0 + 4) = e1;
}

// ---------------- rdeg = 1/max(sum_{s<t} adj,1); flag[t] ----------------
__global__ void deg_k(const float* __restrict__ adj, float* __restrict__ rdeg, int* __restrict__ flagI) {
    int t = blockIdx.x & (S - 1), b = blockIdx.x >> 9;
    int lane = threadIdx.x;
    const float* row = adj + ((size_t)(b * S + t)) * S;
    float s = 0.0f; bool anyp = false;
    for (int i = lane; i < t; i += 64) { float v = row[i]; s += v; anyp |= (v > 0.0f); }
    for (int m = 1; m < 64; m <<= 1) s += __shfl_xor(s, m);
    bool any = __any(anyp);
    if (lane == 0) {
        rdeg[b * S + t] = 1.0f / fmaxf(s, 1.0f);
        if (t > 0 && any) atomicOr(flagI + t, 1);
    }
}

// ================= single-launch full scan (128 blocks x 256 threads) =================
// Block owns (b, 128-dn slice). No cross-block dependencies: the G-recurrence is
// elementwise in dn; Wr-mix couples only the 16 n lanes within one (b,d).
#define SCAN32(RO, ADJT, GSUM)                                              \
    _Pragma("unroll")                                                       \
    for (int j = 0; j < CHUNK; ++j) {                                       \
        float e  = eL [((RO) + j) * 8 + grp];                               \
        float xa = xaL[((RO) + j) * 8 + grp];                               \
        float Bn = BnL[((RO) + j) * 16 + n];                                \
        h = h * e + xa * Bn;                                                \
        float g0 = GSUM[j], g1 = 0.f, g2 = 0.f, g3 = 0.f;                   \
        const float* ar = (ADJT) + j * 36;                                  \
        int sp = 0;                                                         \
        _Pragma("unroll")                                                   \
        for (; sp + 4 <= j; sp += 4) {                                      \
            float4 av = *(const float4*)(ar + sp);                          \
            g0 += av.x * hreg[sp];     g1 += av.y * hreg[sp + 1];           \
            g2 += av.z * hreg[sp + 2]; g3 += av.w * hreg[sp + 3];           \
        }                                                                   \
        _Pragma("unroll")                                                   \
        for (; sp < j; ++sp) g0 += ar[sp] * hreg[sp];                       \
        float gr = (g0 + g1) + (g2 + g3);                                   \
        float m0 = gr * wrr[0] + rork<4>(gr) * wrr[4]                       \
                 + rork<8>(gr) * wrr[8] + rork<12>(gr) * wrr[12];           \
        float m1 = rork<1>(gr) * wrr[1] + rork<5>(gr) * wrr[5]              \
                 + rork<9>(gr) * wrr[9] + rork<13>(gr) * wrr[13];           \
        float m2 = rork<2>(gr) * wrr[2] + rork<6>(gr) * wrr[6]              \
                 + rork<10>(gr) * wrr[10] + rork<14>(gr) * wrr[14];         \
        float m3 = rork<3>(gr) * wrr[3] + rork<7>(gr) * wrr[7]              \
                 + rork<11>(gr) * wrr[11] + rork<15>(gr) * wrr[15];         \
        float acc = fmaf(rdegL[(RO) + j], (m0 + m1) + (m2 + m3), brn);      \
        if (flL[(RO) + j])                                                  \
            h = fmaf(0.1f * acc,                                            \
                     __builtin_amdgcn_rcpf(1.0f + __expf(-acc)), h);        \
        hreg[j] = h;                                                        \
    }

// hist write: global tiled (+ optional LDS hT buffer)
#define HWRITE(CIDX, HTBUF) {                                               \
    ushort16* ht = histT + htIdx(b, dn, (CIDX));                            \
    _Pragma("unroll")                                                       \
    for (int qi = 0; qi < 4; ++qi) {                                        \
        uint4 q;                                                            \
        q.x = pk2(hreg[qi*8+0], hreg[qi*8+1]);                              \
        q.y = pk2(hreg[qi*8+2], hreg[qi*8+3]);                              \
        q.z = pk2(hreg[qi*8+4], hreg[qi*8+5]);                              \
        q.w = pk2(hreg[qi*8+6], hreg[qi*8+7]);                              \
        *(uint4*)(ht + qi * 8) = q;                                         \
        if (HTBUF) *(uint4*)&((short*)(HTBUF))[qi * 1024 + tid * 8] = q;    \
    } }

// mid phase: Gmid[j][col] = sum_{sidx<TCL} adj[tgt rows][src cols] x hT_src (tid<128)
#define MIDPHASE(TCL) {                                                     \
    int w = tid >> 6, l = tid & 63;                                         \
    int ksg = (l >> 4) * 8;                                                 \
    f32x4 ac0[4] = {}, ac1[4] = {};                                         \
    _Pragma("unroll")                                                       \
    for (int sidx = 0; sidx < (TCL); ++sidx) {                              \
        const float* p0 = adj + ((size_t)(b * S + c0s + (TCL) * 32 + (l & 15))) * S \
                        + c0s + sidx * 32 + ksg;                            \
        const float* p1 = p0 + 16 * S;                                      \
        float4 a00 = *(const float4*)p0, a01 = *(const float4*)(p0 + 4);    \
        float4 a10 = *(const float4*)p1, a11 = *(const float4*)(p1 + 4);    \
        uint4 qa, qb;                                                       \
        qa.x = pk2(a00.x, a00.y); qa.y = pk2(a00.z, a00.w);                 \
        qa.z = pk2(a01.x, a01.y); qa.w = pk2(a01.z, a01.w);                 \
        qb.x = pk2(a10.x, a10.y); qb.y = pk2(a10.z, a10.w);                 \
        qb.z = pk2(a11.x, a11.y); qb.w = pk2(a11.z, a11.w);                 \
        bf16x8 aF0, aF1;                                                    \
        *(uint4*)&aF0 = qa; *(uint4*)&aF1 = qb;                             \
        const short* hTs = hTarr[sidx];                                     \
        _Pragma("unroll")                                                   \
        for (int dblk = 0; dblk < 4; ++dblk) {                              \
            int col = w * 64 + dblk * 16 + (l & 15);                        \
            bf16x8 bF = *(const bf16x8*)&hTs[(l >> 4) * 1024 + col * 8];    \
            ac0[dblk] = __builtin_amdgcn_mfma_f32_16x16x32_bf16(aF0, bF, ac0[dblk], 0, 0, 0); \
            ac1[dblk] = __builtin_amdgcn_mfma_f32_16x16x32_bf16(aF1, bF, ac1[dblk], 0, 0, 0); \
        }                                                                   \
    }                                                                       \
    int jb0 = (l >> 4) * 4;                                                 \
    _Pragma("unroll")                                                       \
    for (int dblk = 0; dblk < 4; ++dblk) {                                  \
        int col = w * 64 + dblk * 16 + (l & 15);                            \
        _Pragma("unroll")                                                   \
        for (int reg = 0; reg < 4; ++reg) {                                 \
            Gmid[(jb0 + reg) * 136 + col]      = (short)f2bf(ac0[dblk][reg]); \
            Gmid[(16 + jb0 + reg) * 136 + col] = (short)f2bf(ac1[dblk][reg]); \
        }                                                                   \
    } }

#define GSADD(GSUM)                                                         \
    _Pragma("unroll")                                                       \
    for (int j = 0; j < CHUNK; ++j)                                         \
        GSUM[j] += bf2f((ushort16)Gmid[j * 136 + tid]);

// staging: triangles + operands for 2 chunks starting at row c0s+OFS (all 256)
#define STAGE(OFS) {                                                        \
    int j = tid >> 3, s4 = (tid & 7) * 4;                                   \
    {                                                                       \
        float4 a0 = *(const float4*)(adj + ((size_t)(b * S + c0s + (OFS) + j)) * S + c0s + (OFS) + s4); \
        float* dp = triA + j * 36 + s4;                                     \
        dp[0] = a0.x; dp[1] = a0.y; dp[2] = a0.z; dp[3] = a0.w;             \
    }                                                                       \
    {                                                                       \
        float4 a0 = *(const float4*)(adj + ((size_t)(b * S + c0s + (OFS) + 32 + j)) * S + c0s + (OFS) + 32 + s4); \
        float* dp = triB + j * 36 + s4;                                     \
        dp[0] = a0.x; dp[1] = a0.y; dp[2] = a0.z; dp[3] = a0.w;             \
    }                                                                       \
    int jr = tid >> 2, dd = (tid & 3) * 2;                                  \
    float2 ev = *(const float2*)(E     + ((size_t)(b * S + c0s + (OFS) + jr)) * DI + d0 + dd); \
    float2 xv = *(const float2*)(x_act + ((size_t)(b * S + c0s + (OFS) + jr)) * DI + d0 + dd); \
    eL [jr * 8 + dd] = ev.x; eL [jr * 8 + dd + 1] = ev.y;                   \
    xaL[jr * 8 + dd] = xv.x; xaL[jr * 8 + dd + 1] = xv.y;                   \
    int nn = (tid & 3) * 4;                                                 \
    float4 bv = *(const float4*)(Bm + ((size_t)(b * S + c0s + (OFS) + jr)) * N + nn); \
    BnL[jr * 16 + nn] = bv.x; BnL[jr * 16 + nn + 1] = bv.y;                 \
    BnL[jr * 16 + nn + 2] = bv.z; BnL[jr * 16 + nn + 3] = bv.w;             \
    if (tid < 64) {                                                         \
        rdegL[tid] = rdeg[b * S + c0s + (OFS) + tid];                       \
        flL[tid]   = flagI[c0s + (OFS) + tid];                              \
    } }

// gold for two targets over past chunks 0..KS1-1, streamed from global histT.
// All 256 threads. Results left in acA/acB register arrays.
#define GOLD2(TCA, TCB, KS1, ACA, ACB) {                                    \
    int w = tid >> 6, l = tid & 63;                                         \
    int jh = w >> 1, dh = w & 1;                                            \
    int ksg = (l >> 4) * 8;                                                 \
    const float* aA = adj + ((size_t)(b * S + (TCA) * CHUNK + jh * 16 + (l & 15))) * S + ksg; \
    const float* aB2 = adj + ((size_t)(b * S + (TCB) * CHUNK + jh * 16 + (l & 15))) * S + ksg; \
    _Pragma("unroll 2")                                                     \
    for (int ks = 0; ks < (KS1); ++ks) {                                    \
        uint4 bP[4];                                                        \
        _Pragma("unroll")                                                   \
        for (int dblk = 0; dblk < 4; ++dblk)                                \
            bP[dblk] = *(const uint4*)(histT + htIdx(b, dnbase + dh * 64 + dblk * 16 + (l & 15), ks) + ksg); \
        float4 fa0 = *(const float4*)(aA + ks * 32);                        \
        float4 fa1 = *(const float4*)(aA + ks * 32 + 4);                    \
        float4 fb0 = *(const float4*)(aB2 + ks * 32);                       \
        float4 fb1 = *(const float4*)(aB2 + ks * 32 + 4);                   \
        uint4 qa, qb;                                                       \
        qa.x = pk2(fa0.x, fa0.y); qa.y = pk2(fa0.z, fa0.w);                 \
        qa.z = pk2(fa1.x, fa1.y); qa.w = pk2(fa1.z, fa1.w);                 \
        qb.x = pk2(fb0.x, fb0.y); qb.y = pk2(fb0.z, fb0.w);                 \
        qb.z = pk2(fb1.x, fb1.y); qb.w = pk2(fb1.z, fb1.w);                 \
        bf16x8 aFA, aFB;                                                    \
        *(uint4*)&aFA = qa; *(uint4*)&aFB = qb;                             \
        _Pragma("unroll")                                                   \
        for (int dblk = 0; dblk < 4; ++dblk) {                              \
            bf16x8 bF;                                                      \
            *(uint4*)&bF = bP[dblk];                                        \
            ACA[dblk] = __builtin_amdgcn_mfma_f32_16x16x32_bf16(aFA, bF, ACA[dblk], 0, 0, 0); \
            ACB[dblk] = __builtin_amdgcn_mfma_f32_16x16x32_bf16(aFB, bF, ACB[dblk], 0, 0, 0); \
        }                                                                   \
    } }

// write one gold accumulator set to Gmid (all 256 threads)
#define GOLDWR(AC) {                                                        \
    int w = tid >> 6, l = tid & 63;                                         \
    int jh = w >> 1, dh = w & 1;                                            \
    int jb0 = jh * 16 + (l >> 4) * 4;                                       \
    _Pragma("unroll")                                                       \
    for (int dblk = 0; dblk < 4; ++dblk) {                                  \
        int col = dh * 64 + dblk * 16 + (l & 15);                           \
        _Pragma("unroll")                                                   \
        for (int reg = 0; reg < 4; ++reg)                                   \
            Gmid[(jb0 + reg) * 136 + col] = (short)f2bf(AC[dblk][reg]);     \
    } }

__global__ __launch_bounds__(256) void chunkall_k(const float* __restrict__ adj,
                                                  const float* __restrict__ x_act,
                                                  const float* __restrict__ E,
                                                  const float* __restrict__ Bm,
                                                  const float* __restrict__ rdeg,
                                                  const int* __restrict__ flagI,
                                                  const float* __restrict__ Wr,
                                                  const float* __restrict__ br,
                                                  ushort16* __restrict__ histT) {
    __shared__ __align__(16) char smem[51200];
    float* triA  = (float*)smem;                  // 4608
    float* triB  = (float*)(smem + 4608);         // 4608
    float* eL    = (float*)(smem + 9216);         // [64][8]
    float* xaL   = (float*)(smem + 11264);
    float* BnL   = (float*)(smem + 13312);        // [64][16]
    float* rdegL = (float*)(smem + 17408);        // [64]
    int*   flL   = (int*)  (smem + 17664);        // [64]
    short* hTA   = (short*)(smem + 17920);        // [4][128][8] bf16
    short* hTB   = (short*)(smem + 26112);
    short* hTC   = (short*)(smem + 34304);
    short* Gmid  = (short*)(smem + 42496);        // [32][136] bf16

    int tid = threadIdx.x;
    int b = blockIdx.x >> 6;
    int slice = blockIdx.x & 63;
    int d0 = slice << 3;
    int dnbase = slice << 7;
    int n = tid & 15, grp = (tid >> 4) & 7;
    int d = d0 + grp;
    int dn = d * N + n;
    const short* hTarr[3] = {hTA, hTB, hTC};

    float wrr[16];
    float brn = 0.f, h = 0.f;
    float gs0[CHUNK], gs1[CHUNK];
    float hreg[CHUNK];
    if (tid < 128) {
        int probe = __builtin_amdgcn_mov_dpp((int)n, 0x121, 0xf, 0xf, false);
        bool plusdir = (probe == ((n + 1) & 15));
        #pragma unroll
        for (int k = 0; k < 16; ++k) {
            int ip = (n + k) & 15, im = (n - k + 16) & 15;
            wrr[k] = Wr[n * 16 + (plusdir ? ip : im)];
        }
        brn = br[n];
    }

    #pragma unroll 1
    for (int g = 0; g < 4; ++g) {
        int c0 = 4 * g;
        int c0s = c0 * CHUNK;

        // ---- first pair (chunks c0, c0+1) ----
        STAGE(0)
        __syncthreads();
        if (tid < 128) {
            #pragma unroll
            for (int j = 0; j < CHUNK; ++j) { gs0[j] = 0.f; gs1[j] = 0.f; }
        }
        if (g > 0) {
            f32x4 acA[4] = {}, acB[4] = {};
            GOLD2(c0, c0 + 1, 4 * g, acA, acB)
            GOLDWR(acA)
            __syncthreads();
            if (tid < 128) GSADD(gs0)
            __syncthreads();
            GOLDWR(acB)
            __syncthreads();
            if (tid < 128) GSADD(gs1)
        }
        if (tid < 128) {
            SCAN32(0, triA, gs0)
            HWRITE(c0, hTA)
        }
        __syncthreads();
        if (tid < 128) MIDPHASE(1)
        __syncthreads();
        if (tid < 128) {
            GSADD(gs1)
            SCAN32(32, triB, gs1)
            HWRITE(c0 + 1, hTB)
        }
        __syncthreads();

        // ---- second pair (chunks c0+2, c0+3) ----
        STAGE(64)
        __syncthreads();
        if (tid < 128) {
            #pragma unroll
            for (int j = 0; j < CHUNK; ++j) { gs0[j] = 0.f; gs1[j] = 0.f; }
        }
        if (g > 0) {
            f32x4 acA[4] = {}, acB[4] = {};
            GOLD2(c0 + 2, c0 + 3, 4 * g, acA, acB)
            GOLDWR(acA)
            __syncthreads();
            if (tid < 128) GSADD(gs0)
            __syncthreads();
            GOLDWR(acB)
            __syncthreads();
            if (tid < 128) GSADD(gs1)
        }
        __syncthreads();
        if (tid < 128) MIDPHASE(2)        // C <- {A,B}
        __syncthreads();
        if (tid < 128) {
            GSADD(gs0)
            SCAN32(0, triA, gs0)
            HWRITE(c0 + 2, hTC)
        }
        __syncthreads();
        if (tid < 128) MIDPHASE(3)        // D <- {A,B,C}
        __syncthreads();
        if (tid < 128) {
            GSADD(gs1)
            SCAN32(32, triB, gs1)
            HWRITE(c0 + 3, (short*)nullptr)
        }
        __syncthreads();
    }
}

// ---------------- y_k: y[b,t,d] = (sum_n histT[b][dn][t]*Cm[b,t,n]) * zs[b,t,d] -------
__global__ __launch_bounds__(256) void y_k(const ushort16* __restrict__ histT,
                                           const float* __restrict__ Cm,
                                           const float* __restrict__ zs,
                                           ushort16* __restrict__ yzb) {
    __shared__ float CmL[S * 17];
    int b = blockIdx.x >> 9;
    int d = blockIdx.x & (DI - 1);
    int tid = threadIdx.x;
    #pragma unroll
    for (int q = 0; q < 8; ++q) {
        int l0 = q * 1024 + tid * 4;
        int t = l0 >> 4, n0 = l0 & 15;
        float4 v = *(const float4*)(Cm + (size_t)b * S * N + l0);
        CmL[t * 17 + n0]     = v.x;
        CmL[t * 17 + n0 + 1] = v.y;
        CmL[t * 17 + n0 + 2] = v.z;
        CmL[t * 17 + n0 + 3] = v.w;
    }
    __syncthreads();
    #pragma unroll
    for (int pass = 0; pass < 2; ++pass) {
        int t = pass * 256 + tid;
        int sb = t >> 5, si = t & 31;
        const ushort16* hb = histT + htIdx(b, d * N, sb) + si;
        float a0 = 0.f, a1 = 0.f, a2 = 0.f, a3 = 0.f;
        #pragma unroll
        for (int n = 0; n < 16; n += 4) {
            a0 += bf2f(hb[(size_t)n * 32])       * CmL[t * 17 + n];
            a1 += bf2f(hb[(size_t)(n + 1) * 32]) * CmL[t * 17 + n + 1];
            a2 += bf2f(hb[(size_t)(n + 2) * 32]) * CmL[t * 17 + n + 2];
            a3 += bf2f(hb[(size_t)(n + 3) * 32]) * CmL[t * 17 + n + 3];
        }
        float acc = (a0 + a1) + (a2 + a3);
        float zv = zs[((size_t)(b * S + t)) * DI + d];
        yzb[((size_t)(b * S + t)) * DI + d] = f2bf(acc * zv);
    }
}

// ---------------- launch ----------------
extern "C" void kernel_launch(void* const* d_in, const int* in_sizes, int n_in,
                              void* d_out, int out_size, void* d_ws, size_t ws_size,
                              hipStream_t stream) {
    const float* x      = (const float*)d_in[0];
    const float* adj    = (const float*)d_in[1];
    const float* ln_w   = (const float*)d_in[2];
    const float* ln_b   = (const float*)d_in[3];
    const float* W_in   = (const float*)d_in[4];
    const float* conv_w = (const float*)d_in[5];
    const float* conv_b = (const float*)d_in[6];
    const float* W_xp   = (const float*)d_in[7];
    const float* W_dt   = (const float*)d_in[8];
    const float* b_dt   = (const float*)d_in[9];
    const float* Wr     = (const float*)d_in[10];
    const float* br     = (const float*)d_in[11];
    const float* W_out  = (const float*)d_in[12];
    float* out = (float*)d_out;

    float* ws = (float*)d_ws;
    size_t off = 0;
    float* x_act  = ws + off; off += (size_t)B * S * DI;
    float* Bmb    = ws + off; off += (size_t)B * S * N;
    float* Cmb    = ws + off; off += (size_t)B * S * N;
    float* rdegp  = ws + off; off += (size_t)B * S;
    int*   flagI  = (int*)(ws + off); off += S;
    float* Ebuf   = ws + off; off += (size_t)B * S * DI;
    float* zsbuf  = ws + off; off += (size_t)B * S * DI;
    ushort16* xnb    = (ushort16*)(ws + off); off += (size_t)B * S * D / 2;
    ushort16* yzb    = (ushort16*)(ws + off); off += (size_t)B * S * DI / 2;
    ushort16* histT  = (ushort16*)(ws + off); off += (size_t)B * DN * S / 2;
    ushort16* xpb    = (ushort16*)(ws + off); off += (size_t)B * (S + 3) * DI / 2;

    hipMemsetAsync(flagI, 0, S * sizeof(int), stream);
    hipMemsetAsync(xpb, 0, (size_t)B * (S + 3) * DI * 2, stream);

    ln_k<<<B * S, 64, 0, stream>>>(x, ln_w, ln_b, xnb);
    gemmb_k<1><<<dim3(2 * DI / 64, B * S / 64), 256, 0, stream>>>(
        xnb, W_in, nullptr, nullptr, xpb, zsbuf, B * S, 2 * DI, D);
    convm_k<<<dim3(DI / 32, B * S / 32), 256, 0, stream>>>(xpb, conv_w, conv_b, x_act);
    ssmE_k<<<B * S / 4, 256, 0, stream>>>(x_act, W_xp, W_dt, b_dt, Bmb, Cmb, Ebuf);
    deg_k<<<B * S, 64, 0, stream>>>(adj, rdegp, flagI);

    chunkall_k<<<128, 256, 0, stream>>>(adj, x_act, Ebuf, Bmb, rdegp, flagI,
                                        Wr, br, histT);

    y_k<<<B * DI, 256, 0, stream>>>(histT, Cmb, zsbuf, yzb);

    gemmb_k<0><<<dim3(D / 64, B * S / 64), 256, 0, stream>>>(
        yzb, W_out, x, out, nullptr, nullptr, B * S, D, DI);
}

// Round 17
// 289.845 us; speedup vs baseline: 1.1202x; 1.1202x over previous
//
#include <hip/hip_runtime.h>
#include <math.h>

// Problem constants
static constexpr int B  = 2;
static constexpr int S  = 512;
static constexpr int D  = 256;
static constexpr int N  = 16;
static constexpr int DI = 512;
static constexpr int CHUNK = 32;
static constexpr int NCHUNK = S / CHUNK;   // 16
static constexpr int NL2 = 4;              // 4 launches, 4 chunks each
static constexpr int DN = DI * N;          // 8192
static constexpr int NSLOT = 8;            // 4 gold (tgt) + 4 tails (4+tgt)

typedef unsigned int uint32;
typedef unsigned short ushort16;
using bf16x8 = __attribute__((ext_vector_type(8))) short;
using f32x4  = __attribute__((ext_vector_type(4))) float;

__device__ __forceinline__ ushort16 f2bf(float f) {
    uint32 u = __float_as_uint(f);
    u = (u + 0x7fffu + ((u >> 16) & 1u)) >> 16;   // RNE
    return (ushort16)u;
}
__device__ __forceinline__ float bflo(uint32 u) { return __uint_as_float(u << 16); }
__device__ __forceinline__ float bfhi(uint32 u) { return __uint_as_float(u & 0xffff0000u); }
__device__ __forceinline__ float bf2f(ushort16 u) { return __uint_as_float(((uint32)u) << 16); }
__device__ __forceinline__ uint32 pk2(float a, float b) {
    return (uint32)(ushort16)f2bf(a) | ((uint32)(ushort16)f2bf(b) << 16);
}
// DPP row-rotate within 16-lane rows (VALU pipe, no LDS)
template<int K>
__device__ __forceinline__ float rork(float x) {
    return __uint_as_float((uint32)__builtin_amdgcn_mov_dpp(
        (int)__float_as_uint(x), 0x120 + K, 0xf, 0xf, false));
}
// histT tiled layout: elem (b, dn, s) -> ((b*(S/32) + s/32)*DN + dn)*32 + s%32
__device__ __forceinline__ size_t htIdx(int b, int dn, int sb) {
    return ((size_t)(b * (S / 32) + sb) * DN + dn) * 32;
}

// ---------------- LayerNorm: one wave per row, bf16 output ----------------
__global__ void ln_k(const float* __restrict__ x, const float* __restrict__ w,
                     const float* __restrict__ bias, ushort16* __restrict__ xnb) {
    int row = blockIdx.x;
    int lane = threadIdx.x;
    float4 v = *(const float4*)(x + row * D + lane * 4);
    float s = v.x + v.y + v.z + v.w;
    float q = v.x * v.x + v.y * v.y + v.z * v.z + v.w * v.w;
    for (int m = 1; m < 64; m <<= 1) { s += __shfl_xor(s, m); q += __shfl_xor(q, m); }
    float mu  = s * (1.0f / D);
    float var = q * (1.0f / D) - mu * mu;
    float rs  = rsqrtf(var + 1e-5f);
    float4 wv = *(const float4*)(w + lane * 4);
    float4 bv = *(const float4*)(bias + lane * 4);
    float4 o;
    o.x = (v.x - mu) * rs * wv.x + bv.x;
    o.y = (v.y - mu) * rs * wv.y + bv.y;
    o.z = (v.z - mu) * rs * wv.z + bv.z;
    o.w = (v.w - mu) * rs * wv.w + bv.w;
    uint2 pk;
    pk.x = pk2(o.x, o.y);
    pk.y = pk2(o.z, o.w);
    *(uint2*)(xnb + row * D + lane * 4) = pk;
}

// ------- bf16 MFMA GEMM, W in f32 (converted during staging) -------
template<int MODE>
__global__ __launch_bounds__(256) void gemmb_k(const ushort16* __restrict__ A,
                                               const float* __restrict__ W,
                                               const float* __restrict__ res,
                                               float* __restrict__ C,
                                               ushort16* __restrict__ xpb,
                                               float* __restrict__ zs,
                                               int M, int Nc, int K) {
    __shared__ __align__(16) short As[64 * 40];
    __shared__ __align__(16) short Ws[64 * 40];
    int tid = threadIdx.x;
    int l = tid & 63, wid = tid >> 6;
    int wm = wid & 1, wn = wid >> 1;
    int row0 = blockIdx.y * 64, col0 = blockIdx.x * 64;
    int r = tid >> 2, kseg = (tid & 3) * 8;
    f32x4 acc[2][2] = {};
    for (int k0 = 0; k0 < K; k0 += 32) {
        *(uint4*)&As[r * 40 + kseg] = *(const uint4*)(A + (size_t)(row0 + r) * K + k0 + kseg);
        {
            const float* wrow = W + (size_t)(col0 + r) * K + k0 + kseg;
            float4 w0 = *(const float4*)wrow;
            float4 w1 = *(const float4*)(wrow + 4);
            uint4 q;
            q.x = pk2(w0.x, w0.y); q.y = pk2(w0.z, w0.w);
            q.z = pk2(w1.x, w1.y); q.w = pk2(w1.z, w1.w);
            *(uint4*)&Ws[r * 40 + kseg] = q;
        }
        __syncthreads();
        bf16x8 aF[2], bF[2];
        #pragma unroll
        for (int am = 0; am < 2; ++am)
            aF[am] = *(const bf16x8*)&As[(wm * 32 + am * 16 + (l & 15)) * 40 + (l >> 4) * 8];
        #pragma unroll
        for (int bn = 0; bn < 2; ++bn)
            bF[bn] = *(const bf16x8*)&Ws[(wn * 32 + bn * 16 + (l & 15)) * 40 + (l >> 4) * 8];
        #pragma unroll
        for (int am = 0; am < 2; ++am)
            #pragma unroll
            for (int bn = 0; bn < 2; ++bn)
                acc[am][bn] = __builtin_amdgcn_mfma_f32_16x16x32_bf16(aF[am], bF[bn], acc[am][bn], 0, 0, 0);
        __syncthreads();
    }
    #pragma unroll
    for (int am = 0; am < 2; ++am)
        #pragma unroll
        for (int bn = 0; bn < 2; ++bn) {
            int cc = col0 + wn * 32 + bn * 16 + (l & 15);
            #pragma unroll
            for (int reg = 0; reg < 4; ++reg) {
                int rr = row0 + wm * 32 + am * 16 + (l >> 4) * 4 + reg;
                float v = acc[am][bn][reg];
                if (MODE == 0) {
                    if (res) v += res[(size_t)rr * Nc + cc];
                    C[(size_t)rr * Nc + cc] = v;
                } else {
                    int b = rr >> 9, t = rr & (S - 1);
                    if (cc < DI)
                        xpb[((size_t)(b * (S + 3) + 3 + t)) * DI + cc] = f2bf(v);
                    else
                        zs[((size_t)(b * S + t)) * DI + (cc - DI)] = v / (1.0f + __expf(-v));
                }
            }
        }
}

// ---------------- Causal conv via bf16 MFMA + bias + silu ----------------
__global__ __launch_bounds__(256) void convm_k(const ushort16* __restrict__ xpb,
                                               const float* __restrict__ conv_w,
                                               const float* __restrict__ conv_b,
                                               float* __restrict__ x_act) {
    __shared__ __align__(16) short AxS[35 * 40];
    __shared__ __align__(16) short WbS[4 * 32 * 40];
    int tid = threadIdx.x;
    int l = tid & 63, wid = tid >> 6;
    int wm = wid & 1, wn = wid >> 1;
    int o0 = blockIdx.x * 32;
    int mt = blockIdx.y;
    int b = mt >> 4, tl0 = (mt & 15) * 32;
    f32x4 acc = {0.f, 0.f, 0.f, 0.f};

    for (int k0 = 0; k0 < DI; k0 += 32) {
        if (tid < 140) {
            int rr = tid >> 2, seg = tid & 3;
            uint4 v = *(const uint4*)(xpb + ((size_t)(b * (S + 3) + tl0 + rr)) * DI + k0 + seg * 8);
            *(uint4*)&AxS[rr * 40 + seg * 8] = v;
        }
        #pragma unroll
        for (int it = 0; it < 4; ++it) {
            int p = it * 256 + tid;
            int o = p >> 5, i = p & 31;
            float4 w4 = *(const float4*)(conv_w + ((size_t)(o0 + o) * DI + (k0 + i)) * 4);
            WbS[(0 * 32 + o) * 40 + i] = (short)f2bf(w4.x);
            WbS[(1 * 32 + o) * 40 + i] = (short)f2bf(w4.y);
            WbS[(2 * 32 + o) * 40 + i] = (short)f2bf(w4.z);
            WbS[(3 * 32 + o) * 40 + i] = (short)f2bf(w4.w);
        }
        __syncthreads();
        #pragma unroll
        for (int k = 0; k < 4; ++k) {
            bf16x8 aF = *(const bf16x8*)&AxS[(wm * 16 + (l & 15) + k) * 40 + (l >> 4) * 8];
            bf16x8 bF = *(const bf16x8*)&WbS[(k * 32 + wn * 16 + (l & 15)) * 40 + (l >> 4) * 8];
            acc = __builtin_amdgcn_mfma_f32_16x16x32_bf16(aF, bF, acc, 0, 0, 0);
        }
        __syncthreads();
    }
    int oc = o0 + wn * 16 + (l & 15);
    float bia = conv_b[oc];
    #pragma unroll
    for (int reg = 0; reg < 4; ++reg) {
        int m = wm * 16 + (l >> 4) * 4 + reg;
        float v = acc[reg] + bia;
        x_act[((size_t)(b * S + tl0 + m)) * DI + oc] = v / (1.0f + __expf(-v));
    }
}

// ------- ssm (33 outputs) + E epilogue -------
__global__ void ssmE_k(const float* __restrict__ x_act, const float* __restrict__ W_xp,
                       const float* __restrict__ W_dt, const float* __restrict__ b_dt,
                       float* __restrict__ Bm, float* __restrict__ Cm,
                       float* __restrict__ E) {
    int row = blockIdx.x * 4 + (threadIdx.x >> 6);
    int lane = threadIdx.x & 63;
    const float* xr = x_act + (size_t)row * DI + lane * 8;
    float4 v0 = *(const float4*)xr;
    float4 v1 = *(const float4*)(xr + 4);
    float dtr = 0.0f;
    for (int j = 0; j < 2 * N + 1; ++j) {
        const float* wr = W_xp + (size_t)j * DI + lane * 8;
        float4 w0 = *(const float4*)wr;
        float4 w1 = *(const float4*)(wr + 4);
        float acc = v0.x * w0.x + v0.y * w0.y + v0.z * w0.z + v0.w * w0.w
                  + v1.x * w1.x + v1.y * w1.y + v1.z * w1.z + v1.w * w1.w;
        for (int m = 1; m < 64; m <<= 1) acc += __shfl_xor(acc, m);
        if (j == 0) dtr = acc;
        if (lane == 0) {
            if (j >= 1 && j < 1 + N) Bm[(size_t)row * N + (j - 1)] = acc;
            else if (j >= 1 + N)     Cm[(size_t)row * N + (j - 1 - N)] = acc;
        }
    }
    int d0 = lane * 8;
    float4 w0 = *(const float4*)(W_dt + d0);
    float4 w1 = *(const float4*)(W_dt + d0 + 4);
    float4 q0 = *(const float4*)(b_dt + d0);
    float4 q1 = *(const float4*)(b_dt + d0 + 4);
    float4 e0, e1;
    e0.x = 1.0f / (1.0f + __expf(dtr * w0.x + q0.x));
    e0.y = 1.0f / (1.0f + __expf(dtr * w0.y + q0.y));
    e0.z = 1.0f / (1.0f + __expf(dtr * w0.z + q0.z));
    e0.w = 1.0f / (1.0f + __expf(dtr * w0.w + q0.w));
    e1.x = 1.0f / (1.0f + __expf(dtr * w1.x + q1.x));
    e1.y = 1.0f / (1.0f + __expf(dtr * w1.y + q1.y));
    e1.z = 1.0f / (1.0f + __expf(dtr * w1.z + q1.z));
    e1.w = 1.0f / (1.0f + __expf(dtr * w1.w + q1.w));
    *(float4*)(E + (size_t)row * DI + d0) = e0;
    *(float4*)(E + (size_t)row * DI + d0 + 4) = e1;
}

// ---------------- rdeg = 1/max(sum_{s<t} adj,1); flag[t] ----------------
__global__ void deg_k(const float* __restrict__ adj, float* __restrict__ rdeg, int* __restrict__ flagI) {
    int t = blockIdx.x & (S - 1), b = blockIdx.x >> 9;
    int lane = threadIdx.x;
    const float* row = adj + ((size_t)(b * S + t)) * S;
    float s = 0.0f; bool anyp = false;
    for (int i = lane; i < t; i += 64) { float v = row[i]; s += v; anyp |= (v > 0.0f); }
    for (int m = 1; m < 64; m <<= 1) s += __shfl_xor(s, m);
    bool any = __any(anyp);
    if (lane == 0) {
        rdeg[b * S + t] = 1.0f / fmaxf(s, 1.0f);
        if (t > 0 && any) atomicOr(flagI + t, 1);
    }
}

// ================= quad-chunk fused kernel, compact code (256 thr, 640 blocks) =========
__global__ __launch_bounds__(256) void chunk4_k(const float* __restrict__ adj,
                                                const float* __restrict__ x_act,
                                                const float* __restrict__ E,
                                                const float* __restrict__ Bm,
                                                const float* __restrict__ rdeg,
                                                const int* __restrict__ flagI,
                                                const float* __restrict__ Wr,
                                                const float* __restrict__ br,
                                                ushort16* __restrict__ Gall,
                                                ushort16* __restrict__ histT,
                                                float* __restrict__ hlast, int lc) {
    __shared__ __align__(16) char smem[50432];
    int tid = threadIdx.x;
    int c0 = 4 * lc;
    int c0s = c0 * CHUNK;
    const size_t SLOT = (size_t)B * DN * 32;
    int rp = lc & 1, wp = (lc + 1) & 1;

    if (blockIdx.x < 128) {
        // scan role: one instance of each phase, ci-loop over 4 chunks
        float* tri   = (float*)smem;                  // [32][36] f32
        float* eL    = (float*)(smem + 4608);         // [32][8]
        float* xaL   = (float*)(smem + 5632);
        float* BnL   = (float*)(smem + 6656);         // [32][16]
        float* rdegL = (float*)(smem + 8704);         // [32]
        int*   flL   = (int*)  (smem + 8832);         // [32]
        short* hTbase = (short*)(smem + 8960);        // 4 x [4][128][8] bf16 (4096 shorts ea)
        short* Gmid  = (short*)(smem + 41728);        // [32][136] bf16

        int b = blockIdx.x >> 6;
        int d0 = (blockIdx.x & 63) << 3;
        int n = tid & 15, grp = (tid >> 4) & 7;
        int d = d0 + grp;
        int dn = d * N + n;
        int dnbase = (blockIdx.x & 63) << 7;

        float wrr[16];
        float brn = 0.f, h = 0.f;
        float gs[CHUNK];
        float hreg[CHUNK];
        if (tid < 128) {
            int probe = __builtin_amdgcn_mov_dpp((int)n, 0x121, 0xf, 0xf, false);
            bool plusdir = (probe == ((n + 1) & 15));
            #pragma unroll
            for (int k = 0; k < 16; ++k) {
                int ip = (n + k) & 15, im = (n - k + 16) & 15;
                wrr[k] = Wr[n * 16 + (plusdir ? ip : im)];
            }
            brn = br[n];
            h = (lc == 0) ? 0.0f : hlast[b * DN + dn];
        }

        #pragma unroll 1
        for (int ci = 0; ci < 4; ++ci) {
            int crow = c0s + ci * 32;
            // ---- stage chunk ci (all 256 threads) ----
            {
                int j = tid >> 3, s4 = (tid & 7) * 4;
                float4 a0 = *(const float4*)(adj + ((size_t)(b * S + crow + j)) * S + crow + s4);
                float* dp = tri + j * 36 + s4;
                dp[0] = a0.x; dp[1] = a0.y; dp[2] = a0.z; dp[3] = a0.w;
                int dd = tid & 7;
                eL [j * 8 + dd] = E    [((size_t)(b * S + crow + j)) * DI + d0 + dd];
                xaL[j * 8 + dd] = x_act[((size_t)(b * S + crow + j)) * DI + d0 + dd];
                int nn = (tid & 7) * 2;
                float2 bv = *(const float2*)(Bm + ((size_t)(b * S + crow + j)) * N + nn);
                BnL[j * 16 + nn] = bv.x; BnL[j * 16 + nn + 1] = bv.y;
                if (tid < 32) {
                    rdegL[tid] = rdeg[b * S + crow + tid];
                    flL[tid]   = flagI[crow + tid];
                }
            }
            __syncthreads();
            // ---- midphase: Gmid = sum_{sidx<ci} adj(ci rows, sidx cols) x hT[sidx] ----
            if (ci > 0 && tid < 128) {
                int w = tid >> 6, l = tid & 63;
                int ksg = (l >> 4) * 8;
                f32x4 ac0[4] = {}, ac1[4] = {};
                for (int sidx = 0; sidx < ci; ++sidx) {
                    const float* p0 = adj + ((size_t)(b * S + crow + (l & 15))) * S
                                    + c0s + sidx * 32 + ksg;
                    const float* p1 = p0 + 16 * S;
                    float4 a00 = *(const float4*)p0, a01 = *(const float4*)(p0 + 4);
                    float4 a10 = *(const float4*)p1, a11 = *(const float4*)(p1 + 4);
                    uint4 qa, qb;
                    qa.x = pk2(a00.x, a00.y); qa.y = pk2(a00.z, a00.w);
                    qa.z = pk2(a01.x, a01.y); qa.w = pk2(a01.z, a01.w);
                    qb.x = pk2(a10.x, a10.y); qb.y = pk2(a10.z, a10.w);
                    qb.z = pk2(a11.x, a11.y); qb.w = pk2(a11.z, a11.w);
                    bf16x8 aF0, aF1;
                    *(uint4*)&aF0 = qa; *(uint4*)&aF1 = qb;
                    const short* hTs = hTbase + sidx * 4096;
                    #pragma unroll
                    for (int dblk = 0; dblk < 4; ++dblk) {
                        int col = w * 64 + dblk * 16 + (l & 15);
                        bf16x8 bF = *(const bf16x8*)&hTs[(l >> 4) * 1024 + col * 8];
                        ac0[dblk] = __builtin_amdgcn_mfma_f32_16x16x32_bf16(aF0, bF, ac0[dblk], 0, 0, 0);
                        ac1[dblk] = __builtin_amdgcn_mfma_f32_16x16x32_bf16(aF1, bF, ac1[dblk], 0, 0, 0);
                    }
                }
                int jb0 = (l >> 4) * 4;
                #pragma unroll
                for (int dblk = 0; dblk < 4; ++dblk) {
                    int col = w * 64 + dblk * 16 + (l & 15);
                    #pragma unroll
                    for (int reg = 0; reg < 4; ++reg) {
                        Gmid[(jb0 + reg) * 136 + col]      = (short)f2bf(ac0[dblk][reg]);
                        Gmid[(16 + jb0 + reg) * 136 + col] = (short)f2bf(ac1[dblk][reg]);
                    }
                }
            }
            __syncthreads();
            if (tid < 128) {
                // ---- gather G: presum gold/tail slots + in-launch mid ----
                #pragma unroll
                for (int j = 0; j < CHUNK; ++j) gs[j] = 0.f;
                size_t tb = ((size_t)b * DN + dn) * 32;
                if (lc >= 2) {
                    const ushort16* p = Gall + ((size_t)rp * NSLOT + ci) * SLOT + tb;
                    #pragma unroll
                    for (int qi = 0; qi < 4; ++qi) {
                        uint4 q = *(const uint4*)(p + qi * 8);
                        gs[qi*8+0] += bflo(q.x); gs[qi*8+1] += bfhi(q.x);
                        gs[qi*8+2] += bflo(q.y); gs[qi*8+3] += bfhi(q.y);
                        gs[qi*8+4] += bflo(q.z); gs[qi*8+5] += bfhi(q.z);
                        gs[qi*8+6] += bflo(q.w); gs[qi*8+7] += bfhi(q.w);
                    }
                }
                if (lc >= 1) {
                    const ushort16* p = Gall + ((size_t)rp * NSLOT + 4 + ci) * SLOT + tb;
                    #pragma unroll
                    for (int qi = 0; qi < 4; ++qi) {
                        uint4 q = *(const uint4*)(p + qi * 8);
                        gs[qi*8+0] += bflo(q.x); gs[qi*8+1] += bfhi(q.x);
                        gs[qi*8+2] += bflo(q.y); gs[qi*8+3] += bfhi(q.y);
                        gs[qi*8+4] += bflo(q.z); gs[qi*8+5] += bfhi(q.z);
                        gs[qi*8+6] += bflo(q.w); gs[qi*8+7] += bfhi(q.w);
                    }
                }
                if (ci > 0) {
                    #pragma unroll
                    for (int j = 0; j < CHUNK; ++j)
                        gs[j] += bf2f((ushort16)Gmid[j * 136 + tid]);
                }
                // ---- serial scan of 32 steps ----
                #pragma unroll
                for (int j = 0; j < CHUNK; ++j) {
                    float e  = eL [j * 8 + grp];
                    float xa = xaL[j * 8 + grp];
                    float Bn = BnL[j * 16 + n];
                    h = h * e + xa * Bn;
                    float g0 = gs[j], g1 = 0.f, g2 = 0.f, g3 = 0.f;
                    const float* ar = tri + j * 36;
                    int sp = 0;
                    #pragma unroll
                    for (; sp + 4 <= j; sp += 4) {
                        float4 av = *(const float4*)(ar + sp);
                        g0 += av.x * hreg[sp];     g1 += av.y * hreg[sp + 1];
                        g2 += av.z * hreg[sp + 2]; g3 += av.w * hreg[sp + 3];
                    }
                    #pragma unroll
                    for (; sp < j; ++sp) g0 += ar[sp] * hreg[sp];
                    float gr = (g0 + g1) + (g2 + g3);
                    float m0 = gr * wrr[0] + rork<4>(gr) * wrr[4]
                             + rork<8>(gr) * wrr[8] + rork<12>(gr) * wrr[12];
                    float m1 = rork<1>(gr) * wrr[1] + rork<5>(gr) * wrr[5]
                             + rork<9>(gr) * wrr[9] + rork<13>(gr) * wrr[13];
                    float m2 = rork<2>(gr) * wrr[2] + rork<6>(gr) * wrr[6]
                             + rork<10>(gr) * wrr[10] + rork<14>(gr) * wrr[14];
                    float m3 = rork<3>(gr) * wrr[3] + rork<7>(gr) * wrr[7]
                             + rork<11>(gr) * wrr[11] + rork<15>(gr) * wrr[15];
                    float acc = fmaf(rdegL[j], (m0 + m1) + (m2 + m3), brn);
                    if (flL[j])
                        h = fmaf(0.1f * acc,
                                 __builtin_amdgcn_rcpf(1.0f + __expf(-acc)), h);
                    hreg[j] = h;
                }
                // ---- hist write (global tiled + LDS hT) ----
                {
                    ushort16* ht = histT + htIdx(b, dn, c0 + ci);
                    short* htb = hTbase + ci * 4096;
                    #pragma unroll
                    for (int qi = 0; qi < 4; ++qi) {
                        uint4 q;
                        q.x = pk2(hreg[qi*8+0], hreg[qi*8+1]);
                        q.y = pk2(hreg[qi*8+2], hreg[qi*8+3]);
                        q.z = pk2(hreg[qi*8+4], hreg[qi*8+5]);
                        q.w = pk2(hreg[qi*8+6], hreg[qi*8+7]);
                        *(uint4*)(ht + qi * 8) = q;
                        *(uint4*)&htb[qi * 1024 + tid * 8] = q;
                    }
                }
            }
            __syncthreads();
        }
        if (tid < 128) hlast[b * DN + dn] = h;

        // ---- tails: accumulated over src -> 4 slots (all 256 threads) ----
        if (lc < NL2 - 1) {
            int half = tid >> 7;
            int lt = tid & 127;
            int w = lt >> 6, l = lt & 63;
            int ksg = (l >> 4) * 8;
            int jb0 = (l >> 4) * 4;
            #pragma unroll 1
            for (int tp = 0; tp < 2; ++tp) {
                int tgt = half * 2 + tp;
                f32x4 ac0[4] = {}, ac1[4] = {};
                #pragma unroll 1
                for (int src = 0; src < 4; ++src) {
                    const short* hTs = hTbase + src * 4096;
                    const float* p0 = adj + ((size_t)(b * S + (4 * (lc + 1) + tgt) * 32 + (l & 15))) * S
                                    + (4 * lc + src) * 32 + ksg;
                    const float* p1 = p0 + 16 * S;
                    float4 a00 = *(const float4*)p0, a01 = *(const float4*)(p0 + 4);
                    float4 a10 = *(const float4*)p1, a11 = *(const float4*)(p1 + 4);
                    uint4 qa, qb;
                    qa.x = pk2(a00.x, a00.y); qa.y = pk2(a00.z, a00.w);
                    qa.z = pk2(a01.x, a01.y); qa.w = pk2(a01.z, a01.w);
                    qb.x = pk2(a10.x, a10.y); qb.y = pk2(a10.z, a10.w);
                    qb.z = pk2(a11.x, a11.y); qb.w = pk2(a11.z, a11.w);
                    bf16x8 aF0, aF1;
                    *(uint4*)&aF0 = qa; *(uint4*)&aF1 = qb;
                    #pragma unroll
                    for (int dblk = 0; dblk < 4; ++dblk) {
                        int col = w * 64 + dblk * 16 + (l & 15);
                        bf16x8 bF = *(const bf16x8*)&hTs[(l >> 4) * 1024 + col * 8];
                        ac0[dblk] = __builtin_amdgcn_mfma_f32_16x16x32_bf16(aF0, bF, ac0[dblk], 0, 0, 0);
                        ac1[dblk] = __builtin_amdgcn_mfma_f32_16x16x32_bf16(aF1, bF, ac1[dblk], 0, 0, 0);
                    }
                }
                ushort16* gw = Gall + ((size_t)wp * NSLOT + (4 + tgt)) * SLOT;
                #pragma unroll
                for (int dblk = 0; dblk < 4; ++dblk) {
                    int col = w * 64 + dblk * 16 + (l & 15);
                    int dng = dnbase + col;
                    uint2 o0, o1;
                    o0.x = pk2(ac0[dblk][0], ac0[dblk][1]); o0.y = pk2(ac0[dblk][2], ac0[dblk][3]);
                    o1.x = pk2(ac1[dblk][0], ac1[dblk][1]); o1.y = pk2(ac1[dblk][2], ac1[dblk][3]);
                    *(uint2*)(gw + ((size_t)b * DN + dng) * 32 + jb0) = o0;
                    *(uint2*)(gw + ((size_t)b * DN + dng) * 32 + 16 + jb0) = o1;
                }
            }
        }
    } else {
        // -------- gpast role: gold(tgt) over chunks 0..4lc-1, streamed MFMA --------
        if (lc == 0 || lc >= NL2 - 1) return;
        int idx = blockIdx.x - 128;                // 0..511
        int tile = idx & 63;
        int b = (idx >> 6) & 1;
        int tgt = idx >> 7;                        // 0..3
        int tc = 4 * (lc + 1) + tgt;
        int dn0 = tile * 128;
        int w = tid >> 6, l = tid & 63;
        int jh = w & 1, dh = w >> 1;
        int ksg = (l >> 4) * 8;
        const float* abase = adj + ((size_t)(b * S + tc * CHUNK + jh * 16 + (l & 15))) * S + ksg;
        int dnrow = dn0 + dh * 64 + (l & 15);
        int K = 4 * lc;
        f32x4 acc[4] = {};
        #pragma unroll 2
        for (int ks = 0; ks < K; ++ks) {
            float4 af0 = *(const float4*)(abase + ks * 32);
            float4 af1 = *(const float4*)(abase + ks * 32 + 4);
            uint4 aP;
            aP.x = pk2(af0.x, af0.y); aP.y = pk2(af0.z, af0.w);
            aP.z = pk2(af1.x, af1.y); aP.w = pk2(af1.z, af1.w);
            bf16x8 aF;
            *(uint4*)&aF = aP;
            uint4 bP[4];
            #pragma unroll
            for (int dblk = 0; dblk < 4; ++dblk)
                bP[dblk] = *(const uint4*)(histT + htIdx(b, dnrow + dblk * 16, ks) + ksg);
            #pragma unroll
            for (int dblk = 0; dblk < 4; ++dblk) {
                bf16x8 bF;
                *(uint4*)&bF = bP[dblk];
                acc[dblk] = __builtin_amdgcn_mfma_f32_16x16x32_bf16(aF, bF, acc[dblk], 0, 0, 0);
            }
        }
        int jb = jh * 16 + (l >> 4) * 4;
        ushort16* gbase = Gall + ((size_t)wp * NSLOT + tgt) * SLOT;
        #pragma unroll
        for (int dblk = 0; dblk < 4; ++dblk) {
            int dnc = dn0 + dh * 64 + dblk * 16 + (l & 15);
            uint2 o;
            o.x = pk2(acc[dblk][0], acc[dblk][1]);
            o.y = pk2(acc[dblk][2], acc[dblk][3]);
            *(uint2*)(gbase + ((size_t)b * DN + dnc) * 32 + jb) = o;
        }
    }
}

// ---------------- y_k: y[b,t,d] = (sum_n histT[b][dn][t]*Cm[b,t,n]) * zs[b,t,d] -------
__global__ __launch_bounds__(256) void y_k(const ushort16* __restrict__ histT,
                                           const float* __restrict__ Cm,
                                           const float* __restrict__ zs,
                                           ushort16* __restrict__ yzb) {
    __shared__ float CmL[S * 17];
    int b = blockIdx.x >> 9;
    int d = blockIdx.x & (DI - 1);
    int tid = threadIdx.x;
    #pragma unroll
    for (int q = 0; q < 8; ++q) {
        int l0 = q * 1024 + tid * 4;
        int t = l0 >> 4, n0 = l0 & 15;
        float4 v = *(const float4*)(Cm + (size_t)b * S * N + l0);
        CmL[t * 17 + n0]     = v.x;
        CmL[t * 17 + n0 + 1] = v.y;
        CmL[t * 17 + n0 + 2] = v.z;
        CmL[t * 17 + n0 + 3] = v.w;
    }
    __syncthreads();
    #pragma unroll
    for (int pass = 0; pass < 2; ++pass) {
        int t = pass * 256 + tid;
        int sb = t >> 5, si = t & 31;
        const ushort16* hb = histT + htIdx(b, d * N, sb) + si;
        float a0 = 0.f, a1 = 0.f, a2 = 0.f, a3 = 0.f;
        #pragma unroll
        for (int n = 0; n < 16; n += 4) {
            a0 += bf2f(hb[(size_t)n * 32])       * CmL[t * 17 + n];
            a1 += bf2f(hb[(size_t)(n + 1) * 32]) * CmL[t * 17 + n + 1];
            a2 += bf2f(hb[(size_t)(n + 2) * 32]) * CmL[t * 17 + n + 2];
            a3 += bf2f(hb[(size_t)(n + 3) * 32]) * CmL[t * 17 + n + 3];
        }
        float acc = (a0 + a1) + (a2 + a3);
        float zv = zs[((size_t)(b * S + t)) * DI + d];
        yzb[((size_t)(b * S + t)) * DI + d] = f2bf(acc * zv);
    }
}

// ---------------- launch ----------------
extern "C" void kernel_launch(void* const* d_in, const int* in_sizes, int n_in,
                              void* d_out, int out_size, void* d_ws, size_t ws_size,
                              hipStream_t stream) {
    const float* x      = (const float*)d_in[0];
    const float* adj    = (const float*)d_in[1];
    const float* ln_w   = (const float*)d_in[2];
    const float* ln_b   = (const float*)d_in[3];
    const float* W_in   = (const float*)d_in[4];
    const float* conv_w = (const float*)d_in[5];
    const float* conv_b = (const float*)d_in[6];
    const float* W_xp   = (const float*)d_in[7];
    const float* W_dt   = (const float*)d_in[8];
    const float* b_dt   = (const float*)d_in[9];
    const float* Wr     = (const float*)d_in[10];
    const float* br     = (const float*)d_in[11];
    const float* W_out  = (const float*)d_in[12];
    float* out = (float*)d_out;

    float* ws = (float*)d_ws;
    size_t off = 0;
    float* x_act  = ws + off; off += (size_t)B * S * DI;
    float* Bmb    = ws + off; off += (size_t)B * S * N;
    float* Cmb    = ws + off; off += (size_t)B * S * N;
    float* rdegp  = ws + off; off += (size_t)B * S;
    int*   flagI  = (int*)(ws + off); off += S;
    float* Ebuf   = ws + off; off += (size_t)B * S * DI;
    float* zsbuf  = ws + off; off += (size_t)B * S * DI;
    float* hlast  = ws + off; off += (size_t)B * DN;
    ushort16* xnb    = (ushort16*)(ws + off); off += (size_t)B * S * D / 2;
    ushort16* yzb    = (ushort16*)(ws + off); off += (size_t)B * S * DI / 2;
    ushort16* histT  = (ushort16*)(ws + off); off += (size_t)B * DN * S / 2;
    ushort16* Gall   = (ushort16*)(ws + off); off += (size_t)2 * NSLOT * B * DN * 32 / 2;
    ushort16* xpb    = (ushort16*)(ws + off); off += (size_t)B * (S + 3) * DI / 2;

    hipMemsetAsync(flagI, 0, S * sizeof(int), stream);
    hipMemsetAsync(xpb, 0, (size_t)B * (S + 3) * DI * 2, stream);

    ln_k<<<B * S, 64, 0, stream>>>(x, ln_w, ln_b, xnb);
    gemmb_k<1><<<dim3(2 * DI / 64, B * S / 64), 256, 0, stream>>>(
        xnb, W_in, nullptr, nullptr, xpb, zsbuf, B * S, 2 * DI, D);
    convm_k<<<dim3(DI / 32, B * S / 32), 256, 0, stream>>>(xpb, conv_w, conv_b, x_act);
    ssmE_k<<<B * S / 4, 256, 0, stream>>>(x_act, W_xp, W_dt, b_dt, Bmb, Cmb, Ebuf);
    deg_k<<<B * S, 64, 0, stream>>>(adj, rdegp, flagI);

    for (int lc = 0; lc < NL2; ++lc)
        chunk4_k<<<640, 256, 0, stream>>>(adj, x_act, Ebuf, Bmb, rdegp, flagI,
                                          Wr, br, Gall, histT, hlast, lc);

    y_k<<<B * DI, 256, 0, stream>>>(histT, Cmb, zsbuf, yzb);

    gemmb_k<0><<<dim3(D / 64, B * S / 64), 256, 0, stream>>>(
        yzb, W_out, x, out, nullptr, nullptr, B * S, D, DI);
}

// Round 18
// 259.244 us; speedup vs baseline: 1.2524x; 1.1180x over previous
//
#include <hip/hip_runtime.h>
#include <math.h>

// Problem constants
static constexpr int B  = 2;
static constexpr int S  = 512;
static constexpr int D  = 256;
static constexpr int N  = 16;
static constexpr int DI = 512;
static constexpr int CHUNK = 32;
static constexpr int NCHUNK = S / CHUNK;   // 16
static constexpr int NL2 = 4;              // 4 launches, 4 chunks each
static constexpr int DN = DI * N;          // 8192
static constexpr int NSLOT = 8;            // 4 gold (tgt) + 4 tails (4+tgt)

typedef unsigned int uint32;
typedef unsigned short ushort16;
using bf16x8 = __attribute__((ext_vector_type(8))) short;
using f32x4  = __attribute__((ext_vector_type(4))) float;

__device__ __forceinline__ ushort16 f2bf(float f) {
    uint32 u = __float_as_uint(f);
    u = (u + 0x7fffu + ((u >> 16) & 1u)) >> 16;   // RNE
    return (ushort16)u;
}
__device__ __forceinline__ float bflo(uint32 u) { return __uint_as_float(u << 16); }
__device__ __forceinline__ float bfhi(uint32 u) { return __uint_as_float(u & 0xffff0000u); }
__device__ __forceinline__ float bf2f(ushort16 u) { return __uint_as_float(((uint32)u) << 16); }
__device__ __forceinline__ uint32 pk2(float a, float b) {
    return (uint32)(ushort16)f2bf(a) | ((uint32)(ushort16)f2bf(b) << 16);
}
// DPP row-rotate within 16-lane rows (VALU pipe, no LDS)
template<int K>
__device__ __forceinline__ float rork(float x) {
    return __uint_as_float((uint32)__builtin_amdgcn_mov_dpp(
        (int)__float_as_uint(x), 0x120 + K, 0xf, 0xf, false));
}
// histT tiled layout: elem (b, dn, s) -> ((b*(S/32) + s/32)*DN + dn)*32 + s%32
__device__ __forceinline__ size_t htIdx(int b, int dn, int sb) {
    return ((size_t)(b * (S / 32) + sb) * DN + dn) * 32;
}

// ---------------- LayerNorm: one wave per row, bf16 output ----------------
__global__ void ln_k(const float* __restrict__ x, const float* __restrict__ w,
                     const float* __restrict__ bias, ushort16* __restrict__ xnb) {
    int row = blockIdx.x;
    int lane = threadIdx.x;
    float4 v = *(const float4*)(x + row * D + lane * 4);
    float s = v.x + v.y + v.z + v.w;
    float q = v.x * v.x + v.y * v.y + v.z * v.z + v.w * v.w;
    for (int m = 1; m < 64; m <<= 1) { s += __shfl_xor(s, m); q += __shfl_xor(q, m); }
    float mu  = s * (1.0f / D);
    float var = q * (1.0f / D) - mu * mu;
    float rs  = rsqrtf(var + 1e-5f);
    float4 wv = *(const float4*)(w + lane * 4);
    float4 bv = *(const float4*)(bias + lane * 4);
    float4 o;
    o.x = (v.x - mu) * rs * wv.x + bv.x;
    o.y = (v.y - mu) * rs * wv.y + bv.y;
    o.z = (v.z - mu) * rs * wv.z + bv.z;
    o.w = (v.w - mu) * rs * wv.w + bv.w;
    uint2 pk;
    pk.x = pk2(o.x, o.y);
    pk.y = pk2(o.z, o.w);
    *(uint2*)(xnb + row * D + lane * 4) = pk;
}

// ------- bf16 MFMA GEMM, W in f32 (converted during staging) -------
template<int MODE>
__global__ __launch_bounds__(256) void gemmb_k(const ushort16* __restrict__ A,
                                               const float* __restrict__ W,
                                               const float* __restrict__ res,
                                               float* __restrict__ C,
                                               ushort16* __restrict__ xpb,
                                               float* __restrict__ zs,
                                               int M, int Nc, int K) {
    __shared__ __align__(16) short As[64 * 40];
    __shared__ __align__(16) short Ws[64 * 40];
    int tid = threadIdx.x;
    int l = tid & 63, wid = tid >> 6;
    int wm = wid & 1, wn = wid >> 1;
    int row0 = blockIdx.y * 64, col0 = blockIdx.x * 64;
    int r = tid >> 2, kseg = (tid & 3) * 8;
    f32x4 acc[2][2] = {};
    for (int k0 = 0; k0 < K; k0 += 32) {
        *(uint4*)&As[r * 40 + kseg] = *(const uint4*)(A + (size_t)(row0 + r) * K + k0 + kseg);
        {
            const float* wrow = W + (size_t)(col0 + r) * K + k0 + kseg;
            float4 w0 = *(const float4*)wrow;
            float4 w1 = *(const float4*)(wrow + 4);
            uint4 q;
            q.x = pk2(w0.x, w0.y); q.y = pk2(w0.z, w0.w);
            q.z = pk2(w1.x, w1.y); q.w = pk2(w1.z, w1.w);
            *(uint4*)&Ws[r * 40 + kseg] = q;
        }
        __syncthreads();
        bf16x8 aF[2], bF[2];
        #pragma unroll
        for (int am = 0; am < 2; ++am)
            aF[am] = *(const bf16x8*)&As[(wm * 32 + am * 16 + (l & 15)) * 40 + (l >> 4) * 8];
        #pragma unroll
        for (int bn = 0; bn < 2; ++bn)
            bF[bn] = *(const bf16x8*)&Ws[(wn * 32 + bn * 16 + (l & 15)) * 40 + (l >> 4) * 8];
        #pragma unroll
        for (int am = 0; am < 2; ++am)
            #pragma unroll
            for (int bn = 0; bn < 2; ++bn)
                acc[am][bn] = __builtin_amdgcn_mfma_f32_16x16x32_bf16(aF[am], bF[bn], acc[am][bn], 0, 0, 0);
        __syncthreads();
    }
    #pragma unroll
    for (int am = 0; am < 2; ++am)
        #pragma unroll
        for (int bn = 0; bn < 2; ++bn) {
            int cc = col0 + wn * 32 + bn * 16 + (l & 15);
            #pragma unroll
            for (int reg = 0; reg < 4; ++reg) {
                int rr = row0 + wm * 32 + am * 16 + (l >> 4) * 4 + reg;
                float v = acc[am][bn][reg];
                if (MODE == 0) {
                    if (res) v += res[(size_t)rr * Nc + cc];
                    C[(size_t)rr * Nc + cc] = v;
                } else {
                    int b = rr >> 9, t = rr & (S - 1);
                    if (cc < DI)
                        xpb[((size_t)(b * (S + 3) + 3 + t)) * DI + cc] = f2bf(v);
                    else
                        zs[((size_t)(b * S + t)) * DI + (cc - DI)] = v / (1.0f + __expf(-v));
                }
            }
        }
}

// ---------------- Causal conv via bf16 MFMA + bias + silu ----------------
__global__ __launch_bounds__(256) void convm_k(const ushort16* __restrict__ xpb,
                                               const float* __restrict__ conv_w,
                                               const float* __restrict__ conv_b,
                                               float* __restrict__ x_act) {
    __shared__ __align__(16) short AxS[35 * 40];
    __shared__ __align__(16) short WbS[4 * 32 * 40];
    int tid = threadIdx.x;
    int l = tid & 63, wid = tid >> 6;
    int wm = wid & 1, wn = wid >> 1;
    int o0 = blockIdx.x * 32;
    int mt = blockIdx.y;
    int b = mt >> 4, tl0 = (mt & 15) * 32;
    f32x4 acc = {0.f, 0.f, 0.f, 0.f};

    for (int k0 = 0; k0 < DI; k0 += 32) {
        if (tid < 140) {
            int rr = tid >> 2, seg = tid & 3;
            uint4 v = *(const uint4*)(xpb + ((size_t)(b * (S + 3) + tl0 + rr)) * DI + k0 + seg * 8);
            *(uint4*)&AxS[rr * 40 + seg * 8] = v;
        }
        #pragma unroll
        for (int it = 0; it < 4; ++it) {
            int p = it * 256 + tid;
            int o = p >> 5, i = p & 31;
            float4 w4 = *(const float4*)(conv_w + ((size_t)(o0 + o) * DI + (k0 + i)) * 4);
            WbS[(0 * 32 + o) * 40 + i] = (short)f2bf(w4.x);
            WbS[(1 * 32 + o) * 40 + i] = (short)f2bf(w4.y);
            WbS[(2 * 32 + o) * 40 + i] = (short)f2bf(w4.z);
            WbS[(3 * 32 + o) * 40 + i] = (short)f2bf(w4.w);
        }
        __syncthreads();
        #pragma unroll
        for (int k = 0; k < 4; ++k) {
            bf16x8 aF = *(const bf16x8*)&AxS[(wm * 16 + (l & 15) + k) * 40 + (l >> 4) * 8];
            bf16x8 bF = *(const bf16x8*)&WbS[(k * 32 + wn * 16 + (l & 15)) * 40 + (l >> 4) * 8];
            acc = __builtin_amdgcn_mfma_f32_16x16x32_bf16(aF, bF, acc, 0, 0, 0);
        }
        __syncthreads();
    }
    int oc = o0 + wn * 16 + (l & 15);
    float bia = conv_b[oc];
    #pragma unroll
    for (int reg = 0; reg < 4; ++reg) {
        int m = wm * 16 + (l >> 4) * 4 + reg;
        float v = acc[reg] + bia;
        x_act[((size_t)(b * S + tl0 + m)) * DI + oc] = v / (1.0f + __expf(-v));
    }
}

// ------- ssm (33 outputs) + E epilogue -------
__global__ void ssmE_k(const float* __restrict__ x_act, const float* __restrict__ W_xp,
                       const float* __restrict__ W_dt, const float* __restrict__ b_dt,
                       float* __restrict__ Bm, float* __restrict__ Cm,
                       float* __restrict__ E) {
    int row = blockIdx.x * 4 + (threadIdx.x >> 6);
    int lane = threadIdx.x & 63;
    const float* xr = x_act + (size_t)row * DI + lane * 8;
    float4 v0 = *(const float4*)xr;
    float4 v1 = *(const float4*)(xr + 4);
    float dtr = 0.0f;
    for (int j = 0; j < 2 * N + 1; ++j) {
        const float* wr = W_xp + (size_t)j * DI + lane * 8;
        float4 w0 = *(const float4*)wr;
        float4 w1 = *(const float4*)(wr + 4);
        float acc = v0.x * w0.x + v0.y * w0.y + v0.z * w0.z + v0.w * w0.w
                  + v1.x * w1.x + v1.y * w1.y + v1.z * w1.z + v1.w * w1.w;
        for (int m = 1; m < 64; m <<= 1) acc += __shfl_xor(acc, m);
        if (j == 0) dtr = acc;
        if (lane == 0) {
            if (j >= 1 && j < 1 + N) Bm[(size_t)row * N + (j - 1)] = acc;
            else if (j >= 1 + N)     Cm[(size_t)row * N + (j - 1 - N)] = acc;
        }
    }
    int d0 = lane * 8;
    float4 w0 = *(const float4*)(W_dt + d0);
    float4 w1 = *(const float4*)(W_dt + d0 + 4);
    float4 q0 = *(const float4*)(b_dt + d0);
    float4 q1 = *(const float4*)(b_dt + d0 + 4);
    float4 e0, e1;
    e0.x = 1.0f / (1.0f + __expf(dtr * w0.x + q0.x));
    e0.y = 1.0f / (1.0f + __expf(dtr * w0.y + q0.y));
    e0.z = 1.0f / (1.0f + __expf(dtr * w0.z + q0.z));
    e0.w = 1.0f / (1.0f + __expf(dtr * w0.w + q0.w));
    e1.x = 1.0f / (1.0f + __expf(dtr * w1.x + q1.x));
    e1.y = 1.0f / (1.0f + __expf(dtr * w1.y + q1.y));
    e1.z = 1.0f / (1.0f + __expf(dtr * w1.z + q1.z));
    e1.w = 1.0f / (1.0f + __expf(dtr * w1.w + q1.w));
    *(float4*)(E + (size_t)row * DI + d0) = e0;
    *(float4*)(E + (size_t)row * DI + d0 + 4) = e1;
}

// ---------------- rdeg = 1/max(sum_{s<t} adj,1); flag[t] ----------------
__global__ void deg_k(const float* __restrict__ adj, float* __restrict__ rdeg, int* __restrict__ flagI) {
    int t = blockIdx.x & (S - 1), b = blockIdx.x >> 9;
    int lane = threadIdx.x;
    const float* row = adj + ((size_t)(b * S + t)) * S;
    float s = 0.0f; bool anyp = false;
    for (int i = lane; i < t; i += 64) { float v = row[i]; s += v; anyp |= (v > 0.0f); }
    for (int m = 1; m < 64; m <<= 1) s += __shfl_xor(s, m);
    bool any = __any(anyp);
    if (lane == 0) {
        rdeg[b * S + t] = 1.0f / fmaxf(s, 1.0f);
        if (t > 0 && any) atomicOr(flagI + t, 1);
    }
}

// ================= quad-chunk fused kernel (256 threads, 256 blocks) =================
#define SCAN32(RO, ADJT, GSUM)                                              \
    _Pragma("unroll")                                                       \
    for (int j = 0; j < CHUNK; ++j) {                                       \
        float e  = eL [((RO) + j) * 8 + grp];                               \
        float xa = xaL[((RO) + j) * 8 + grp];                               \
        float Bn = BnL[((RO) + j) * 16 + n];                                \
        h = h * e + xa * Bn;                                                \
        float g0 = GSUM[j], g1 = 0.f, g2 = 0.f, g3 = 0.f;                   \
        const float* ar = (ADJT) + j * 36;                                  \
        int sp = 0;                                                         \
        _Pragma("unroll")                                                   \
        for (; sp + 4 <= j; sp += 4) {                                      \
            float4 av = *(const float4*)(ar + sp);                          \
            g0 += av.x * hreg[sp];     g1 += av.y * hreg[sp + 1];           \
            g2 += av.z * hreg[sp + 2]; g3 += av.w * hreg[sp + 3];           \
        }                                                                   \
        _Pragma("unroll")                                                   \
        for (; sp < j; ++sp) g0 += ar[sp] * hreg[sp];                       \
        float gr = (g0 + g1) + (g2 + g3);                                   \
        float m0 = gr * wrr[0] + rork<4>(gr) * wrr[4]                       \
                 + rork<8>(gr) * wrr[8] + rork<12>(gr) * wrr[12];           \
        float m1 = rork<1>(gr) * wrr[1] + rork<5>(gr) * wrr[5]              \
                 + rork<9>(gr) * wrr[9] + rork<13>(gr) * wrr[13];           \
        float m2 = rork<2>(gr) * wrr[2] + rork<6>(gr) * wrr[6]              \
                 + rork<10>(gr) * wrr[10] + rork<14>(gr) * wrr[14];         \
        float m3 = rork<3>(gr) * wrr[3] + rork<7>(gr) * wrr[7]              \
                 + rork<11>(gr) * wrr[11] + rork<15>(gr) * wrr[15];         \
        float acc = fmaf(rdegL[(RO) + j], (m0 + m1) + (m2 + m3), brn);      \
        if (flL[(RO) + j])                                                  \
            h = fmaf(0.1f * acc,                                            \
                     __builtin_amdgcn_rcpf(1.0f + __expf(-acc)), h);        \
        hreg[j] = h;                                                        \
    }

#define PRESUM(GSUM, PTR) {                                                 \
    const ushort16* _p = (PTR);                                             \
    _Pragma("unroll")                                                       \
    for (int qi = 0; qi < 4; ++qi) {                                        \
        uint4 q = *(const uint4*)(_p + qi * 8);                             \
        GSUM[qi*8+0] += bflo(q.x); GSUM[qi*8+1] += bfhi(q.x);               \
        GSUM[qi*8+2] += bflo(q.y); GSUM[qi*8+3] += bfhi(q.y);               \
        GSUM[qi*8+4] += bflo(q.z); GSUM[qi*8+5] += bfhi(q.z);               \
        GSUM[qi*8+6] += bflo(q.w); GSUM[qi*8+7] += bfhi(q.w);               \
    } }

// hist write (global tiled + LDS hT buffer)
#define HWRITE(CIDX, HTBUF) {                                               \
    ushort16* ht = histT + htIdx(b, dn, (CIDX));                            \
    _Pragma("unroll")                                                       \
    for (int qi = 0; qi < 4; ++qi) {                                        \
        uint4 q;                                                            \
        q.x = pk2(hreg[qi*8+0], hreg[qi*8+1]);                              \
        q.y = pk2(hreg[qi*8+2], hreg[qi*8+3]);                              \
        q.z = pk2(hreg[qi*8+4], hreg[qi*8+5]);                              \
        q.w = pk2(hreg[qi*8+6], hreg[qi*8+7]);                              \
        *(uint4*)(ht + qi * 8) = q;                                         \
        *(uint4*)&(HTBUF)[qi * 1024 + tid * 8] = q;                         \
    } }

// mid phase: Gmid[j][col] = sum_{sidx<TCL} adj[target rows][src cols] x hT_src
#define MIDPHASE(TCL) {                                                     \
    int w = tid >> 6, l = tid & 63;                                         \
    int ksg = (l >> 4) * 8;                                                 \
    f32x4 ac0[4] = {}, ac1[4] = {};                                         \
    _Pragma("unroll")                                                       \
    for (int sidx = 0; sidx < (TCL); ++sidx) {                              \
        const float* p0 = adj + ((size_t)(b * S + c0s + (TCL) * 32 + (l & 15))) * S \
                        + c0s + sidx * 32 + ksg;                            \
        const float* p1 = p0 + 16 * S;                                      \
        float4 a00 = *(const float4*)p0, a01 = *(const float4*)(p0 + 4);    \
        float4 a10 = *(const float4*)p1, a11 = *(const float4*)(p1 + 4);    \
        uint4 qa, qb;                                                       \
        qa.x = pk2(a00.x, a00.y); qa.y = pk2(a00.z, a00.w);                 \
        qa.z = pk2(a01.x, a01.y); qa.w = pk2(a01.z, a01.w);                 \
        qb.x = pk2(a10.x, a10.y); qb.y = pk2(a10.z, a10.w);                 \
        qb.z = pk2(a11.x, a11.y); qb.w = pk2(a11.z, a11.w);                 \
        bf16x8 aF0, aF1;                                                    \
        *(uint4*)&aF0 = qa; *(uint4*)&aF1 = qb;                             \
        const short* hTs = hTarr[sidx];                                     \
        _Pragma("unroll")                                                   \
        for (int dblk = 0; dblk < 4; ++dblk) {                              \
            int col = w * 64 + dblk * 16 + (l & 15);                        \
            bf16x8 bF = *(const bf16x8*)&hTs[(l >> 4) * 1024 + col * 8];    \
            ac0[dblk] = __builtin_amdgcn_mfma_f32_16x16x32_bf16(aF0, bF, ac0[dblk], 0, 0, 0); \
            ac1[dblk] = __builtin_amdgcn_mfma_f32_16x16x32_bf16(aF1, bF, ac1[dblk], 0, 0, 0); \
        }                                                                   \
    }                                                                       \
    int jb0 = (l >> 4) * 4;                                                 \
    _Pragma("unroll")                                                       \
    for (int dblk = 0; dblk < 4; ++dblk) {                                  \
        int col = w * 64 + dblk * 16 + (l & 15);                            \
        _Pragma("unroll")                                                   \
        for (int reg = 0; reg < 4; ++reg) {                                 \
            Gmid[(jb0 + reg) * 136 + col]      = (short)f2bf(ac0[dblk][reg]); \
            Gmid[(16 + jb0 + reg) * 136 + col] = (short)f2bf(ac1[dblk][reg]); \
        }                                                                   \
    } }

#define GSADD(GSUM)                                                         \
    _Pragma("unroll")                                                       \
    for (int j = 0; j < CHUNK; ++j)                                         \
        GSUM[j] += bf2f((ushort16)Gmid[j * 136 + tid]);

__global__ __launch_bounds__(256) void chunk4_k(const float* __restrict__ adj,
                                                const float* __restrict__ x_act,
                                                const float* __restrict__ E,
                                                const float* __restrict__ Bm,
                                                const float* __restrict__ rdeg,
                                                const int* __restrict__ flagI,
                                                const float* __restrict__ Wr,
                                                const float* __restrict__ br,
                                                ushort16* __restrict__ Gall,
                                                ushort16* __restrict__ histT,
                                                float* __restrict__ hlast, int lc) {
    __shared__ __align__(16) char smem[51200];
    int tid = threadIdx.x;
    int c0 = 4 * lc;               // first chunk index this launch
    int c0s = c0 * CHUNK;          // its row offset
    const size_t SLOT = (size_t)B * DN * 32;
    int rp = lc & 1, wp = (lc + 1) & 1;

    if (blockIdx.x < 128) {
        // ---------------- scan role ----------------
        float* triA  = (float*)smem;                  // 4608
        float* triB  = (float*)(smem + 4608);         // 4608
        float* eL    = (float*)(smem + 9216);         // [64][8]
        float* xaL   = (float*)(smem + 11264);
        float* BnL   = (float*)(smem + 13312);        // [64][16]
        float* rdegL = (float*)(smem + 17408);        // [64]
        int*   flL   = (int*)  (smem + 17664);        // [64]
        short* hTA   = (short*)(smem + 17920);        // [4][128][8]
        short* hTB   = (short*)(smem + 26112);
        short* hTC   = (short*)(smem + 34304);
        short* Gmid  = (short*)(smem + 42496);        // [32][136] bf16 (overlay hTD)
        short* hTD   = (short*)(smem + 42496);

        int b = blockIdx.x >> 6;
        int d0 = (blockIdx.x & 63) << 3;
        int n = tid & 15, grp = (tid >> 4) & 7;
        int d = d0 + grp;
        int dn = d * N + n;
        int dnbase = (blockIdx.x & 63) << 7;
        const short* hTarr[4] = {hTA, hTB, hTC, hTD};

        // ---- stage1: chunks A,B ----
        {
            int j = tid >> 3, s4 = (tid & 7) * 4;
            {
                float4 a0 = *(const float4*)(adj + ((size_t)(b * S + c0s + j)) * S + c0s + s4);
                float* dp = triA + j * 36 + s4;
                dp[0] = a0.x; dp[1] = a0.y; dp[2] = a0.z; dp[3] = a0.w;
            }
            {
                float4 a0 = *(const float4*)(adj + ((size_t)(b * S + c0s + 32 + j)) * S + c0s + 32 + s4);
                float* dp = triB + j * 36 + s4;
                dp[0] = a0.x; dp[1] = a0.y; dp[2] = a0.z; dp[3] = a0.w;
            }
            int jr = tid >> 2, dd = (tid & 3) * 2;
            float2 ev = *(const float2*)(E     + ((size_t)(b * S + c0s + jr)) * DI + d0 + dd);
            float2 xv = *(const float2*)(x_act + ((size_t)(b * S + c0s + jr)) * DI + d0 + dd);
            eL [jr * 8 + dd] = ev.x; eL [jr * 8 + dd + 1] = ev.y;
            xaL[jr * 8 + dd] = xv.x; xaL[jr * 8 + dd + 1] = xv.y;
            int nn = (tid & 3) * 4;
            float4 bv = *(const float4*)(Bm + ((size_t)(b * S + c0s + jr)) * N + nn);
            BnL[jr * 16 + nn] = bv.x; BnL[jr * 16 + nn + 1] = bv.y;
            BnL[jr * 16 + nn + 2] = bv.z; BnL[jr * 16 + nn + 3] = bv.w;
            if (tid < 64) {
                rdegL[tid] = rdeg[b * S + c0s + tid];
                flL[tid]   = flagI[c0s + tid];
            }
        }
        __syncthreads();

        float gs0[CHUNK], gs1[CHUNK];
        float wrr[16];
        float brn = 0.f, h = 0.f;
        float hreg[CHUNK];

        if (tid < 128) {
            #pragma unroll
            for (int j = 0; j < CHUNK; ++j) { gs0[j] = 0.f; gs1[j] = 0.f; }
            size_t tb = ((size_t)b * DN + dn) * 32;
            if (lc >= 2) {
                PRESUM(gs0, Gall + ((size_t)rp * NSLOT + 0) * SLOT + tb);
                PRESUM(gs1, Gall + ((size_t)rp * NSLOT + 1) * SLOT + tb);
            }
            if (lc >= 1) {
                PRESUM(gs0, Gall + ((size_t)rp * NSLOT + 4) * SLOT + tb);
                PRESUM(gs1, Gall + ((size_t)rp * NSLOT + 5) * SLOT + tb);
            }
            int probe = __builtin_amdgcn_mov_dpp((int)n, 0x121, 0xf, 0xf, false);
            bool plusdir = (probe == ((n + 1) & 15));
            #pragma unroll
            for (int k = 0; k < 16; ++k) {
                int ip = (n + k) & 15, im = (n - k + 16) & 15;
                wrr[k] = Wr[n * 16 + (plusdir ? ip : im)];
            }
            brn = br[n];
            h = (lc == 0) ? 0.0f : hlast[b * DN + dn];

            SCAN32(0, triA, gs0)          // chunk A
            HWRITE(c0 + 0, hTA)
        }
        __syncthreads();
        if (tid < 128) MIDPHASE(1)        // B <- A
        __syncthreads();
        if (tid < 128) {
            GSADD(gs1)
            SCAN32(32, triB, gs1)         // chunk B
            HWRITE(c0 + 1, hTB)
        }
        __syncthreads();

        // ---- stage2: chunks C,D (restage) ----
        {
            int j = tid >> 3, s4 = (tid & 7) * 4;
            {
                float4 a0 = *(const float4*)(adj + ((size_t)(b * S + c0s + 64 + j)) * S + c0s + 64 + s4);
                float* dp = triA + j * 36 + s4;
                dp[0] = a0.x; dp[1] = a0.y; dp[2] = a0.z; dp[3] = a0.w;
            }
            {
                float4 a0 = *(const float4*)(adj + ((size_t)(b * S + c0s + 96 + j)) * S + c0s + 96 + s4);
                float* dp = triB + j * 36 + s4;
                dp[0] = a0.x; dp[1] = a0.y; dp[2] = a0.z; dp[3] = a0.w;
            }
            int jr = tid >> 2, dd = (tid & 3) * 2;
            float2 ev = *(const float2*)(E     + ((size_t)(b * S + c0s + 64 + jr)) * DI + d0 + dd);
            float2 xv = *(const float2*)(x_act + ((size_t)(b * S + c0s + 64 + jr)) * DI + d0 + dd);
            eL [jr * 8 + dd] = ev.x; eL [jr * 8 + dd + 1] = ev.y;
            xaL[jr * 8 + dd] = xv.x; xaL[jr * 8 + dd + 1] = xv.y;
            int nn = (tid & 3) * 4;
            float4 bv = *(const float4*)(Bm + ((size_t)(b * S + c0s + 64 + jr)) * N + nn);
            BnL[jr * 16 + nn] = bv.x; BnL[jr * 16 + nn + 1] = bv.y;
            BnL[jr * 16 + nn + 2] = bv.z; BnL[jr * 16 + nn + 3] = bv.w;
            if (tid < 64) {
                rdegL[tid] = rdeg[b * S + c0s + 64 + tid];
                flL[tid]   = flagI[c0s + 64 + tid];
            }
        }
        if (tid < 128) {
            #pragma unroll
            for (int j = 0; j < CHUNK; ++j) { gs0[j] = 0.f; gs1[j] = 0.f; }
            size_t tb = ((size_t)b * DN + dn) * 32;
            if (lc >= 2) {
                PRESUM(gs0, Gall + ((size_t)rp * NSLOT + 2) * SLOT + tb);
                PRESUM(gs1, Gall + ((size_t)rp * NSLOT + 3) * SLOT + tb);
            }
            if (lc >= 1) {
                PRESUM(gs0, Gall + ((size_t)rp * NSLOT + 6) * SLOT + tb);
                PRESUM(gs1, Gall + ((size_t)rp * NSLOT + 7) * SLOT + tb);
            }
        }
        __syncthreads();
        if (tid < 128) MIDPHASE(2)        // C <- {A,B}
        __syncthreads();
        if (tid < 128) {
            GSADD(gs0)
            SCAN32(0, triA, gs0)          // chunk C
            HWRITE(c0 + 2, hTC)
        }
        __syncthreads();
        if (tid < 128) MIDPHASE(3)        // D <- {A,B,C}
        __syncthreads();
        if (tid < 128) GSADD(gs1)
        __syncthreads();                  // Gmid reads done before hTD overlay write
        if (tid < 128) {
            SCAN32(32, triB, gs1)         // chunk D
            HWRITE(c0 + 3, hTD)
            hlast[b * DN + dn] = h;
        }
        __syncthreads();

        // ---- tails: accumulated over src -> 4 slots (all 256 threads) ----
        if (lc < NL2 - 1) {
            int half = tid >> 7;
            int lt = tid & 127;
            int w = lt >> 6, l = lt & 63;
            int ksg = (l >> 4) * 8;
            int jb0 = (l >> 4) * 4;
            #pragma unroll
            for (int tp = 0; tp < 2; ++tp) {
                int tgt = half * 2 + tp;
                f32x4 ac0[4] = {}, ac1[4] = {};
                #pragma unroll
                for (int src = 0; src < 4; ++src) {
                    const short* hTs = hTarr[src];
                    const float* p0 = adj + ((size_t)(b * S + (4 * (lc + 1) + tgt) * 32 + (l & 15))) * S
                                    + (4 * lc + src) * 32 + ksg;
                    const float* p1 = p0 + 16 * S;
                    float4 a00 = *(const float4*)p0, a01 = *(const float4*)(p0 + 4);
                    float4 a10 = *(const float4*)p1, a11 = *(const float4*)(p1 + 4);
                    uint4 qa, qb;
                    qa.x = pk2(a00.x, a00.y); qa.y = pk2(a00.z, a00.w);
                    qa.z = pk2(a01.x, a01.y); qa.w = pk2(a01.z, a01.w);
                    qb.x = pk2(a10.x, a10.y); qb.y = pk2(a10.z, a10.w);
                    qb.z = pk2(a11.x, a11.y); qb.w = pk2(a11.z, a11.w);
                    bf16x8 aF0, aF1;
                    *(uint4*)&aF0 = qa; *(uint4*)&aF1 = qb;
                    #pragma unroll
                    for (int dblk = 0; dblk < 4; ++dblk) {
                        int col = w * 64 + dblk * 16 + (l & 15);
                        bf16x8 bF = *(const bf16x8*)&hTs[(l >> 4) * 1024 + col * 8];
                        ac0[dblk] = __builtin_amdgcn_mfma_f32_16x16x32_bf16(aF0, bF, ac0[dblk], 0, 0, 0);
                        ac1[dblk] = __builtin_amdgcn_mfma_f32_16x16x32_bf16(aF1, bF, ac1[dblk], 0, 0, 0);
                    }
                }
                ushort16* gw = Gall + ((size_t)wp * NSLOT + (4 + tgt)) * SLOT;
                #pragma unroll
                for (int dblk = 0; dblk < 4; ++dblk) {
                    int col = w * 64 + dblk * 16 + (l & 15);
                    int dng = dnbase + col;
                    uint2 o0, o1;
                    o0.x = pk2(ac0[dblk][0], ac0[dblk][1]); o0.y = pk2(ac0[dblk][2], ac0[dblk][3]);
                    o1.x = pk2(ac1[dblk][0], ac1[dblk][1]); o1.y = pk2(ac1[dblk][2], ac1[dblk][3]);
                    *(uint2*)(gw + ((size_t)b * DN + dng) * 32 + jb0) = o0;
                    *(uint2*)(gw + ((size_t)b * DN + dng) * 32 + 16 + jb0) = o1;
                }
            }
        }
    } else {
        // -------- gpast role: 4 targets per block, histT read ONCE per fragment --------
        if (lc == 0 || lc >= NL2 - 1) return;
        int idx = blockIdx.x - 128;                // 0..127
        int tile = idx & 63;
        int b = idx >> 6;
        int dn0 = tile * 128;
        int w = tid >> 6, l = tid & 63;
        int jh = w & 1, dh = w >> 1;
        int ksg = (l >> 4) * 8;
        int dnrow = dn0 + dh * 64 + (l & 15);
        int K = 4 * lc;
        const float* abase0 = adj + ((size_t)(b * S + (4 * (lc + 1) + 0) * CHUNK + jh * 16 + (l & 15))) * S + ksg;
        const float* abase1 = abase0 + (size_t)CHUNK * S;
        const float* abase2 = abase1 + (size_t)CHUNK * S;
        const float* abase3 = abase2 + (size_t)CHUNK * S;
        f32x4 acc[4][4] = {};
        #pragma unroll 1
        for (int ks = 0; ks < K; ++ks) {
            bf16x8 bF[4];
            #pragma unroll
            for (int dblk = 0; dblk < 4; ++dblk) {
                uint4 bP = *(const uint4*)(histT + htIdx(b, dnrow + dblk * 16, ks) + ksg);
                *(uint4*)&bF[dblk] = bP;
            }
            #pragma unroll
            for (int tgt = 0; tgt < 4; ++tgt) {
                const float* ab = (tgt == 0) ? abase0 : (tgt == 1) ? abase1
                                : (tgt == 2) ? abase2 : abase3;
                float4 af0 = *(const float4*)(ab + ks * 32);
                float4 af1 = *(const float4*)(ab + ks * 32 + 4);
                uint4 aP;
                aP.x = pk2(af0.x, af0.y); aP.y = pk2(af0.z, af0.w);
                aP.z = pk2(af1.x, af1.y); aP.w = pk2(af1.z, af1.w);
                bf16x8 aF;
                *(uint4*)&aF = aP;
                #pragma unroll
                for (int dblk = 0; dblk < 4; ++dblk)
                    acc[tgt][dblk] = __builtin_amdgcn_mfma_f32_16x16x32_bf16(aF, bF[dblk], acc[tgt][dblk], 0, 0, 0);
            }
        }
        int jb = jh * 16 + (l >> 4) * 4;
        #pragma unroll
        for (int tgt = 0; tgt < 4; ++tgt) {
            ushort16* gbase = Gall + ((size_t)wp * NSLOT + tgt) * SLOT;
            #pragma unroll
            for (int dblk = 0; dblk < 4; ++dblk) {
                int dnc = dn0 + dh * 64 + dblk * 16 + (l & 15);
                uint2 o;
                o.x = pk2(acc[tgt][dblk][0], acc[tgt][dblk][1]);
                o.y = pk2(acc[tgt][dblk][2], acc[tgt][dblk][3]);
                *(uint2*)(gbase + ((size_t)b * DN + dnc) * 32 + jb) = o;
            }
        }
    }
}

// ---------------- y_k: y[b,t,d] = (sum_n histT[b][dn][t]*Cm[b,t,n]) * zs[b,t,d] -------
__global__ __launch_bounds__(256) void y_k(const ushort16* __restrict__ histT,
                                           const float* __restrict__ Cm,
                                           const float* __restrict__ zs,
                                           ushort16* __restrict__ yzb) {
    __shared__ float CmL[S * 17];
    int b = blockIdx.x >> 9;
    int d = blockIdx.x & (DI - 1);
    int tid = threadIdx.x;
    #pragma unroll
    for (int q = 0; q < 8; ++q) {
        int l0 = q * 1024 + tid * 4;
        int t = l0 >> 4, n0 = l0 & 15;
        float4 v = *(const float4*)(Cm + (size_t)b * S * N + l0);
        CmL[t * 17 + n0]     = v.x;
        CmL[t * 17 + n0 + 1] = v.y;
        CmL[t * 17 + n0 + 2] = v.z;
        CmL[t * 17 + n0 + 3] = v.w;
    }
    __syncthreads();
    #pragma unroll
    for (int pass = 0; pass < 2; ++pass) {
        int t = pass * 256 + tid;
        int sb = t >> 5, si = t & 31;
        const ushort16* hb = histT + htIdx(b, d * N, sb) + si;
        float a0 = 0.f, a1 = 0.f, a2 = 0.f, a3 = 0.f;
        #pragma unroll
        for (int n = 0; n < 16; n += 4) {
            a0 += bf2f(hb[(size_t)n * 32])       * CmL[t * 17 + n];
            a1 += bf2f(hb[(size_t)(n + 1) * 32]) * CmL[t * 17 + n + 1];
            a2 += bf2f(hb[(size_t)(n + 2) * 32]) * CmL[t * 17 + n + 2];
            a3 += bf2f(hb[(size_t)(n + 3) * 32]) * CmL[t * 17 + n + 3];
        }
        float acc = (a0 + a1) + (a2 + a3);
        float zv = zs[((size_t)(b * S + t)) * DI + d];
        yzb[((size_t)(b * S + t)) * DI + d] = f2bf(acc * zv);
    }
}

// ---------------- launch ----------------
extern "C" void kernel_launch(void* const* d_in, const int* in_sizes, int n_in,
                              void* d_out, int out_size, void* d_ws, size_t ws_size,
                              hipStream_t stream) {
    const float* x      = (const float*)d_in[0];
    const float* adj    = (const float*)d_in[1];
    const float* ln_w   = (const float*)d_in[2];
    const float* ln_b   = (const float*)d_in[3];
    const float* W_in   = (const float*)d_in[4];
    const float* conv_w = (const float*)d_in[5];
    const float* conv_b = (const float*)d_in[6];
    const float* W_xp   = (const float*)d_in[7];
    const float* W_dt   = (const float*)d_in[8];
    const float* b_dt   = (const float*)d_in[9];
    const float* Wr     = (const float*)d_in[10];
    const float* br     = (const float*)d_in[11];
    const float* W_out  = (const float*)d_in[12];
    float* out = (float*)d_out;

    float* ws = (float*)d_ws;
    size_t off = 0;
    float* x_act  = ws + off; off += (size_t)B * S * DI;
    float* Bmb    = ws + off; off += (size_t)B * S * N;
    float* Cmb    = ws + off; off += (size_t)B * S * N;
    float* rdegp  = ws + off; off += (size_t)B * S;
    int*   flagI  = (int*)(ws + off); off += S;
    float* Ebuf   = ws + off; off += (size_t)B * S * DI;
    float* zsbuf  = ws + off; off += (size_t)B * S * DI;
    float* hlast  = ws + off; off += (size_t)B * DN;
    ushort16* xnb    = (ushort16*)(ws + off); off += (size_t)B * S * D / 2;
    ushort16* yzb    = (ushort16*)(ws + off); off += (size_t)B * S * DI / 2;
    ushort16* histT  = (ushort16*)(ws + off); off += (size_t)B * DN * S / 2;
    ushort16* Gall   = (ushort16*)(ws + off); off += (size_t)2 * NSLOT * B * DN * 32 / 2;
    ushort16* xpb    = (ushort16*)(ws + off); off += (size_t)B * (S + 3) * DI / 2;

    hipMemsetAsync(flagI, 0, S * sizeof(int), stream);
    hipMemsetAsync(xpb, 0, (size_t)B * (S + 3) * DI * 2, stream);

    ln_k<<<B * S, 64, 0, stream>>>(x, ln_w, ln_b, xnb);
    gemmb_k<1><<<dim3(2 * DI / 64, B * S / 64), 256, 0, stream>>>(
        xnb, W_in, nullptr, nullptr, xpb, zsbuf, B * S, 2 * DI, D);
    convm_k<<<dim3(DI / 32, B * S / 32), 256, 0, stream>>>(xpb, conv_w, conv_b, x_act);
    ssmE_k<<<B * S / 4, 256, 0, stream>>>(x_act, W_xp, W_dt, b_dt, Bmb, Cmb, Ebuf);
    deg_k<<<B * S, 64, 0, stream>>>(adj, rdegp, flagI);

    for (int lc = 0; lc < NL2; ++lc)
        chunk4_k<<<256, 256, 0, stream>>>(adj, x_act, Ebuf, Bmb, rdegp, flagI,
                                          Wr, br, Gall, histT, hlast, lc);

    y_k<<<B * DI, 256, 0, stream>>>(histT, Cmb, zsbuf, yzb);

    gemmb_k<0><<<dim3(D / 64, B * S / 64), 256, 0, stream>>>(
        yzb, W_out, x, out, nullptr, nullptr, B * S, D, DI);
}

// Round 19
// 256.898 us; speedup vs baseline: 1.2639x; 1.0091x over previous
//
#include <hip/hip_runtime.h>
#include <math.h>

// Problem constants
static constexpr int B  = 2;
static constexpr int S  = 512;
static constexpr int D  = 256;
static constexpr int N  = 16;
static constexpr int DI = 512;
static constexpr int CHUNK = 32;
static constexpr int NCHUNK = S / CHUNK;   // 16
static constexpr int NL2 = 4;              // 4 launches, 4 chunks each
static constexpr int DN = DI * N;          // 8192
static constexpr int NSLOT = 8;            // 4 gold (tgt) + 4 tails (4+tgt)

typedef unsigned int uint32;
typedef unsigned short ushort16;
using bf16x8 = __attribute__((ext_vector_type(8))) short;
using f32x4  = __attribute__((ext_vector_type(4))) float;

__device__ __forceinline__ ushort16 f2bf(float f) {
    uint32 u = __float_as_uint(f);
    u = (u + 0x7fffu + ((u >> 16) & 1u)) >> 16;   // RNE
    return (ushort16)u;
}
__device__ __forceinline__ float bflo(uint32 u) { return __uint_as_float(u << 16); }
__device__ __forceinline__ float bfhi(uint32 u) { return __uint_as_float(u & 0xffff0000u); }
__device__ __forceinline__ float bf2f(ushort16 u) { return __uint_as_float(((uint32)u) << 16); }
__device__ __forceinline__ uint32 pk2(float a, float b) {
    return (uint32)(ushort16)f2bf(a) | ((uint32)(ushort16)f2bf(b) << 16);
}
// DPP row-rotate within 16-lane rows (VALU pipe, no LDS)
template<int K>
__device__ __forceinline__ float rork(float x) {
    return __uint_as_float((uint32)__builtin_amdgcn_mov_dpp(
        (int)__float_as_uint(x), 0x120 + K, 0xf, 0xf, false));
}
// histT tiled layout: elem (b, dn, s) -> ((b*(S/32) + s/32)*DN + dn)*32 + s%32
__device__ __forceinline__ size_t htIdx(int b, int dn, int sb) {
    return ((size_t)(b * (S / 32) + sb) * DN + dn) * 32;
}

// ---------------- LayerNorm: one wave per row, bf16 output ----------------
__global__ void ln_k(const float* __restrict__ x, const float* __restrict__ w,
                     const float* __restrict__ bias, ushort16* __restrict__ xnb) {
    int row = blockIdx.x;
    int lane = threadIdx.x;
    float4 v = *(const float4*)(x + row * D + lane * 4);
    float s = v.x + v.y + v.z + v.w;
    float q = v.x * v.x + v.y * v.y + v.z * v.z + v.w * v.w;
    for (int m = 1; m < 64; m <<= 1) { s += __shfl_xor(s, m); q += __shfl_xor(q, m); }
    float mu  = s * (1.0f / D);
    float var = q * (1.0f / D) - mu * mu;
    float rs  = rsqrtf(var + 1e-5f);
    float4 wv = *(const float4*)(w + lane * 4);
    float4 bv = *(const float4*)(bias + lane * 4);
    float4 o;
    o.x = (v.x - mu) * rs * wv.x + bv.x;
    o.y = (v.y - mu) * rs * wv.y + bv.y;
    o.z = (v.z - mu) * rs * wv.z + bv.z;
    o.w = (v.w - mu) * rs * wv.w + bv.w;
    uint2 pk;
    pk.x = pk2(o.x, o.y);
    pk.y = pk2(o.z, o.w);
    *(uint2*)(xnb + row * D + lane * 4) = pk;
}

// ------- bf16 MFMA GEMM, W in f32 (converted during staging) -------
template<int MODE>
__global__ __launch_bounds__(256) void gemmb_k(const ushort16* __restrict__ A,
                                               const float* __restrict__ W,
                                               const float* __restrict__ res,
                                               float* __restrict__ C,
                                               ushort16* __restrict__ xpb,
                                               float* __restrict__ zs,
                                               int M, int Nc, int K) {
    __shared__ __align__(16) short As[64 * 40];
    __shared__ __align__(16) short Ws[64 * 40];
    int tid = threadIdx.x;
    int l = tid & 63, wid = tid >> 6;
    int wm = wid & 1, wn = wid >> 1;
    int row0 = blockIdx.y * 64, col0 = blockIdx.x * 64;
    int r = tid >> 2, kseg = (tid & 3) * 8;
    f32x4 acc[2][2] = {};
    for (int k0 = 0; k0 < K; k0 += 32) {
        *(uint4*)&As[r * 40 + kseg] = *(const uint4*)(A + (size_t)(row0 + r) * K + k0 + kseg);
        {
            const float* wrow = W + (size_t)(col0 + r) * K + k0 + kseg;
            float4 w0 = *(const float4*)wrow;
            float4 w1 = *(const float4*)(wrow + 4);
            uint4 q;
            q.x = pk2(w0.x, w0.y); q.y = pk2(w0.z, w0.w);
            q.z = pk2(w1.x, w1.y); q.w = pk2(w1.z, w1.w);
            *(uint4*)&Ws[r * 40 + kseg] = q;
        }
        __syncthreads();
        bf16x8 aF[2], bF[2];
        #pragma unroll
        for (int am = 0; am < 2; ++am)
            aF[am] = *(const bf16x8*)&As[(wm * 32 + am * 16 + (l & 15)) * 40 + (l >> 4) * 8];
        #pragma unroll
        for (int bn = 0; bn < 2; ++bn)
            bF[bn] = *(const bf16x8*)&Ws[(wn * 32 + bn * 16 + (l & 15)) * 40 + (l >> 4) * 8];
        #pragma unroll
        for (int am = 0; am < 2; ++am)
            #pragma unroll
            for (int bn = 0; bn < 2; ++bn)
                acc[am][bn] = __builtin_amdgcn_mfma_f32_16x16x32_bf16(aF[am], bF[bn], acc[am][bn], 0, 0, 0);
        __syncthreads();
    }
    #pragma unroll
    for (int am = 0; am < 2; ++am)
        #pragma unroll
        for (int bn = 0; bn < 2; ++bn) {
            int cc = col0 + wn * 32 + bn * 16 + (l & 15);
            #pragma unroll
            for (int reg = 0; reg < 4; ++reg) {
                int rr = row0 + wm * 32 + am * 16 + (l >> 4) * 4 + reg;
                float v = acc[am][bn][reg];
                if (MODE == 0) {
                    if (res) v += res[(size_t)rr * Nc + cc];
                    C[(size_t)rr * Nc + cc] = v;
                } else {
                    int b = rr >> 9, t = rr & (S - 1);
                    if (cc < DI)
                        xpb[((size_t)(b * (S + 3) + 3 + t)) * DI + cc] = f2bf(v);
                    else
                        zs[((size_t)(b * S + t)) * DI + (cc - DI)] = v / (1.0f + __expf(-v));
                }
            }
        }
}

// ---------------- Causal conv via bf16 MFMA + bias + silu ----------------
__global__ __launch_bounds__(256) void convm_k(const ushort16* __restrict__ xpb,
                                               const float* __restrict__ conv_w,
                                               const float* __restrict__ conv_b,
                                               float* __restrict__ x_act) {
    __shared__ __align__(16) short AxS[35 * 40];
    __shared__ __align__(16) short WbS[4 * 32 * 40];
    int tid = threadIdx.x;
    int l = tid & 63, wid = tid >> 6;
    int wm = wid & 1, wn = wid >> 1;
    int o0 = blockIdx.x * 32;
    int mt = blockIdx.y;
    int b = mt >> 4, tl0 = (mt & 15) * 32;
    f32x4 acc = {0.f, 0.f, 0.f, 0.f};

    for (int k0 = 0; k0 < DI; k0 += 32) {
        if (tid < 140) {
            int rr = tid >> 2, seg = tid & 3;
            uint4 v = *(const uint4*)(xpb + ((size_t)(b * (S + 3) + tl0 + rr)) * DI + k0 + seg * 8);
            *(uint4*)&AxS[rr * 40 + seg * 8] = v;
        }
        #pragma unroll
        for (int it = 0; it < 4; ++it) {
            int p = it * 256 + tid;
            int o = p >> 5, i = p & 31;
            float4 w4 = *(const float4*)(conv_w + ((size_t)(o0 + o) * DI + (k0 + i)) * 4);
            WbS[(0 * 32 + o) * 40 + i] = (short)f2bf(w4.x);
            WbS[(1 * 32 + o) * 40 + i] = (short)f2bf(w4.y);
            WbS[(2 * 32 + o) * 40 + i] = (short)f2bf(w4.z);
            WbS[(3 * 32 + o) * 40 + i] = (short)f2bf(w4.w);
        }
        __syncthreads();
        #pragma unroll
        for (int k = 0; k < 4; ++k) {
            bf16x8 aF = *(const bf16x8*)&AxS[(wm * 16 + (l & 15) + k) * 40 + (l >> 4) * 8];
            bf16x8 bF = *(const bf16x8*)&WbS[(k * 32 + wn * 16 + (l & 15)) * 40 + (l >> 4) * 8];
            acc = __builtin_amdgcn_mfma_f32_16x16x32_bf16(aF, bF, acc, 0, 0, 0);
        }
        __syncthreads();
    }
    int oc = o0 + wn * 16 + (l & 15);
    float bia = conv_b[oc];
    #pragma unroll
    for (int reg = 0; reg < 4; ++reg) {
        int m = wm * 16 + (l >> 4) * 4 + reg;
        float v = acc[reg] + bia;
        x_act[((size_t)(b * S + tl0 + m)) * DI + oc] = v / (1.0f + __expf(-v));
    }
}

// ------- ssm (33 outputs) + E epilogue -------
__global__ void ssmE_k(const float* __restrict__ x_act, const float* __restrict__ W_xp,
                       const float* __restrict__ W_dt, const float* __restrict__ b_dt,
                       float* __restrict__ Bm, float* __restrict__ Cm,
                       float* __restrict__ E) {
    int row = blockIdx.x * 4 + (threadIdx.x >> 6);
    int lane = threadIdx.x & 63;
    const float* xr = x_act + (size_t)row * DI + lane * 8;
    float4 v0 = *(const float4*)xr;
    float4 v1 = *(const float4*)(xr + 4);
    float dtr = 0.0f;
    for (int j = 0; j < 2 * N + 1; ++j) {
        const float* wr = W_xp + (size_t)j * DI + lane * 8;
        float4 w0 = *(const float4*)wr;
        float4 w1 = *(const float4*)(wr + 4);
        float acc = v0.x * w0.x + v0.y * w0.y + v0.z * w0.z + v0.w * w0.w
                  + v1.x * w1.x + v1.y * w1.y + v1.z * w1.z + v1.w * w1.w;
        for (int m = 1; m < 64; m <<= 1) acc += __shfl_xor(acc, m);
        if (j == 0) dtr = acc;
        if (lane == 0) {
            if (j >= 1 && j < 1 + N) Bm[(size_t)row * N + (j - 1)] = acc;
            else if (j >= 1 + N)     Cm[(size_t)row * N + (j - 1 - N)] = acc;
        }
    }
    int d0 = lane * 8;
    float4 w0 = *(const float4*)(W_dt + d0);
    float4 w1 = *(const float4*)(W_dt + d0 + 4);
    float4 q0 = *(const float4*)(b_dt + d0);
    float4 q1 = *(const float4*)(b_dt + d0 + 4);
    float4 e0, e1;
    e0.x = 1.0f / (1.0f + __expf(dtr * w0.x + q0.x));
    e0.y = 1.0f / (1.0f + __expf(dtr * w0.y + q0.y));
    e0.z = 1.0f / (1.0f + __expf(dtr * w0.z + q0.z));
    e0.w = 1.0f / (1.0f + __expf(dtr * w0.w + q0.w));
    e1.x = 1.0f / (1.0f + __expf(dtr * w1.x + q1.x));
    e1.y = 1.0f / (1.0f + __expf(dtr * w1.y + q1.y));
    e1.z = 1.0f / (1.0f + __expf(dtr * w1.z + q1.z));
    e1.w = 1.0f / (1.0f + __expf(dtr * w1.w + q1.w));
    *(float4*)(E + (size_t)row * DI + d0) = e0;
    *(float4*)(E + (size_t)row * DI + d0 + 4) = e1;
}

// ---------------- rdeg = 1/max(sum_{s<t} adj,1); flag[t] ----------------
__global__ void deg_k(const float* __restrict__ adj, float* __restrict__ rdeg, int* __restrict__ flagI) {
    int t = blockIdx.x & (S - 1), b = blockIdx.x >> 9;
    int lane = threadIdx.x;
    const float* row = adj + ((size_t)(b * S + t)) * S;
    float s = 0.0f; bool anyp = false;
    for (int i = lane; i < t; i += 64) { float v = row[i]; s += v; anyp |= (v > 0.0f); }
    for (int m = 1; m < 64; m <<= 1) s += __shfl_xor(s, m);
    bool any = __any(anyp);
    if (lane == 0) {
        rdeg[b * S + t] = 1.0f / fmaxf(s, 1.0f);
        if (t > 0 && any) atomicOr(flagI + t, 1);
    }
}

// ================= quad-chunk fused kernel (256 threads, 256 blocks) =================
// Operand-set arguments let scan phases read set1 (A,B) or set2 (C,D); set2 is
// staged by the idle half-block (tid>=128) concurrently with scan A/B.
#define SCAN32(RO, ADJT, GSUM, EL, XAL, BNL, RDEGL, FLL)                    \
    _Pragma("unroll")                                                       \
    for (int j = 0; j < CHUNK; ++j) {                                       \
        float e  = (EL) [((RO) + j) * 8 + grp];                             \
        float xa = (XAL)[((RO) + j) * 8 + grp];                             \
        float Bn = (BNL)[((RO) + j) * 16 + n];                              \
        h = h * e + xa * Bn;                                                \
        float g0 = GSUM[j], g1 = 0.f, g2 = 0.f, g3 = 0.f;                   \
        const float* ar = (ADJT) + j * 36;                                  \
        int sp = 0;                                                         \
        _Pragma("unroll")                                                   \
        for (; sp + 4 <= j; sp += 4) {                                      \
            float4 av = *(const float4*)(ar + sp);                          \
            g0 += av.x * hreg[sp];     g1 += av.y * hreg[sp + 1];           \
            g2 += av.z * hreg[sp + 2]; g3 += av.w * hreg[sp + 3];           \
        }                                                                   \
        _Pragma("unroll")                                                   \
        for (; sp < j; ++sp) g0 += ar[sp] * hreg[sp];                       \
        float gr = (g0 + g1) + (g2 + g3);                                   \
        float m0 = gr * wrr[0] + rork<4>(gr) * wrr[4]                       \
                 + rork<8>(gr) * wrr[8] + rork<12>(gr) * wrr[12];           \
        float m1 = rork<1>(gr) * wrr[1] + rork<5>(gr) * wrr[5]              \
                 + rork<9>(gr) * wrr[9] + rork<13>(gr) * wrr[13];           \
        float m2 = rork<2>(gr) * wrr[2] + rork<6>(gr) * wrr[6]              \
                 + rork<10>(gr) * wrr[10] + rork<14>(gr) * wrr[14];         \
        float m3 = rork<3>(gr) * wrr[3] + rork<7>(gr) * wrr[7]              \
                 + rork<11>(gr) * wrr[11] + rork<15>(gr) * wrr[15];         \
        float acc = fmaf((RDEGL)[(RO) + j], (m0 + m1) + (m2 + m3), brn);    \
        if ((FLL)[(RO) + j])                                                \
            h = fmaf(0.1f * acc,                                            \
                     __builtin_amdgcn_rcpf(1.0f + __expf(-acc)), h);        \
        hreg[j] = h;                                                        \
    }

#define PRESUM(GSUM, PTR) {                                                 \
    const ushort16* _p = (PTR);                                             \
    _Pragma("unroll")                                                       \
    for (int qi = 0; qi < 4; ++qi) {                                        \
        uint4 q = *(const uint4*)(_p + qi * 8);                             \
        GSUM[qi*8+0] += bflo(q.x); GSUM[qi*8+1] += bfhi(q.x);               \
        GSUM[qi*8+2] += bflo(q.y); GSUM[qi*8+3] += bfhi(q.y);               \
        GSUM[qi*8+4] += bflo(q.z); GSUM[qi*8+5] += bfhi(q.z);               \
        GSUM[qi*8+6] += bflo(q.w); GSUM[qi*8+7] += bfhi(q.w);               \
    } }

// hist write (global tiled + LDS hT buffer)
#define HWRITE(CIDX, HTBUF) {                                               \
    ushort16* ht = histT + htIdx(b, dn, (CIDX));                            \
    _Pragma("unroll")                                                       \
    for (int qi = 0; qi < 4; ++qi) {                                        \
        uint4 q;                                                            \
        q.x = pk2(hreg[qi*8+0], hreg[qi*8+1]);                              \
        q.y = pk2(hreg[qi*8+2], hreg[qi*8+3]);                              \
        q.z = pk2(hreg[qi*8+4], hreg[qi*8+5]);                              \
        q.w = pk2(hreg[qi*8+6], hreg[qi*8+7]);                              \
        *(uint4*)(ht + qi * 8) = q;                                         \
        *(uint4*)&(HTBUF)[qi * 1024 + tid * 8] = q;                         \
    } }

// mid phase: Gmid[j][col] = sum_{sidx<TCL} adj[target rows][src cols] x hT_src
#define MIDPHASE(TCL) {                                                     \
    int w = tid >> 6, l = tid & 63;                                         \
    int ksg = (l >> 4) * 8;                                                 \
    f32x4 ac0[4] = {}, ac1[4] = {};                                         \
    _Pragma("unroll")                                                       \
    for (int sidx = 0; sidx < (TCL); ++sidx) {                              \
        const float* p0 = adj + ((size_t)(b * S + c0s + (TCL) * 32 + (l & 15))) * S \
                        + c0s + sidx * 32 + ksg;                            \
        const float* p1 = p0 + 16 * S;                                      \
        float4 a00 = *(const float4*)p0, a01 = *(const float4*)(p0 + 4);    \
        float4 a10 = *(const float4*)p1, a11 = *(const float4*)(p1 + 4);    \
        uint4 qa, qb;                                                       \
        qa.x = pk2(a00.x, a00.y); qa.y = pk2(a00.z, a00.w);                 \
        qa.z = pk2(a01.x, a01.y); qa.w = pk2(a01.z, a01.w);                 \
        qb.x = pk2(a10.x, a10.y); qb.y = pk2(a10.z, a10.w);                 \
        qb.z = pk2(a11.x, a11.y); qb.w = pk2(a11.z, a11.w);                 \
        bf16x8 aF0, aF1;                                                    \
        *(uint4*)&aF0 = qa; *(uint4*)&aF1 = qb;                             \
        const short* hTs = hTarr[sidx];                                     \
        _Pragma("unroll")                                                   \
        for (int dblk = 0; dblk < 4; ++dblk) {                              \
            int col = w * 64 + dblk * 16 + (l & 15);                        \
            bf16x8 bF = *(const bf16x8*)&hTs[(l >> 4) * 1024 + col * 8];    \
            ac0[dblk] = __builtin_amdgcn_mfma_f32_16x16x32_bf16(aF0, bF, ac0[dblk], 0, 0, 0); \
            ac1[dblk] = __builtin_amdgcn_mfma_f32_16x16x32_bf16(aF1, bF, ac1[dblk], 0, 0, 0); \
        }                                                                   \
    }                                                                       \
    int jb0 = (l >> 4) * 4;                                                 \
    _Pragma("unroll")                                                       \
    for (int dblk = 0; dblk < 4; ++dblk) {                                  \
        int col = w * 64 + dblk * 16 + (l & 15);                            \
        _Pragma("unroll")                                                   \
        for (int reg = 0; reg < 4; ++reg) {                                 \
            Gmid[(jb0 + reg) * 136 + col]      = (short)f2bf(ac0[dblk][reg]); \
            Gmid[(16 + jb0 + reg) * 136 + col] = (short)f2bf(ac1[dblk][reg]); \
        }                                                                   \
    } }

#define GSADD(GSUM)                                                         \
    _Pragma("unroll")                                                       \
    for (int j = 0; j < CHUNK; ++j)                                         \
        GSUM[j] += bf2f((ushort16)Gmid[j * 136 + tid]);

// staging of one 2-chunk operand set by thread index T (0..255) at rows c0s+OFS
#define STAGEOPS(T, OFS, TRI0, TRI1, EL, XAL, BNL, RDEGL, FLL) {            \
    int j = (T) >> 3, s4 = ((T) & 7) * 4;                                   \
    {                                                                       \
        float4 a0 = *(const float4*)(adj + ((size_t)(b * S + c0s + (OFS) + j)) * S + c0s + (OFS) + s4); \
        float* dp = (TRI0) + j * 36 + s4;                                   \
        dp[0] = a0.x; dp[1] = a0.y; dp[2] = a0.z; dp[3] = a0.w;             \
    }                                                                       \
    {                                                                       \
        float4 a0 = *(const float4*)(adj + ((size_t)(b * S + c0s + (OFS) + 32 + j)) * S + c0s + (OFS) + 32 + s4); \
        float* dp = (TRI1) + j * 36 + s4;                                   \
        dp[0] = a0.x; dp[1] = a0.y; dp[2] = a0.z; dp[3] = a0.w;             \
    }                                                                       \
    int jr = (T) >> 2, dd = ((T) & 3) * 2;                                  \
    float2 ev = *(const float2*)(E     + ((size_t)(b * S + c0s + (OFS) + jr)) * DI + d0 + dd); \
    float2 xv = *(const float2*)(x_act + ((size_t)(b * S + c0s + (OFS) + jr)) * DI + d0 + dd); \
    (EL) [jr * 8 + dd] = ev.x; (EL) [jr * 8 + dd + 1] = ev.y;               \
    (XAL)[jr * 8 + dd] = xv.x; (XAL)[jr * 8 + dd + 1] = xv.y;               \
    int nn = ((T) & 3) * 4;                                                 \
    float4 bv = *(const float4*)(Bm + ((size_t)(b * S + c0s + (OFS) + jr)) * N + nn); \
    (BNL)[jr * 16 + nn] = bv.x; (BNL)[jr * 16 + nn + 1] = bv.y;             \
    (BNL)[jr * 16 + nn + 2] = bv.z; (BNL)[jr * 16 + nn + 3] = bv.w;         \
    if ((T) < 64) {                                                         \
        (RDEGL)[(T)] = rdeg[b * S + c0s + (OFS) + (T)];                     \
        (FLL)[(T)]   = flagI[c0s + (OFS) + (T)];                            \
    } }

__global__ __launch_bounds__(256) void chunk4_k(const float* __restrict__ adj,
                                                const float* __restrict__ x_act,
                                                const float* __restrict__ E,
                                                const float* __restrict__ Bm,
                                                const float* __restrict__ rdeg,
                                                const int* __restrict__ flagI,
                                                const float* __restrict__ Wr,
                                                const float* __restrict__ br,
                                                ushort16* __restrict__ Gall,
                                                ushort16* __restrict__ histT,
                                                float* __restrict__ hlast, int lc) {
    __shared__ __align__(16) char smem[69120];
    int tid = threadIdx.x;
    int c0 = 4 * lc;
    int c0s = c0 * CHUNK;
    const size_t SLOT = (size_t)B * DN * 32;
    int rp = lc & 1, wp = (lc + 1) & 1;

    if (blockIdx.x < 128) {
        // ---------------- scan role ----------------
        float* triA   = (float*)smem;                  // set1
        float* triB   = (float*)(smem + 4608);
        float* eLa    = (float*)(smem + 9216);
        float* xaLa   = (float*)(smem + 11264);
        float* BnLa   = (float*)(smem + 13312);
        float* rdegLa = (float*)(smem + 17408);
        int*   flLa   = (int*)  (smem + 17664);
        float* triC   = (float*)(smem + 17920);        // set2
        float* triD   = (float*)(smem + 22528);
        float* eLb    = (float*)(smem + 27136);
        float* xaLb   = (float*)(smem + 29184);
        float* BnLb   = (float*)(smem + 31232);
        float* rdegLb = (float*)(smem + 35328);
        int*   flLb   = (int*)  (smem + 35584);
        short* hTA    = (short*)(smem + 35840);
        short* hTB    = (short*)(smem + 44032);
        short* hTC    = (short*)(smem + 52224);
        short* Gmid   = (short*)(smem + 60416);        // overlay hTD
        short* hTD    = (short*)(smem + 60416);

        int b = blockIdx.x >> 6;
        int d0 = (blockIdx.x & 63) << 3;
        int n = tid & 15, grp = (tid >> 4) & 7;
        int d = d0 + grp;
        int dn = d * N + n;
        int dnbase = (blockIdx.x & 63) << 7;
        const short* hTarr[4] = {hTA, hTB, hTC, hTD};

        // ---- phase 1: stage set1 (A,B) by all 256 ----
        STAGEOPS(tid, 0, triA, triB, eLa, xaLa, BnLa, rdegLa, flLa)
        __syncthreads();

        float gs0[CHUNK], gs1[CHUNK];
        float wrr[16];
        float brn = 0.f, h = 0.f;
        float hreg[CHUNK];

        // ---- phase 2: scan A (tid<128)  ||  stage set2 (tid>=128) ----
        if (tid < 128) {
            #pragma unroll
            for (int j = 0; j < CHUNK; ++j) { gs0[j] = 0.f; gs1[j] = 0.f; }
            size_t tb = ((size_t)b * DN + dn) * 32;
            if (lc >= 2) {
                PRESUM(gs0, Gall + ((size_t)rp * NSLOT + 0) * SLOT + tb);
                PRESUM(gs1, Gall + ((size_t)rp * NSLOT + 1) * SLOT + tb);
            }
            if (lc >= 1) {
                PRESUM(gs0, Gall + ((size_t)rp * NSLOT + 4) * SLOT + tb);
                PRESUM(gs1, Gall + ((size_t)rp * NSLOT + 5) * SLOT + tb);
            }
            int probe = __builtin_amdgcn_mov_dpp((int)n, 0x121, 0xf, 0xf, false);
            bool plusdir = (probe == ((n + 1) & 15));
            #pragma unroll
            for (int k = 0; k < 16; ++k) {
                int ip = (n + k) & 15, im = (n - k + 16) & 15;
                wrr[k] = Wr[n * 16 + (plusdir ? ip : im)];
            }
            brn = br[n];
            h = (lc == 0) ? 0.0f : hlast[b * DN + dn];

            SCAN32(0, triA, gs0, eLa, xaLa, BnLa, rdegLa, flLa)   // chunk A
            HWRITE(c0 + 0, hTA)
        } else {
            #pragma unroll
            for (int rep = 0; rep < 2; ++rep) {
                int t2 = ((tid - 128) << 1) | rep;
                STAGEOPS(t2, 64, triC, triD, eLb, xaLb, BnLb, rdegLb, flLb)
            }
        }
        __syncthreads();
        if (tid < 128) MIDPHASE(1)        // B <- A
        __syncthreads();
        if (tid < 128) {
            GSADD(gs1)
            SCAN32(32, triB, gs1, eLa, xaLa, BnLa, rdegLa, flLa)  // chunk B
            HWRITE(c0 + 1, hTB)
        }
        __syncthreads();

        // ---- second pair: presum C/D + mid C ----
        if (tid < 128) {
            #pragma unroll
            for (int j = 0; j < CHUNK; ++j) { gs0[j] = 0.f; gs1[j] = 0.f; }
            size_t tb = ((size_t)b * DN + dn) * 32;
            if (lc >= 2) {
                PRESUM(gs0, Gall + ((size_t)rp * NSLOT + 2) * SLOT + tb);
                PRESUM(gs1, Gall + ((size_t)rp * NSLOT + 3) * SLOT + tb);
            }
            if (lc >= 1) {
                PRESUM(gs0, Gall + ((size_t)rp * NSLOT + 6) * SLOT + tb);
                PRESUM(gs1, Gall + ((size_t)rp * NSLOT + 7) * SLOT + tb);
            }
            MIDPHASE(2)                   // C <- {A,B}
        }
        __syncthreads();
        if (tid < 128) {
            GSADD(gs0)
            SCAN32(0, triC, gs0, eLb, xaLb, BnLb, rdegLb, flLb)   // chunk C
            HWRITE(c0 + 2, hTC)
        }
        __syncthreads();
        if (tid < 128) MIDPHASE(3)        // D <- {A,B,C}
        __syncthreads();
        if (tid < 128) GSADD(gs1)
        __syncthreads();                  // Gmid reads done before hTD overlay write
        if (tid < 128) {
            SCAN32(32, triD, gs1, eLb, xaLb, BnLb, rdegLb, flLb)  // chunk D
            HWRITE(c0 + 3, hTD)
            hlast[b * DN + dn] = h;
        }
        __syncthreads();

        // ---- tails: accumulated over src -> 4 slots (all 256 threads) ----
        if (lc < NL2 - 1) {
            int half = tid >> 7;
            int lt = tid & 127;
            int w = lt >> 6, l = lt & 63;
            int ksg = (l >> 4) * 8;
            int jb0 = (l >> 4) * 4;
            #pragma unroll
            for (int tp = 0; tp < 2; ++tp) {
                int tgt = half * 2 + tp;
                f32x4 ac0[4] = {}, ac1[4] = {};
                #pragma unroll
                for (int src = 0; src < 4; ++src) {
                    const short* hTs = hTarr[src];
                    const float* p0 = adj + ((size_t)(b * S + (4 * (lc + 1) + tgt) * 32 + (l & 15))) * S
                                    + (4 * lc + src) * 32 + ksg;
                    const float* p1 = p0 + 16 * S;
                    float4 a00 = *(const float4*)p0, a01 = *(const float4*)(p0 + 4);
                    float4 a10 = *(const float4*)p1, a11 = *(const float4*)(p1 + 4);
                    uint4 qa, qb;
                    qa.x = pk2(a00.x, a00.y); qa.y = pk2(a00.z, a00.w);
                    qa.z = pk2(a01.x, a01.y); qa.w = pk2(a01.z, a01.w);
                    qb.x = pk2(a10.x, a10.y); qb.y = pk2(a10.z, a10.w);
                    qb.z = pk2(a11.x, a11.y); qb.w = pk2(a11.z, a11.w);
                    bf16x8 aF0, aF1;
                    *(uint4*)&aF0 = qa; *(uint4*)&aF1 = qb;
                    #pragma unroll
                    for (int dblk = 0; dblk < 4; ++dblk) {
                        int col = w * 64 + dblk * 16 + (l & 15);
                        bf16x8 bF = *(const bf16x8*)&hTs[(l >> 4) * 1024 + col * 8];
                        ac0[dblk] = __builtin_amdgcn_mfma_f32_16x16x32_bf16(aF0, bF, ac0[dblk], 0, 0, 0);
                        ac1[dblk] = __builtin_amdgcn_mfma_f32_16x16x32_bf16(aF1, bF, ac1[dblk], 0, 0, 0);
                    }
                }
                ushort16* gw = Gall + ((size_t)wp * NSLOT + (4 + tgt)) * SLOT;
                #pragma unroll
                for (int dblk = 0; dblk < 4; ++dblk) {
                    int col = w * 64 + dblk * 16 + (l & 15);
                    int dng = dnbase + col;
                    uint2 o0, o1;
                    o0.x = pk2(ac0[dblk][0], ac0[dblk][1]); o0.y = pk2(ac0[dblk][2], ac0[dblk][3]);
                    o1.x = pk2(ac1[dblk][0], ac1[dblk][1]); o1.y = pk2(ac1[dblk][2], ac1[dblk][3]);
                    *(uint2*)(gw + ((size_t)b * DN + dng) * 32 + jb0) = o0;
                    *(uint2*)(gw + ((size_t)b * DN + dng) * 32 + 16 + jb0) = o1;
                }
            }
        }
    } else {
        // -------- gpast role: 4 targets per block, histT read ONCE per fragment --------
        if (lc == 0 || lc >= NL2 - 1) return;
        int idx = blockIdx.x - 128;                // 0..127
        int tile = idx & 63;
        int b = idx >> 6;
        int dn0 = tile * 128;
        int w = tid >> 6, l = tid & 63;
        int jh = w & 1, dh = w >> 1;
        int ksg = (l >> 4) * 8;
        int dnrow = dn0 + dh * 64 + (l & 15);
        int K = 4 * lc;
        const float* abase0 = adj + ((size_t)(b * S + (4 * (lc + 1) + 0) * CHUNK + jh * 16 + (l & 15))) * S + ksg;
        const float* abase1 = abase0 + (size_t)CHUNK * S;
        const float* abase2 = abase1 + (size_t)CHUNK * S;
        const float* abase3 = abase2 + (size_t)CHUNK * S;
        f32x4 acc[4][4] = {};
        #pragma unroll 1
        for (int ks = 0; ks < K; ++ks) {
            bf16x8 bF[4];
            #pragma unroll
            for (int dblk = 0; dblk < 4; ++dblk) {
                uint4 bP = *(const uint4*)(histT + htIdx(b, dnrow + dblk * 16, ks) + ksg);
                *(uint4*)&bF[dblk] = bP;
            }
            #pragma unroll
            for (int tgt = 0; tgt < 4; ++tgt) {
                const float* ab = (tgt == 0) ? abase0 : (tgt == 1) ? abase1
                                : (tgt == 2) ? abase2 : abase3;
                float4 af0 = *(const float4*)(ab + ks * 32);
                float4 af1 = *(const float4*)(ab + ks * 32 + 4);
                uint4 aP;
                aP.x = pk2(af0.x, af0.y); aP.y = pk2(af0.z, af0.w);
                aP.z = pk2(af1.x, af1.y); aP.w = pk2(af1.z, af1.w);
                bf16x8 aF;
                *(uint4*)&aF = aP;
                #pragma unroll
                for (int dblk = 0; dblk < 4; ++dblk)
                    acc[tgt][dblk] = __builtin_amdgcn_mfma_f32_16x16x32_bf16(aF, bF[dblk], acc[tgt][dblk], 0, 0, 0);
            }
        }
        int jb = jh * 16 + (l >> 4) * 4;
        #pragma unroll
        for (int tgt = 0; tgt < 4; ++tgt) {
            ushort16* gbase = Gall + ((size_t)wp * NSLOT + tgt) * SLOT;
            #pragma unroll
            for (int dblk = 0; dblk < 4; ++dblk) {
                int dnc = dn0 + dh * 64 + dblk * 16 + (l & 15);
                uint2 o;
                o.x = pk2(acc[tgt][dblk][0], acc[tgt][dblk][1]);
                o.y = pk2(acc[tgt][dblk][2], acc[tgt][dblk][3]);
                *(uint2*)(gbase + ((size_t)b * DN + dnc) * 32 + jb) = o;
            }
        }
    }
}

// ---------------- y_k: y[b,t,d] = (sum_n histT[b][dn][t]*Cm[b,t,n]) * zs[b,t,d] -------
__global__ __launch_bounds__(256) void y_k(const ushort16* __restrict__ histT,
                                           const float* __restrict__ Cm,
                                           const float* __restrict__ zs,
                                           ushort16* __restrict__ yzb) {
    __shared__ float CmL[S * 17];
    int b = blockIdx.x >> 9;
    int d = blockIdx.x & (DI - 1);
    int tid = threadIdx.x;
    #pragma unroll
    for (int q = 0; q < 8; ++q) {
        int l0 = q * 1024 + tid * 4;
        int t = l0 >> 4, n0 = l0 & 15;
        float4 v = *(const float4*)(Cm + (size_t)b * S * N + l0);
        CmL[t * 17 + n0]     = v.x;
        CmL[t * 17 + n0 + 1] = v.y;
        CmL[t * 17 + n0 + 2] = v.z;
        CmL[t * 17 + n0 + 3] = v.w;
    }
    __syncthreads();
    #pragma unroll
    for (int pass = 0; pass < 2; ++pass) {
        int t = pass * 256 + tid;
        int sb = t >> 5, si = t & 31;
        const ushort16* hb = histT + htIdx(b, d * N, sb) + si;
        float a0 = 0.f, a1 = 0.f, a2 = 0.f, a3 = 0.f;
        #pragma unroll
        for (int n = 0; n < 16; n += 4) {
            a0 += bf2f(hb[(size_t)n * 32])       * CmL[t * 17 + n];
            a1 += bf2f(hb[(size_t)(n + 1) * 32]) * CmL[t * 17 + n + 1];
            a2 += bf2f(hb[(size_t)(n + 2) * 32]) * CmL[t * 17 + n + 2];
            a3 += bf2f(hb[(size_t)(n + 3) * 32]) * CmL[t * 17 + n + 3];
        }
        float acc = (a0 + a1) + (a2 + a3);
        float zv = zs[((size_t)(b * S + t)) * DI + d];
        yzb[((size_t)(b * S + t)) * DI + d] = f2bf(acc * zv);
    }
}

// ---------------- launch ----------------
extern "C" void kernel_launch(void* const* d_in, const int* in_sizes, int n_in,
                              void* d_out, int out_size, void* d_ws, size_t ws_size,
                              hipStream_t stream) {
    const float* x      = (const float*)d_in[0];
    const float* adj    = (const float*)d_in[1];
    const float* ln_w   = (const float*)d_in[2];
    const float* ln_b   = (const float*)d_in[3];
    const float* W_in   = (const float*)d_in[4];
    const float* conv_w = (const float*)d_in[5];
    const float* conv_b = (const float*)d_in[6];
    const float* W_xp   = (const float*)d_in[7];
    const float* W_dt   = (const float*)d_in[8];
    const float* b_dt   = (const float*)d_in[9];
    const float* Wr     = (const float*)d_in[10];
    const float* br     = (const float*)d_in[11];
    const float* W_out  = (const float*)d_in[12];
    float* out = (float*)d_out;

    float* ws = (float*)d_ws;
    size_t off = 0;
    float* x_act  = ws + off; off += (size_t)B * S * DI;
    float* Bmb    = ws + off; off += (size_t)B * S * N;
    float* Cmb    = ws + off; off += (size_t)B * S * N;
    float* rdegp  = ws + off; off += (size_t)B * S;
    int*   flagI  = (int*)(ws + off); off += S;
    float* Ebuf   = ws + off; off += (size_t)B * S * DI;
    float* zsbuf  = ws + off; off += (size_t)B * S * DI;
    float* hlast  = ws + off; off += (size_t)B * DN;
    ushort16* xnb    = (ushort16*)(ws + off); off += (size_t)B * S * D / 2;
    ushort16* yzb    = (ushort16*)(ws + off); off += (size_t)B * S * DI / 2;
    ushort16* histT  = (ushort16*)(ws + off); off += (size_t)B * DN * S / 2;
    ushort16* Gall   = (ushort16*)(ws + off); off += (size_t)2 * NSLOT * B * DN * 32 / 2;
    ushort16* xpb    = (ushort16*)(ws + off); off += (size_t)B * (S + 3) * DI / 2;

    hipMemsetAsync(flagI, 0, S * sizeof(int), stream);
    hipMemsetAsync(xpb, 0, (size_t)B * (S + 3) * DI * 2, stream);

    ln_k<<<B * S, 64, 0, stream>>>(x, ln_w, ln_b, xnb);
    gemmb_k<1><<<dim3(2 * DI / 64, B * S / 64), 256, 0, stream>>>(
        xnb, W_in, nullptr, nullptr, xpb, zsbuf, B * S, 2 * DI, D);
    convm_k<<<dim3(DI / 32, B * S / 32), 256, 0, stream>>>(xpb, conv_w, conv_b, x_act);
    ssmE_k<<<B * S / 4, 256, 0, stream>>>(x_act, W_xp, W_dt, b_dt, Bmb, Cmb, Ebuf);
    deg_k<<<B * S, 64, 0, stream>>>(adj, rdegp, flagI);

    for (int lc = 0; lc < NL2; ++lc)
        chunk4_k<<<256, 256, 0, stream>>>(adj, x_act, Ebuf, Bmb, rdegp, flagI,
                                          Wr, br, Gall, histT, hlast, lc);

    y_k<<<B * DI, 256, 0, stream>>>(histT, Cmb, zsbuf, yzb);

    gemmb_k<0><<<dim3(D / 64, B * S / 64), 256, 0, stream>>>(
        yzb, W_out, x, out, nullptr, nullptr, B * S, D, DI);
}

// Round 20
// 250.546 us; speedup vs baseline: 1.2959x; 1.0254x over previous
//
#include <hip/hip_runtime.h>
#include <math.h>

// Problem constants
static constexpr int B  = 2;
static constexpr int S  = 512;
static constexpr int D  = 256;
static constexpr int N  = 16;
static constexpr int DI = 512;
static constexpr int CHUNK = 32;
static constexpr int NCHUNK = S / CHUNK;   // 16
static constexpr int NL2 = 4;              // 4 launches, 4 chunks each
static constexpr int DN = DI * N;          // 8192
static constexpr int NSLOT = 8;            // 4 gold (tgt) + 4 tails (4+tgt)

typedef unsigned int uint32;
typedef unsigned short ushort16;
using bf16x8 = __attribute__((ext_vector_type(8))) short;
using f32x4  = __attribute__((ext_vector_type(4))) float;

__device__ __forceinline__ ushort16 f2bf(float f) {
    uint32 u = __float_as_uint(f);
    u = (u + 0x7fffu + ((u >> 16) & 1u)) >> 16;   // RNE
    return (ushort16)u;
}
__device__ __forceinline__ float bflo(uint32 u) { return __uint_as_float(u << 16); }
__device__ __forceinline__ float bfhi(uint32 u) { return __uint_as_float(u & 0xffff0000u); }
__device__ __forceinline__ float bf2f(ushort16 u) { return __uint_as_float(((uint32)u) << 16); }
__device__ __forceinline__ uint32 pk2(float a, float b) {
    return (uint32)(ushort16)f2bf(a) | ((uint32)(ushort16)f2bf(b) << 16);
}
// DPP row-rotate within 16-lane rows (VALU pipe, no LDS)
template<int K>
__device__ __forceinline__ float rork(float x) {
    return __uint_as_float((uint32)__builtin_amdgcn_mov_dpp(
        (int)__float_as_uint(x), 0x120 + K, 0xf, 0xf, false));
}
// histT tiled layout: elem (b, dn, s) -> ((b*(S/32) + s/32)*DN + dn)*32 + s%32
__device__ __forceinline__ size_t htIdx(int b, int dn, int sb) {
    return ((size_t)(b * (S / 32) + sb) * DN + dn) * 32;
}

// ------- fused LayerNorm (blocks < B*S) + deg/flag + xpb-halo zero (blocks >= B*S) -------
__global__ void lndeg_k(const float* __restrict__ x, const float* __restrict__ w,
                        const float* __restrict__ bias, ushort16* __restrict__ xnb,
                        const float* __restrict__ adj, float* __restrict__ rdeg,
                        int* __restrict__ flagI, ushort16* __restrict__ xpb) {
    int id = blockIdx.x;
    int lane = threadIdx.x;
    if (id < B * S) {
        int row = id;
        float4 v = *(const float4*)(x + row * D + lane * 4);
        float s = v.x + v.y + v.z + v.w;
        float q = v.x * v.x + v.y * v.y + v.z * v.z + v.w * v.w;
        for (int m = 1; m < 64; m <<= 1) { s += __shfl_xor(s, m); q += __shfl_xor(q, m); }
        float mu  = s * (1.0f / D);
        float var = q * (1.0f / D) - mu * mu;
        float rs  = rsqrtf(var + 1e-5f);
        float4 wv = *(const float4*)(w + lane * 4);
        float4 bv = *(const float4*)(bias + lane * 4);
        float4 o;
        o.x = (v.x - mu) * rs * wv.x + bv.x;
        o.y = (v.y - mu) * rs * wv.y + bv.y;
        o.z = (v.z - mu) * rs * wv.z + bv.z;
        o.w = (v.w - mu) * rs * wv.w + bv.w;
        uint2 pk;
        pk.x = pk2(o.x, o.y);
        pk.y = pk2(o.z, o.w);
        *(uint2*)(xnb + row * D + lane * 4) = pk;
    } else {
        int rid = id - B * S;
        int t = rid & (S - 1), b = rid >> 9;
        const float* row = adj + ((size_t)(b * S + t)) * S;
        float s = 0.0f; bool anyp = false;
        for (int i = lane; i < t; i += 64) { float v = row[i]; s += v; anyp |= (v > 0.0f); }
        for (int m = 1; m < 64; m <<= 1) s += __shfl_xor(s, m);
        bool any = __any(anyp);
        if (lane == 0) {
            rdeg[b * S + t] = 1.0f / fmaxf(s, 1.0f);
            if (t > 0 && any) atomicOr(flagI + t, 1);
        }
        if (t < 3) {   // zero xpb halo row t for batch b
            uint4 z = {0u, 0u, 0u, 0u};
            *(uint4*)(xpb + ((size_t)(b * (S + 3) + t)) * DI + lane * 8) = z;
        }
    }
}

// ------- bf16 MFMA GEMM, W in f32 (converted during staging) -------
template<int MODE>
__global__ __launch_bounds__(256) void gemmb_k(const ushort16* __restrict__ A,
                                               const float* __restrict__ W,
                                               const float* __restrict__ res,
                                               float* __restrict__ C,
                                               ushort16* __restrict__ xpb,
                                               float* __restrict__ zs,
                                               int M, int Nc, int K) {
    __shared__ __align__(16) short As[64 * 40];
    __shared__ __align__(16) short Ws[64 * 40];
    int tid = threadIdx.x;
    int l = tid & 63, wid = tid >> 6;
    int wm = wid & 1, wn = wid >> 1;
    int row0 = blockIdx.y * 64, col0 = blockIdx.x * 64;
    int r = tid >> 2, kseg = (tid & 3) * 8;
    f32x4 acc[2][2] = {};
    for (int k0 = 0; k0 < K; k0 += 32) {
        *(uint4*)&As[r * 40 + kseg] = *(const uint4*)(A + (size_t)(row0 + r) * K + k0 + kseg);
        {
            const float* wrow = W + (size_t)(col0 + r) * K + k0 + kseg;
            float4 w0 = *(const float4*)wrow;
            float4 w1 = *(const float4*)(wrow + 4);
            uint4 q;
            q.x = pk2(w0.x, w0.y); q.y = pk2(w0.z, w0.w);
            q.z = pk2(w1.x, w1.y); q.w = pk2(w1.z, w1.w);
            *(uint4*)&Ws[r * 40 + kseg] = q;
        }
        __syncthreads();
        bf16x8 aF[2], bF[2];
        #pragma unroll
        for (int am = 0; am < 2; ++am)
            aF[am] = *(const bf16x8*)&As[(wm * 32 + am * 16 + (l & 15)) * 40 + (l >> 4) * 8];
        #pragma unroll
        for (int bn = 0; bn < 2; ++bn)
            bF[bn] = *(const bf16x8*)&Ws[(wn * 32 + bn * 16 + (l & 15)) * 40 + (l >> 4) * 8];
        #pragma unroll
        for (int am = 0; am < 2; ++am)
            #pragma unroll
            for (int bn = 0; bn < 2; ++bn)
                acc[am][bn] = __builtin_amdgcn_mfma_f32_16x16x32_bf16(aF[am], bF[bn], acc[am][bn], 0, 0, 0);
        __syncthreads();
    }
    #pragma unroll
    for (int am = 0; am < 2; ++am)
        #pragma unroll
        for (int bn = 0; bn < 2; ++bn) {
            int cc = col0 + wn * 32 + bn * 16 + (l & 15);
            #pragma unroll
            for (int reg = 0; reg < 4; ++reg) {
                int rr = row0 + wm * 32 + am * 16 + (l >> 4) * 4 + reg;
                float v = acc[am][bn][reg];
                if (MODE == 0) {
                    if (res) v += res[(size_t)rr * Nc + cc];
                    C[(size_t)rr * Nc + cc] = v;
                } else {
                    int b = rr >> 9, t = rr & (S - 1);
                    if (cc < DI)
                        xpb[((size_t)(b * (S + 3) + 3 + t)) * DI + cc] = f2bf(v);
                    else
                        zs[((size_t)(b * S + t)) * DI + (cc - DI)] = v / (1.0f + __expf(-v));
                }
            }
        }
}

// ---------------- Causal conv via bf16 MFMA + bias + silu ----------------
__global__ __launch_bounds__(256) void convm_k(const ushort16* __restrict__ xpb,
                                               const float* __restrict__ conv_w,
                                               const float* __restrict__ conv_b,
                                               float* __restrict__ x_act) {
    __shared__ __align__(16) short AxS[35 * 40];
    __shared__ __align__(16) short WbS[4 * 32 * 40];
    int tid = threadIdx.x;
    int l = tid & 63, wid = tid >> 6;
    int wm = wid & 1, wn = wid >> 1;
    int o0 = blockIdx.x * 32;
    int mt = blockIdx.y;
    int b = mt >> 4, tl0 = (mt & 15) * 32;
    f32x4 acc = {0.f, 0.f, 0.f, 0.f};

    for (int k0 = 0; k0 < DI; k0 += 32) {
        if (tid < 140) {
            int rr = tid >> 2, seg = tid & 3;
            uint4 v = *(const uint4*)(xpb + ((size_t)(b * (S + 3) + tl0 + rr)) * DI + k0 + seg * 8);
            *(uint4*)&AxS[rr * 40 + seg * 8] = v;
        }
        #pragma unroll
        for (int it = 0; it < 4; ++it) {
            int p = it * 256 + tid;
            int o = p >> 5, i = p & 31;
            float4 w4 = *(const float4*)(conv_w + ((size_t)(o0 + o) * DI + (k0 + i)) * 4);
            WbS[(0 * 32 + o) * 40 + i] = (short)f2bf(w4.x);
            WbS[(1 * 32 + o) * 40 + i] = (short)f2bf(w4.y);
            WbS[(2 * 32 + o) * 40 + i] = (short)f2bf(w4.z);
            WbS[(3 * 32 + o) * 40 + i] = (short)f2bf(w4.w);
        }
        __syncthreads();
        #pragma unroll
        for (int k = 0; k < 4; ++k) {
            bf16x8 aF = *(const bf16x8*)&AxS[(wm * 16 + (l & 15) + k) * 40 + (l >> 4) * 8];
            bf16x8 bF = *(const bf16x8*)&WbS[(k * 32 + wn * 16 + (l & 15)) * 40 + (l >> 4) * 8];
            acc = __builtin_amdgcn_mfma_f32_16x16x32_bf16(aF, bF, acc, 0, 0, 0);
        }
        __syncthreads();
    }
    int oc = o0 + wn * 16 + (l & 15);
    float bia = conv_b[oc];
    #pragma unroll
    for (int reg = 0; reg < 4; ++reg) {
        int m = wm * 16 + (l >> 4) * 4 + reg;
        float v = acc[reg] + bia;
        x_act[((size_t)(b * S + tl0 + m)) * DI + oc] = v / (1.0f + __expf(-v));
    }
}

// ------- ssm (33 outputs) + E epilogue -------
__global__ void ssmE_k(const float* __restrict__ x_act, const float* __restrict__ W_xp,
                       const float* __restrict__ W_dt, const float* __restrict__ b_dt,
                       float* __restrict__ Bm, float* __restrict__ Cm,
                       float* __restrict__ E) {
    int row = blockIdx.x * 4 + (threadIdx.x >> 6);
    int lane = threadIdx.x & 63;
    const float* xr = x_act + (size_t)row * DI + lane * 8;
    float4 v0 = *(const float4*)xr;
    float4 v1 = *(const float4*)(xr + 4);
    float dtr = 0.0f;
    for (int j = 0; j < 2 * N + 1; ++j) {
        const float* wr = W_xp + (size_t)j * DI + lane * 8;
        float4 w0 = *(const float4*)wr;
        float4 w1 = *(const float4*)(wr + 4);
        float acc = v0.x * w0.x + v0.y * w0.y + v0.z * w0.z + v0.w * w0.w
                  + v1.x * w1.x + v1.y * w1.y + v1.z * w1.z + v1.w * w1.w;
        for (int m = 1; m < 64; m <<= 1) acc += __shfl_xor(acc, m);
        if (j == 0) dtr = acc;
        if (lane == 0) {
            if (j >= 1 && j < 1 + N) Bm[(size_t)row * N + (j - 1)] = acc;
            else if (j >= 1 + N)     Cm[(size_t)row * N + (j - 1 - N)] = acc;
        }
    }
    int d0 = lane * 8;
    float4 w0 = *(const float4*)(W_dt + d0);
    float4 w1 = *(const float4*)(W_dt + d0 + 4);
    float4 q0 = *(const float4*)(b_dt + d0);
    float4 q1 = *(const float4*)(b_dt + d0 + 4);
    float4 e0, e1;
    e0.x = 1.0f / (1.0f + __expf(dtr * w0.x + q0.x));
    e0.y = 1.0f / (1.0f + __expf(dtr * w0.y + q0.y));
    e0.z = 1.0f / (1.0f + __expf(dtr * w0.z + q0.z));
    e0.w = 1.0f / (1.0f + __expf(dtr * w0.w + q0.w));
    e1.x = 1.0f / (1.0f + __expf(dtr * w1.x + q1.x));
    e1.y = 1.0f / (1.0f + __expf(dtr * w1.y + q1.y));
    e1.z = 1.0f / (1.0f + __expf(dtr * w1.z + q1.z));
    e1.w = 1.0f / (1.0f + __expf(dtr * w1.w + q1.w));
    *(float4*)(E + (size_t)row * DI + d0) = e0;
    *(float4*)(E + (size_t)row * DI + d0 + 4) = e1;
}

// ================= quad-chunk fused kernel (256 threads, 256 blocks) =================
#define SCAN32(RO, ADJT, GSUM, EL, XAL, BNL, RDEGL, FLL)                    \
    _Pragma("unroll")                                                       \
    for (int j = 0; j < CHUNK; ++j) {                                       \
        float e  = (EL) [((RO) + j) * 8 + grp];                             \
        float xa = (XAL)[((RO) + j) * 8 + grp];                             \
        float Bn = (BNL)[((RO) + j) * 16 + n];                              \
        h = h * e + xa * Bn;                                                \
        float g0 = GSUM[j], g1 = 0.f, g2 = 0.f, g3 = 0.f;                   \
        const float* ar = (ADJT) + j * 36;                                  \
        int sp = 0;                                                         \
        _Pragma("unroll")                                                   \
        for (; sp + 4 <= j; sp += 4) {                                      \
            float4 av = *(const float4*)(ar + sp);                          \
            g0 += av.x * hreg[sp];     g1 += av.y * hreg[sp + 1];           \
            g2 += av.z * hreg[sp + 2]; g3 += av.w * hreg[sp + 3];           \
        }                                                                   \
        _Pragma("unroll")                                                   \
        for (; sp < j; ++sp) g0 += ar[sp] * hreg[sp];                       \
        float gr = (g0 + g1) + (g2 + g3);                                   \
        float m0 = gr * wrr[0] + rork<4>(gr) * wrr[4]                       \
                 + rork<8>(gr) * wrr[8] + rork<12>(gr) * wrr[12];           \
        float m1 = rork<1>(gr) * wrr[1] + rork<5>(gr) * wrr[5]              \
                 + rork<9>(gr) * wrr[9] + rork<13>(gr) * wrr[13];           \
        float m2 = rork<2>(gr) * wrr[2] + rork<6>(gr) * wrr[6]              \
                 + rork<10>(gr) * wrr[10] + rork<14>(gr) * wrr[14];         \
        float m3 = rork<3>(gr) * wrr[3] + rork<7>(gr) * wrr[7]              \
                 + rork<11>(gr) * wrr[11] + rork<15>(gr) * wrr[15];         \
        float acc = fmaf((RDEGL)[(RO) + j], (m0 + m1) + (m2 + m3), brn);    \
        if ((FLL)[(RO) + j])                                                \
            h = fmaf(0.1f * acc,                                            \
                     __builtin_amdgcn_rcpf(1.0f + __expf(-acc)), h);        \
        hreg[j] = h;                                                        \
    }

#define PRESUM(GSUM, PTR) {                                                 \
    const ushort16* _p = (PTR);                                             \
    _Pragma("unroll")                                                       \
    for (int qi = 0; qi < 4; ++qi) {                                        \
        uint4 q = *(const uint4*)(_p + qi * 8);                             \
        GSUM[qi*8+0] += bflo(q.x); GSUM[qi*8+1] += bfhi(q.x);               \
        GSUM[qi*8+2] += bflo(q.y); GSUM[qi*8+3] += bfhi(q.y);               \
        GSUM[qi*8+4] += bflo(q.z); GSUM[qi*8+5] += bfhi(q.z);               \
        GSUM[qi*8+6] += bflo(q.w); GSUM[qi*8+7] += bfhi(q.w);               \
    } }

// hist write (global tiled + LDS hT buffer)
#define HWRITE(CIDX, HTBUF) {                                               \
    ushort16* ht = histT + htIdx(b, dn, (CIDX));                            \
    _Pragma("unroll")                                                       \
    for (int qi = 0; qi < 4; ++qi) {                                        \
        uint4 q;                                                            \
        q.x = pk2(hreg[qi*8+0], hreg[qi*8+1]);                              \
        q.y = pk2(hreg[qi*8+2], hreg[qi*8+3]);                              \
        q.z = pk2(hreg[qi*8+4], hreg[qi*8+5]);                              \
        q.w = pk2(hreg[qi*8+6], hreg[qi*8+7]);                              \
        *(uint4*)(ht + qi * 8) = q;                                         \
        *(uint4*)&(HTBUF)[qi * 1024 + tid * 8] = q;                         \
    } }

// mid phase: Gmid[j][col] = sum_{sidx<TCL} adj[target rows][src cols] x hT_src
#define MIDPHASE(TCL) {                                                     \
    int w = tid >> 6, l = tid & 63;                                         \
    int ksg = (l >> 4) * 8;                                                 \
    f32x4 ac0[4] = {}, ac1[4] = {};                                         \
    _Pragma("unroll")                                                       \
    for (int sidx = 0; sidx < (TCL); ++sidx) {                              \
        const float* p0 = adj + ((size_t)(b * S + c0s + (TCL) * 32 + (l & 15))) * S \
                        + c0s + sidx * 32 + ksg;                            \
        const float* p1 = p0 + 16 * S;                                      \
        float4 a00 = *(const float4*)p0, a01 = *(const float4*)(p0 + 4);    \
        float4 a10 = *(const float4*)p1, a11 = *(const float4*)(p1 + 4);    \
        uint4 qa, qb;                                                       \
        qa.x = pk2(a00.x, a00.y); qa.y = pk2(a00.z, a00.w);                 \
        qa.z = pk2(a01.x, a01.y); qa.w = pk2(a01.z, a01.w);                 \
        qb.x = pk2(a10.x, a10.y); qb.y = pk2(a10.z, a10.w);                 \
        qb.z = pk2(a11.x, a11.y); qb.w = pk2(a11.z, a11.w);                 \
        bf16x8 aF0, aF1;                                                    \
        *(uint4*)&aF0 = qa; *(uint4*)&aF1 = qb;                             \
        const short* hTs = hTarr[sidx];                                     \
        _Pragma("unroll")                                                   \
        for (int dblk = 0; dblk < 4; ++dblk) {                              \
            int col = w * 64 + dblk * 16 + (l & 15);                        \
            bf16x8 bF = *(const bf16x8*)&hTs[(l >> 4) * 1024 + col * 8];    \
            ac0[dblk] = __builtin_amdgcn_mfma_f32_16x16x32_bf16(aF0, bF, ac0[dblk], 0, 0, 0); \
            ac1[dblk] = __builtin_amdgcn_mfma_f32_16x16x32_bf16(aF1, bF, ac1[dblk], 0, 0, 0); \
        }                                                                   \
    }                                                                       \
    int jb0 = (l >> 4) * 4;                                                 \
    _Pragma("unroll")                                                       \
    for (int dblk = 0; dblk < 4; ++dblk) {                                  \
        int col = w * 64 + dblk * 16 + (l & 15);                            \
        _Pragma("unroll")                                                   \
        for (int reg = 0; reg < 4; ++reg) {                                 \
            Gmid[(jb0 + reg) * 136 + col]      = (short)f2bf(ac0[dblk][reg]); \
            Gmid[(16 + jb0 + reg) * 136 + col] = (short)f2bf(ac1[dblk][reg]); \
        }                                                                   \
    } }

#define GSADD(GSUM)                                                         \
    _Pragma("unroll")                                                       \
    for (int j = 0; j < CHUNK; ++j)                                         \
        GSUM[j] += bf2f((ushort16)Gmid[j * 136 + tid]);

// staging of one 2-chunk operand set by thread index T (0..255) at rows c0s+OFS
#define STAGEOPS(T, OFS, TRI0, TRI1, EL, XAL, BNL, RDEGL, FLL) {            \
    int j = (T) >> 3, s4 = ((T) & 7) * 4;                                   \
    {                                                                       \
        float4 a0 = *(const float4*)(adj + ((size_t)(b * S + c0s + (OFS) + j)) * S + c0s + (OFS) + s4); \
        float* dp = (TRI0) + j * 36 + s4;                                   \
        dp[0] = a0.x; dp[1] = a0.y; dp[2] = a0.z; dp[3] = a0.w;             \
    }                                                                       \
    {                                                                       \
        float4 a0 = *(const float4*)(adj + ((size_t)(b * S + c0s + (OFS) + 32 + j)) * S + c0s + (OFS) + 32 + s4); \
        float* dp = (TRI1) + j * 36 + s4;                                   \
        dp[0] = a0.x; dp[1] = a0.y; dp[2] = a0.z; dp[3] = a0.w;             \
    }                                                                       \
    int jr = (T) >> 2, dd = ((T) & 3) * 2;                                  \
    float2 ev = *(const float2*)(E     + ((size_t)(b * S + c0s + (OFS) + jr)) * DI + d0 + dd); \
    float2 xv = *(const float2*)(x_act + ((size_t)(b * S + c0s + (OFS) + jr)) * DI + d0 + dd); \
    (EL) [jr * 8 + dd] = ev.x; (EL) [jr * 8 + dd + 1] = ev.y;               \
    (XAL)[jr * 8 + dd] = xv.x; (XAL)[jr * 8 + dd + 1] = xv.y;               \
    int nn = ((T) & 3) * 4;                                                 \
    float4 bv = *(const float4*)(Bm + ((size_t)(b * S + c0s + (OFS) + jr)) * N + nn); \
    (BNL)[jr * 16 + nn] = bv.x; (BNL)[jr * 16 + nn + 1] = bv.y;             \
    (BNL)[jr * 16 + nn + 2] = bv.z; (BNL)[jr * 16 + nn + 3] = bv.w;         \
    if ((T) < 64) {                                                         \
        (RDEGL)[(T)] = rdeg[b * S + c0s + (OFS) + (T)];                     \
        (FLL)[(T)]   = flagI[c0s + (OFS) + (T)];                            \
    } }

__global__ __launch_bounds__(256) void chunk4_k(const float* __restrict__ adj,
                                                const float* __restrict__ x_act,
                                                const float* __restrict__ E,
                                                const float* __restrict__ Bm,
                                                const float* __restrict__ rdeg,
                                                const int* __restrict__ flagI,
                                                const float* __restrict__ Wr,
                                                const float* __restrict__ br,
                                                ushort16* __restrict__ Gall,
                                                ushort16* __restrict__ histT,
                                                float* __restrict__ hlast, int lc) {
    __shared__ __align__(16) char smem[69120];
    int tid = threadIdx.x;
    int c0 = 4 * lc;
    int c0s = c0 * CHUNK;
    const size_t SLOT = (size_t)B * DN * 32;
    int rp = lc & 1, wp = (lc + 1) & 1;

    if (blockIdx.x < 128) {
        // ---------------- scan role ----------------
        float* triA   = (float*)smem;                  // set1
        float* triB   = (float*)(smem + 4608);
        float* eLa    = (float*)(smem + 9216);
        float* xaLa   = (float*)(smem + 11264);
        float* BnLa   = (float*)(smem + 13312);
        float* rdegLa = (float*)(smem + 17408);
        int*   flLa   = (int*)  (smem + 17664);
        float* triC   = (float*)(smem + 17920);        // set2
        float* triD   = (float*)(smem + 22528);
        float* eLb    = (float*)(smem + 27136);
        float* xaLb   = (float*)(smem + 29184);
        float* BnLb   = (float*)(smem + 31232);
        float* rdegLb = (float*)(smem + 35328);
        int*   flLb   = (int*)  (smem + 35584);
        short* hTA    = (short*)(smem + 35840);
        short* hTB    = (short*)(smem + 44032);
        short* hTC    = (short*)(smem + 52224);
        short* Gmid   = (short*)(smem + 60416);        // overlay hTD
        short* hTD    = (short*)(smem + 60416);

        int b = blockIdx.x >> 6;
        int d0 = (blockIdx.x & 63) << 3;
        int n = tid & 15, grp = (tid >> 4) & 7;
        int d = d0 + grp;
        int dn = d * N + n;
        int dnbase = (blockIdx.x & 63) << 7;
        const short* hTarr[4] = {hTA, hTB, hTC, hTD};

        // ---- phase 1: stage set1 (A,B) by all 256 ----
        STAGEOPS(tid, 0, triA, triB, eLa, xaLa, BnLa, rdegLa, flLa)
        __syncthreads();

        float gs0[CHUNK], gs1[CHUNK];
        float wrr[16];
        float brn = 0.f, h = 0.f;
        float hreg[CHUNK];

        // ---- phase 2: scan A (tid<128)  ||  stage set2 (tid>=128) ----
        if (tid < 128) {
            #pragma unroll
            for (int j = 0; j < CHUNK; ++j) { gs0[j] = 0.f; gs1[j] = 0.f; }
            size_t tb = ((size_t)b * DN + dn) * 32;
            if (lc >= 2) {
                PRESUM(gs0, Gall + ((size_t)rp * NSLOT + 0) * SLOT + tb);
                PRESUM(gs1, Gall + ((size_t)rp * NSLOT + 1) * SLOT + tb);
            }
            if (lc >= 1) {
                PRESUM(gs0, Gall + ((size_t)rp * NSLOT + 4) * SLOT + tb);
                PRESUM(gs1, Gall + ((size_t)rp * NSLOT + 5) * SLOT + tb);
            }
            int probe = __builtin_amdgcn_mov_dpp((int)n, 0x121, 0xf, 0xf, false);
            bool plusdir = (probe == ((n + 1) & 15));
            #pragma unroll
            for (int k = 0; k < 16; ++k) {
                int ip = (n + k) & 15, im = (n - k + 16) & 15;
                wrr[k] = Wr[n * 16 + (plusdir ? ip : im)];
            }
            brn = br[n];
            h = (lc == 0) ? 0.0f : hlast[b * DN + dn];

            SCAN32(0, triA, gs0, eLa, xaLa, BnLa, rdegLa, flLa)   // chunk A
            HWRITE(c0 + 0, hTA)
        } else {
            #pragma unroll
            for (int rep = 0; rep < 2; ++rep) {
                int t2 = ((tid - 128) << 1) | rep;
                STAGEOPS(t2, 64, triC, triD, eLb, xaLb, BnLb, rdegLb, flLb)
            }
        }
        __syncthreads();
        if (tid < 128) MIDPHASE(1)        // B <- A
        __syncthreads();
        if (tid < 128) {
            GSADD(gs1)
            SCAN32(32, triB, gs1, eLa, xaLa, BnLa, rdegLa, flLa)  // chunk B
            HWRITE(c0 + 1, hTB)
        }
        __syncthreads();

        // ---- second pair: presum C/D + mid C ----
        if (tid < 128) {
            #pragma unroll
            for (int j = 0; j < CHUNK; ++j) { gs0[j] = 0.f; gs1[j] = 0.f; }
            size_t tb = ((size_t)b * DN + dn) * 32;
            if (lc >= 2) {
                PRESUM(gs0, Gall + ((size_t)rp * NSLOT + 2) * SLOT + tb);
                PRESUM(gs1, Gall + ((size_t)rp * NSLOT + 3) * SLOT + tb);
            }
            if (lc >= 1) {
                PRESUM(gs0, Gall + ((size_t)rp * NSLOT + 6) * SLOT + tb);
                PRESUM(gs1, Gall + ((size_t)rp * NSLOT + 7) * SLOT + tb);
            }
            MIDPHASE(2)                   // C <- {A,B}
        }
        __syncthreads();
        if (tid < 128) {
            GSADD(gs0)
            SCAN32(0, triC, gs0, eLb, xaLb, BnLb, rdegLb, flLb)   // chunk C
            HWRITE(c0 + 2, hTC)
        }
        __syncthreads();
        if (tid < 128) MIDPHASE(3)        // D <- {A,B,C}
        __syncthreads();
        if (tid < 128) GSADD(gs1)
        __syncthreads();                  // Gmid reads done before hTD overlay write
        if (tid < 128) {
            SCAN32(32, triD, gs1, eLb, xaLb, BnLb, rdegLb, flLb)  // chunk D
            HWRITE(c0 + 3, hTD)
            hlast[b * DN + dn] = h;
        }
        __syncthreads();

        // ---- tails: accumulated over src -> 4 slots (all 256 threads) ----
        if (lc < NL2 - 1) {
            int half = tid >> 7;
            int lt = tid & 127;
            int w = lt >> 6, l = lt & 63;
            int ksg = (l >> 4) * 8;
            int jb0 = (l >> 4) * 4;
            #pragma unroll
            for (int tp = 0; tp < 2; ++tp) {
                int tgt = half * 2 + tp;
                f32x4 ac0[4] = {}, ac1[4] = {};
                #pragma unroll
                for (int src = 0; src < 4; ++src) {
                    const short* hTs = hTarr[src];
                    const float* p0 = adj + ((size_t)(b * S + (4 * (lc + 1) + tgt) * 32 + (l & 15))) * S
                                    + (4 * lc + src) * 32 + ksg;
                    const float* p1 = p0 + 16 * S;
                    float4 a00 = *(const float4*)p0, a01 = *(const float4*)(p0 + 4);
                    float4 a10 = *(const float4*)p1, a11 = *(const float4*)(p1 + 4);
                    uint4 qa, qb;
                    qa.x = pk2(a00.x, a00.y); qa.y = pk2(a00.z, a00.w);
                    qa.z = pk2(a01.x, a01.y); qa.w = pk2(a01.z, a01.w);
                    qb.x = pk2(a10.x, a10.y); qb.y = pk2(a10.z, a10.w);
                    qb.z = pk2(a11.x, a11.y); qb.w = pk2(a11.z, a11.w);
                    bf16x8 aF0, aF1;
                    *(uint4*)&aF0 = qa; *(uint4*)&aF1 = qb;
                    #pragma unroll
                    for (int dblk = 0; dblk < 4; ++dblk) {
                        int col = w * 64 + dblk * 16 + (l & 15);
                        bf16x8 bF = *(const bf16x8*)&hTs[(l >> 4) * 1024 + col * 8];
                        ac0[dblk] = __builtin_amdgcn_mfma_f32_16x16x32_bf16(aF0, bF, ac0[dblk], 0, 0, 0);
                        ac1[dblk] = __builtin_amdgcn_mfma_f32_16x16x32_bf16(aF1, bF, ac1[dblk], 0, 0, 0);
                    }
                }
                ushort16* gw = Gall + ((size_t)wp * NSLOT + (4 + tgt)) * SLOT;
                #pragma unroll
                for (int dblk = 0; dblk < 4; ++dblk) {
                    int col = w * 64 + dblk * 16 + (l & 15);
                    int dng = dnbase + col;
                    uint2 o0, o1;
                    o0.x = pk2(ac0[dblk][0], ac0[dblk][1]); o0.y = pk2(ac0[dblk][2], ac0[dblk][3]);
                    o1.x = pk2(ac1[dblk][0], ac1[dblk][1]); o1.y = pk2(ac1[dblk][2], ac1[dblk][3]);
                    *(uint2*)(gw + ((size_t)b * DN + dng) * 32 + jb0) = o0;
                    *(uint2*)(gw + ((size_t)b * DN + dng) * 32 + 16 + jb0) = o1;
                }
            }
        }
    } else {
        // -------- gpast role: 4 targets per block, histT read ONCE per fragment --------
        if (lc == 0 || lc >= NL2 - 1) return;
        int idx = blockIdx.x - 128;                // 0..127
        int tile = idx & 63;
        int b = idx >> 6;
        int dn0 = tile * 128;
        int w = tid >> 6, l = tid & 63;
        int jh = w & 1, dh = w >> 1;
        int ksg = (l >> 4) * 8;
        int dnrow = dn0 + dh * 64 + (l & 15);
        int K = 4 * lc;
        const float* abase0 = adj + ((size_t)(b * S + (4 * (lc + 1) + 0) * CHUNK + jh * 16 + (l & 15))) * S + ksg;
        const float* abase1 = abase0 + (size_t)CHUNK * S;
        const float* abase2 = abase1 + (size_t)CHUNK * S;
        const float* abase3 = abase2 + (size_t)CHUNK * S;
        f32x4 acc[4][4] = {};
        #pragma unroll 1
        for (int ks = 0; ks < K; ++ks) {
            bf16x8 bF[4];
            #pragma unroll
            for (int dblk = 0; dblk < 4; ++dblk) {
                uint4 bP = *(const uint4*)(histT + htIdx(b, dnrow + dblk * 16, ks) + ksg);
                *(uint4*)&bF[dblk] = bP;
            }
            #pragma unroll
            for (int tgt = 0; tgt < 4; ++tgt) {
                const float* ab = (tgt == 0) ? abase0 : (tgt == 1) ? abase1
                                : (tgt == 2) ? abase2 : abase3;
                float4 af0 = *(const float4*)(ab + ks * 32);
                float4 af1 = *(const float4*)(ab + ks * 32 + 4);
                uint4 aP;
                aP.x = pk2(af0.x, af0.y); aP.y = pk2(af0.z, af0.w);
                aP.z = pk2(af1.x, af1.y); aP.w = pk2(af1.z, af1.w);
                bf16x8 aF;
                *(uint4*)&aF = aP;
                #pragma unroll
                for (int dblk = 0; dblk < 4; ++dblk)
                    acc[tgt][dblk] = __builtin_amdgcn_mfma_f32_16x16x32_bf16(aF, bF[dblk], acc[tgt][dblk], 0, 0, 0);
            }
        }
        int jb = jh * 16 + (l >> 4) * 4;
        #pragma unroll
        for (int tgt = 0; tgt < 4; ++tgt) {
            ushort16* gbase = Gall + ((size_t)wp * NSLOT + tgt) * SLOT;
            #pragma unroll
            for (int dblk = 0; dblk < 4; ++dblk) {
                int dnc = dn0 + dh * 64 + dblk * 16 + (l & 15);
                uint2 o;
                o.x = pk2(acc[tgt][dblk][0], acc[tgt][dblk][1]);
                o.y = pk2(acc[tgt][dblk][2], acc[tgt][dblk][3]);
                *(uint2*)(gbase + ((size_t)b * DN + dnc) * 32 + jb) = o;
            }
        }
    }
}

// ---------------- y_k: y[b,t,d] = (sum_n histT[b][dn][t]*Cm[b,t,n]) * zs[b,t,d] -------
__global__ __launch_bounds__(256) void y_k(const ushort16* __restrict__ histT,
                                           const float* __restrict__ Cm,
                                           const float* __restrict__ zs,
                                           ushort16* __restrict__ yzb) {
    __shared__ float CmL[S * 17];
    int b = blockIdx.x >> 9;
    int d = blockIdx.x & (DI - 1);
    int tid = threadIdx.x;
    #pragma unroll
    for (int q = 0; q < 8; ++q) {
        int l0 = q * 1024 + tid * 4;
        int t = l0 >> 4, n0 = l0 & 15;
        float4 v = *(const float4*)(Cm + (size_t)b * S * N + l0);
        CmL[t * 17 + n0]     = v.x;
        CmL[t * 17 + n0 + 1] = v.y;
        CmL[t * 17 + n0 + 2] = v.z;
        CmL[t * 17 + n0 + 3] = v.w;
    }
    __syncthreads();
    #pragma unroll
    for (int pass = 0; pass < 2; ++pass) {
        int t = pass * 256 + tid;
        int sb = t >> 5, si = t & 31;
        const ushort16* hb = histT + htIdx(b, d * N, sb) + si;
        float a0 = 0.f, a1 = 0.f, a2 = 0.f, a3 = 0.f;
        #pragma unroll
        for (int n = 0; n < 16; n += 4) {
            a0 += bf2f(hb[(size_t)n * 32])       * CmL[t * 17 + n];
            a1 += bf2f(hb[(size_t)(n + 1) * 32]) * CmL[t * 17 + n + 1];
            a2 += bf2f(hb[(size_t)(n + 2) * 32]) * CmL[t * 17 + n + 2];
            a3 += bf2f(hb[(size_t)(n + 3) * 32]) * CmL[t * 17 + n + 3];
        }
        float acc = (a0 + a1) + (a2 + a3);
        float zv = zs[((size_t)(b * S + t)) * DI + d];
        yzb[((size_t)(b * S + t)) * DI + d] = f2bf(acc * zv);
    }
}

// ---------------- launch ----------------
extern "C" void kernel_launch(void* const* d_in, const int* in_sizes, int n_in,
                              void* d_out, int out_size, void* d_ws, size_t ws_size,
                              hipStream_t stream) {
    const float* x      = (const float*)d_in[0];
    const float* adj    = (const float*)d_in[1];
    const float* ln_w   = (const float*)d_in[2];
    const float* ln_b   = (const float*)d_in[3];
    const float* W_in   = (const float*)d_in[4];
    const float* conv_w = (const float*)d_in[5];
    const float* conv_b = (const float*)d_in[6];
    const float* W_xp   = (const float*)d_in[7];
    const float* W_dt   = (const float*)d_in[8];
    const float* b_dt   = (const float*)d_in[9];
    const float* Wr     = (const float*)d_in[10];
    const float* br     = (const float*)d_in[11];
    const float* W_out  = (const float*)d_in[12];
    float* out = (float*)d_out;

    float* ws = (float*)d_ws;
    size_t off = 0;
    float* x_act  = ws + off; off += (size_t)B * S * DI;
    float* Bmb    = ws + off; off += (size_t)B * S * N;
    float* Cmb    = ws + off; off += (size_t)B * S * N;
    float* rdegp  = ws + off; off += (size_t)B * S;
    int*   flagI  = (int*)(ws + off); off += S;
    float* Ebuf   = ws + off; off += (size_t)B * S * DI;
    float* zsbuf  = ws + off; off += (size_t)B * S * DI;
    float* hlast  = ws + off; off += (size_t)B * DN;
    ushort16* xnb    = (ushort16*)(ws + off); off += (size_t)B * S * D / 2;
    ushort16* yzb    = (ushort16*)(ws + off); off += (size_t)B * S * DI / 2;
    ushort16* histT  = (ushort16*)(ws + off); off += (size_t)B * DN * S / 2;
    ushort16* Gall   = (ushort16*)(ws + off); off += (size_t)2 * NSLOT * B * DN * 32 / 2;
    ushort16* xpb    = (ushort16*)(ws + off); off += (size_t)B * (S + 3) * DI / 2;

    hipMemsetAsync(flagI, 0, S * sizeof(int), stream);

    lndeg_k<<<2 * B * S, 64, 0, stream>>>(x, ln_w, ln_b, xnb, adj, rdegp, flagI, xpb);
    gemmb_k<1><<<dim3(2 * DI / 64, B * S / 64), 256, 0, stream>>>(
        xnb, W_in, nullptr, nullptr, xpb, zsbuf, B * S, 2 * DI, D);
    convm_k<<<dim3(DI / 32, B * S / 32), 256, 0, stream>>>(xpb, conv_w, conv_b, x_act);
    ssmE_k<<<B * S / 4, 256, 0, stream>>>(x_act, W_xp, W_dt, b_dt, Bmb, Cmb, Ebuf);

    for (int lc = 0; lc < NL2; ++lc)
        chunk4_k<<<256, 256, 0, stream>>>(adj, x_act, Ebuf, Bmb, rdegp, flagI,
                                          Wr, br, Gall, histT, hlast, lc);

    y_k<<<B * DI, 256, 0, stream>>>(histT, Cmb, zsbuf, yzb);

    gemmb_k<0><<<dim3(D / 64, B * S / 64), 256, 0, stream>>>(
        yzb, W_out, x, out, nullptr, nullptr, B * S, D, DI);
}

// Round 21
// 250.408 us; speedup vs baseline: 1.2966x; 1.0006x over previous
//
#include <hip/hip_runtime.h>
#include <math.h>

// Problem constants
static constexpr int B  = 2;
static constexpr int S  = 512;
static constexpr int D  = 256;
static constexpr int N  = 16;
static constexpr int DI = 512;
static constexpr int CHUNK = 32;
static constexpr int NCHUNK = S / CHUNK;   // 16
static constexpr int NL2 = 4;              // 4 launches, 4 chunks each
static constexpr int DN = DI * N;          // 8192
static constexpr int NSLOT = 8;            // 4 gold (tgt) + 4 tails (4+tgt)

typedef unsigned int uint32;
typedef unsigned short ushort16;
using bf16x8 = __attribute__((ext_vector_type(8))) short;
using f32x4  = __attribute__((ext_vector_type(4))) float;

__device__ __forceinline__ ushort16 f2bf(float f) {
    uint32 u = __float_as_uint(f);
    u = (u + 0x7fffu + ((u >> 16) & 1u)) >> 16;   // RNE
    return (ushort16)u;
}
__device__ __forceinline__ float bflo(uint32 u) { return __uint_as_float(u << 16); }
__device__ __forceinline__ float bfhi(uint32 u) { return __uint_as_float(u & 0xffff0000u); }
__device__ __forceinline__ float bf2f(ushort16 u) { return __uint_as_float(((uint32)u) << 16); }
__device__ __forceinline__ uint32 pk2(float a, float b) {
    return (uint32)(ushort16)f2bf(a) | ((uint32)(ushort16)f2bf(b) << 16);
}
// DPP row-rotate within 16-lane rows (VALU pipe, no LDS)
template<int K>
__device__ __forceinline__ float rork(float x) {
    return __uint_as_float((uint32)__builtin_amdgcn_mov_dpp(
        (int)__float_as_uint(x), 0x120 + K, 0xf, 0xf, false));
}
// histT tiled layout: elem (b, dn, s) -> ((b*(S/32) + s/32)*DN + dn)*32 + s%32
__device__ __forceinline__ size_t htIdx(int b, int dn, int sb) {
    return ((size_t)(b * (S / 32) + sb) * DN + dn) * 32;
}

// ------- fused LayerNorm (blocks < B*S) + deg/flag + xpb-halo zero (blocks >= B*S) -------
__global__ void lndeg_k(const float* __restrict__ x, const float* __restrict__ w,
                        const float* __restrict__ bias, ushort16* __restrict__ xnb,
                        const float* __restrict__ adj, float* __restrict__ rdeg,
                        int* __restrict__ flagI, ushort16* __restrict__ xpb) {
    int id = blockIdx.x;
    int lane = threadIdx.x;
    if (id < B * S) {
        int row = id;
        float4 v = *(const float4*)(x + row * D + lane * 4);
        float s = v.x + v.y + v.z + v.w;
        float q = v.x * v.x + v.y * v.y + v.z * v.z + v.w * v.w;
        for (int m = 1; m < 64; m <<= 1) { s += __shfl_xor(s, m); q += __shfl_xor(q, m); }
        float mu  = s * (1.0f / D);
        float var = q * (1.0f / D) - mu * mu;
        float rs  = rsqrtf(var + 1e-5f);
        float4 wv = *(const float4*)(w + lane * 4);
        float4 bv = *(const float4*)(bias + lane * 4);
        float4 o;
        o.x = (v.x - mu) * rs * wv.x + bv.x;
        o.y = (v.y - mu) * rs * wv.y + bv.y;
        o.z = (v.z - mu) * rs * wv.z + bv.z;
        o.w = (v.w - mu) * rs * wv.w + bv.w;
        uint2 pk;
        pk.x = pk2(o.x, o.y);
        pk.y = pk2(o.z, o.w);
        *(uint2*)(xnb + row * D + lane * 4) = pk;
    } else {
        int rid = id - B * S;
        int t = rid & (S - 1), b = rid >> 9;
        const float* row = adj + ((size_t)(b * S + t)) * S;
        float s = 0.0f; bool anyp = false;
        for (int i = lane; i < t; i += 64) { float v = row[i]; s += v; anyp |= (v > 0.0f); }
        for (int m = 1; m < 64; m <<= 1) s += __shfl_xor(s, m);
        bool any = __any(anyp);
        if (lane == 0) {
            rdeg[b * S + t] = 1.0f / fmaxf(s, 1.0f);
            if (t > 0 && any) atomicOr(flagI + t, 1);
        }
        if (t < 3) {   // zero xpb halo row t for batch b
            uint4 z = {0u, 0u, 0u, 0u};
            *(uint4*)(xpb + ((size_t)(b * (S + 3) + t)) * DI + lane * 8) = z;
        }
    }
}

// ------- bf16 MFMA GEMM, W in f32 (converted during staging) -------
template<int MODE>
__global__ __launch_bounds__(256) void gemmb_k(const ushort16* __restrict__ A,
                                               const float* __restrict__ W,
                                               const float* __restrict__ res,
                                               float* __restrict__ C,
                                               ushort16* __restrict__ xpb,
                                               float* __restrict__ zs,
                                               int M, int Nc, int K) {
    __shared__ __align__(16) short As[64 * 40];
    __shared__ __align__(16) short Ws[64 * 40];
    int tid = threadIdx.x;
    int l = tid & 63, wid = tid >> 6;
    int wm = wid & 1, wn = wid >> 1;
    int row0 = blockIdx.y * 64, col0 = blockIdx.x * 64;
    int r = tid >> 2, kseg = (tid & 3) * 8;
    f32x4 acc[2][2] = {};
    for (int k0 = 0; k0 < K; k0 += 32) {
        *(uint4*)&As[r * 40 + kseg] = *(const uint4*)(A + (size_t)(row0 + r) * K + k0 + kseg);
        {
            const float* wrow = W + (size_t)(col0 + r) * K + k0 + kseg;
            float4 w0 = *(const float4*)wrow;
            float4 w1 = *(const float4*)(wrow + 4);
            uint4 q;
            q.x = pk2(w0.x, w0.y); q.y = pk2(w0.z, w0.w);
            q.z = pk2(w1.x, w1.y); q.w = pk2(w1.z, w1.w);
            *(uint4*)&Ws[r * 40 + kseg] = q;
        }
        __syncthreads();
        bf16x8 aF[2], bF[2];
        #pragma unroll
        for (int am = 0; am < 2; ++am)
            aF[am] = *(const bf16x8*)&As[(wm * 32 + am * 16 + (l & 15)) * 40 + (l >> 4) * 8];
        #pragma unroll
        for (int bn = 0; bn < 2; ++bn)
            bF[bn] = *(const bf16x8*)&Ws[(wn * 32 + bn * 16 + (l & 15)) * 40 + (l >> 4) * 8];
        #pragma unroll
        for (int am = 0; am < 2; ++am)
            #pragma unroll
            for (int bn = 0; bn < 2; ++bn)
                acc[am][bn] = __builtin_amdgcn_mfma_f32_16x16x32_bf16(aF[am], bF[bn], acc[am][bn], 0, 0, 0);
        __syncthreads();
    }
    #pragma unroll
    for (int am = 0; am < 2; ++am)
        #pragma unroll
        for (int bn = 0; bn < 2; ++bn) {
            int cc = col0 + wn * 32 + bn * 16 + (l & 15);
            #pragma unroll
            for (int reg = 0; reg < 4; ++reg) {
                int rr = row0 + wm * 32 + am * 16 + (l >> 4) * 4 + reg;
                float v = acc[am][bn][reg];
                if (MODE == 0) {
                    if (res) v += res[(size_t)rr * Nc + cc];
                    C[(size_t)rr * Nc + cc] = v;
                } else {
                    int b = rr >> 9, t = rr & (S - 1);
                    if (cc < DI)
                        xpb[((size_t)(b * (S + 3) + 3 + t)) * DI + cc] = f2bf(v);
                    else
                        zs[((size_t)(b * S + t)) * DI + (cc - DI)] = v / (1.0f + __expf(-v));
                }
            }
        }
}

// ---------------- Causal conv via bf16 MFMA + bias + silu ----------------
__global__ __launch_bounds__(256) void convm_k(const ushort16* __restrict__ xpb,
                                               const float* __restrict__ conv_w,
                                               const float* __restrict__ conv_b,
                                               float* __restrict__ x_act) {
    __shared__ __align__(16) short AxS[35 * 40];
    __shared__ __align__(16) short WbS[4 * 32 * 40];
    int tid = threadIdx.x;
    int l = tid & 63, wid = tid >> 6;
    int wm = wid & 1, wn = wid >> 1;
    int o0 = blockIdx.x * 32;
    int mt = blockIdx.y;
    int b = mt >> 4, tl0 = (mt & 15) * 32;
    f32x4 acc = {0.f, 0.f, 0.f, 0.f};

    for (int k0 = 0; k0 < DI; k0 += 32) {
        if (tid < 140) {
            int rr = tid >> 2, seg = tid & 3;
            uint4 v = *(const uint4*)(xpb + ((size_t)(b * (S + 3) + tl0 + rr)) * DI + k0 + seg * 8);
            *(uint4*)&AxS[rr * 40 + seg * 8] = v;
        }
        #pragma unroll
        for (int it = 0; it < 4; ++it) {
            int p = it * 256 + tid;
            int o = p >> 5, i = p & 31;
            float4 w4 = *(const float4*)(conv_w + ((size_t)(o0 + o) * DI + (k0 + i)) * 4);
            WbS[(0 * 32 + o) * 40 + i] = (short)f2bf(w4.x);
            WbS[(1 * 32 + o) * 40 + i] = (short)f2bf(w4.y);
            WbS[(2 * 32 + o) * 40 + i] = (short)f2bf(w4.z);
            WbS[(3 * 32 + o) * 40 + i] = (short)f2bf(w4.w);
        }
        __syncthreads();
        #pragma unroll
        for (int k = 0; k < 4; ++k) {
            bf16x8 aF = *(const bf16x8*)&AxS[(wm * 16 + (l & 15) + k) * 40 + (l >> 4) * 8];
            bf16x8 bF = *(const bf16x8*)&WbS[(k * 32 + wn * 16 + (l & 15)) * 40 + (l >> 4) * 8];
            acc = __builtin_amdgcn_mfma_f32_16x16x32_bf16(aF, bF, acc, 0, 0, 0);
        }
        __syncthreads();
    }
    int oc = o0 + wn * 16 + (l & 15);
    float bia = conv_b[oc];
    #pragma unroll
    for (int reg = 0; reg < 4; ++reg) {
        int m = wm * 16 + (l >> 4) * 4 + reg;
        float v = acc[reg] + bia;
        x_act[((size_t)(b * S + tl0 + m)) * DI + oc] = v / (1.0f + __expf(-v));
    }
}

// ------- ssm (33 outputs) + E epilogue -------
__global__ void ssmE_k(const float* __restrict__ x_act, const float* __restrict__ W_xp,
                       const float* __restrict__ W_dt, const float* __restrict__ b_dt,
                       float* __restrict__ Bm, float* __restrict__ Cm,
                       float* __restrict__ E) {
    int row = blockIdx.x * 4 + (threadIdx.x >> 6);
    int lane = threadIdx.x & 63;
    const float* xr = x_act + (size_t)row * DI + lane * 8;
    float4 v0 = *(const float4*)xr;
    float4 v1 = *(const float4*)(xr + 4);
    float dtr = 0.0f;
    for (int j = 0; j < 2 * N + 1; ++j) {
        const float* wr = W_xp + (size_t)j * DI + lane * 8;
        float4 w0 = *(const float4*)wr;
        float4 w1 = *(const float4*)(wr + 4);
        float acc = v0.x * w0.x + v0.y * w0.y + v0.z * w0.z + v0.w * w0.w
                  + v1.x * w1.x + v1.y * w1.y + v1.z * w1.z + v1.w * w1.w;
        for (int m = 1; m < 64; m <<= 1) acc += __shfl_xor(acc, m);
        if (j == 0) dtr = acc;
        if (lane == 0) {
            if (j >= 1 && j < 1 + N) Bm[(size_t)row * N + (j - 1)] = acc;
            else if (j >= 1 + N)     Cm[(size_t)row * N + (j - 1 - N)] = acc;
        }
    }
    int d0 = lane * 8;
    float4 w0 = *(const float4*)(W_dt + d0);
    float4 w1 = *(const float4*)(W_dt + d0 + 4);
    float4 q0 = *(const float4*)(b_dt + d0);
    float4 q1 = *(const float4*)(b_dt + d0 + 4);
    float4 e0, e1;
    e0.x = 1.0f / (1.0f + __expf(dtr * w0.x + q0.x));
    e0.y = 1.0f / (1.0f + __expf(dtr * w0.y + q0.y));
    e0.z = 1.0f / (1.0f + __expf(dtr * w0.z + q0.z));
    e0.w = 1.0f / (1.0f + __expf(dtr * w0.w + q0.w));
    e1.x = 1.0f / (1.0f + __expf(dtr * w1.x + q1.x));
    e1.y = 1.0f / (1.0f + __expf(dtr * w1.y + q1.y));
    e1.z = 1.0f / (1.0f + __expf(dtr * w1.z + q1.z));
    e1.w = 1.0f / (1.0f + __expf(dtr * w1.w + q1.w));
    *(float4*)(E + (size_t)row * DI + d0) = e0;
    *(float4*)(E + (size_t)row * DI + d0 + 4) = e1;
}

// ================= quad-chunk fused kernel (256 threads, 256 blocks) =================
#define SCAN32(RO, ADJT, GSUM, EL, XAL, BNL, RDEGL, FLL)                    \
    _Pragma("unroll")                                                       \
    for (int j = 0; j < CHUNK; ++j) {                                       \
        float e  = (EL) [((RO) + j) * 8 + grp];                             \
        float xa = (XAL)[((RO) + j) * 8 + grp];                             \
        float Bn = (BNL)[((RO) + j) * 16 + n];                              \
        h = h * e + xa * Bn;                                                \
        float g0 = GSUM[j], g1 = 0.f, g2 = 0.f, g3 = 0.f;                   \
        const float* ar = (ADJT) + j * 36;                                  \
        int sp = 0;                                                         \
        _Pragma("unroll")                                                   \
        for (; sp + 4 <= j; sp += 4) {                                      \
            float4 av = *(const float4*)(ar + sp);                          \
            g0 += av.x * hreg[sp];     g1 += av.y * hreg[sp + 1];           \
            g2 += av.z * hreg[sp + 2]; g3 += av.w * hreg[sp + 3];           \
        }                                                                   \
        _Pragma("unroll")                                                   \
        for (; sp < j; ++sp) g0 += ar[sp] * hreg[sp];                       \
        float gr = (g0 + g1) + (g2 + g3);                                   \
        float m0 = gr * wrr[0] + rork<4>(gr) * wrr[4]                       \
                 + rork<8>(gr) * wrr[8] + rork<12>(gr) * wrr[12];           \
        float m1 = rork<1>(gr) * wrr[1] + rork<5>(gr) * wrr[5]              \
                 + rork<9>(gr) * wrr[9] + rork<13>(gr) * wrr[13];           \
        float m2 = rork<2>(gr) * wrr[2] + rork<6>(gr) * wrr[6]              \
                 + rork<10>(gr) * wrr[10] + rork<14>(gr) * wrr[14];         \
        float m3 = rork<3>(gr) * wrr[3] + rork<7>(gr) * wrr[7]              \
                 + rork<11>(gr) * wrr[11] + rork<15>(gr) * wrr[15];         \
        float acc = fmaf((RDEGL)[(RO) + j], (m0 + m1) + (m2 + m3), brn);    \
        if ((FLL)[(RO) + j])                                                \
            h = fmaf(0.1f * acc,                                            \
                     __builtin_amdgcn_rcpf(1.0f + __expf(-acc)), h);        \
        hreg[j] = h;                                                        \
    }

#define PRESUM(GSUM, PTR) {                                                 \
    const ushort16* _p = (PTR);                                             \
    _Pragma("unroll")                                                       \
    for (int qi = 0; qi < 4; ++qi) {                                        \
        uint4 q = *(const uint4*)(_p + qi * 8);                             \
        GSUM[qi*8+0] += bflo(q.x); GSUM[qi*8+1] += bfhi(q.x);               \
        GSUM[qi*8+2] += bflo(q.y); GSUM[qi*8+3] += bfhi(q.y);               \
        GSUM[qi*8+4] += bflo(q.z); GSUM[qi*8+5] += bfhi(q.z);               \
        GSUM[qi*8+6] += bflo(q.w); GSUM[qi*8+7] += bfhi(q.w);               \
    } }

// hist write (global tiled + LDS hT buffer)
#define HWRITE(CIDX, HTBUF) {                                               \
    ushort16* ht = histT + htIdx(b, dn, (CIDX));                            \
    _Pragma("unroll")                                                       \
    for (int qi = 0; qi < 4; ++qi) {                                        \
        uint4 q;                                                            \
        q.x = pk2(hreg[qi*8+0], hreg[qi*8+1]);                              \
        q.y = pk2(hreg[qi*8+2], hreg[qi*8+3]);                              \
        q.z = pk2(hreg[qi*8+4], hreg[qi*8+5]);                              \
        q.w = pk2(hreg[qi*8+6], hreg[qi*8+7]);                              \
        *(uint4*)(ht + qi * 8) = q;                                         \
        *(uint4*)&(HTBUF)[qi * 1024 + tid * 8] = q;                         \
    } }

// mid-source phase: (GM)[j][col] = sum_{sidx in [S0v,S1v)} adj(tgt TGT rows,
// src sidx cols) x hT[sidx].  Runs on any half-block (uses tid&127).
#define MIDSRC(TGT, S0v, S1v, GM) {                                         \
    int lt = tid & 127;                                                     \
    int w = lt >> 6, l = lt & 63;                                           \
    int ksg = (l >> 4) * 8;                                                 \
    f32x4 ac0[4] = {}, ac1[4] = {};                                         \
    _Pragma("unroll")                                                       \
    for (int sidx = (S0v); sidx < (S1v); ++sidx) {                          \
        const float* p0 = adj + ((size_t)(b * S + c0s + (TGT) * 32 + (l & 15))) * S \
                        + c0s + sidx * 32 + ksg;                            \
        const float* p1 = p0 + 16 * S;                                      \
        float4 a00 = *(const float4*)p0, a01 = *(const float4*)(p0 + 4);    \
        float4 a10 = *(const float4*)p1, a11 = *(const float4*)(p1 + 4);    \
        uint4 qa, qb;                                                       \
        qa.x = pk2(a00.x, a00.y); qa.y = pk2(a00.z, a00.w);                 \
        qa.z = pk2(a01.x, a01.y); qa.w = pk2(a01.z, a01.w);                 \
        qb.x = pk2(a10.x, a10.y); qb.y = pk2(a10.z, a10.w);                 \
        qb.z = pk2(a11.x, a11.y); qb.w = pk2(a11.z, a11.w);                 \
        bf16x8 aF0, aF1;                                                    \
        *(uint4*)&aF0 = qa; *(uint4*)&aF1 = qb;                             \
        const short* hTs = hTarr[sidx];                                     \
        _Pragma("unroll")                                                   \
        for (int dblk = 0; dblk < 4; ++dblk) {                              \
            int col = w * 64 + dblk * 16 + (l & 15);                        \
            bf16x8 bF = *(const bf16x8*)&hTs[(l >> 4) * 1024 + col * 8];    \
            ac0[dblk] = __builtin_amdgcn_mfma_f32_16x16x32_bf16(aF0, bF, ac0[dblk], 0, 0, 0); \
            ac1[dblk] = __builtin_amdgcn_mfma_f32_16x16x32_bf16(aF1, bF, ac1[dblk], 0, 0, 0); \
        }                                                                   \
    }                                                                       \
    int jb0 = (l >> 4) * 4;                                                 \
    _Pragma("unroll")                                                       \
    for (int dblk = 0; dblk < 4; ++dblk) {                                  \
        int col = w * 64 + dblk * 16 + (l & 15);                            \
        _Pragma("unroll")                                                   \
        for (int reg = 0; reg < 4; ++reg) {                                 \
            (GM)[(jb0 + reg) * 136 + col]      = (short)f2bf(ac0[dblk][reg]); \
            (GM)[(16 + jb0 + reg) * 136 + col] = (short)f2bf(ac1[dblk][reg]); \
        }                                                                   \
    } }

#define GSADD1(GSUM, GM)                                                    \
    _Pragma("unroll")                                                       \
    for (int j = 0; j < CHUNK; ++j)                                         \
        GSUM[j] += bf2f((ushort16)(GM)[j * 136 + tid]);

#define GSADD2(GSUM, GM1, GM2)                                              \
    _Pragma("unroll")                                                       \
    for (int j = 0; j < CHUNK; ++j)                                         \
        GSUM[j] += bf2f((ushort16)(GM1)[j * 136 + tid])                     \
                 + bf2f((ushort16)(GM2)[j * 136 + tid]);

// staging of one 2-chunk operand set by thread index T (0..255) at rows c0s+OFS
#define STAGEOPS(T, OFS, TRI0, TRI1, EL, XAL, BNL, RDEGL, FLL) {            \
    int j = (T) >> 3, s4 = ((T) & 7) * 4;                                   \
    {                                                                       \
        float4 a0 = *(const float4*)(adj + ((size_t)(b * S + c0s + (OFS) + j)) * S + c0s + (OFS) + s4); \
        float* dp = (TRI0) + j * 36 + s4;                                   \
        dp[0] = a0.x; dp[1] = a0.y; dp[2] = a0.z; dp[3] = a0.w;             \
    }                                                                       \
    {                                                                       \
        float4 a0 = *(const float4*)(adj + ((size_t)(b * S + c0s + (OFS) + 32 + j)) * S + c0s + (OFS) + 32 + s4); \
        float* dp = (TRI1) + j * 36 + s4;                                   \
        dp[0] = a0.x; dp[1] = a0.y; dp[2] = a0.z; dp[3] = a0.w;             \
    }                                                                       \
    int jr = (T) >> 2, dd = ((T) & 3) * 2;                                  \
    float2 ev = *(const float2*)(E     + ((size_t)(b * S + c0s + (OFS) + jr)) * DI + d0 + dd); \
    float2 xv = *(const float2*)(x_act + ((size_t)(b * S + c0s + (OFS) + jr)) * DI + d0 + dd); \
    (EL) [jr * 8 + dd] = ev.x; (EL) [jr * 8 + dd + 1] = ev.y;               \
    (XAL)[jr * 8 + dd] = xv.x; (XAL)[jr * 8 + dd + 1] = xv.y;               \
    int nn = ((T) & 3) * 4;                                                 \
    float4 bv = *(const float4*)(Bm + ((size_t)(b * S + c0s + (OFS) + jr)) * N + nn); \
    (BNL)[jr * 16 + nn] = bv.x; (BNL)[jr * 16 + nn + 1] = bv.y;             \
    (BNL)[jr * 16 + nn + 2] = bv.z; (BNL)[jr * 16 + nn + 3] = bv.w;         \
    if ((T) < 64) {                                                         \
        (RDEGL)[(T)] = rdeg[b * S + c0s + (OFS) + (T)];                     \
        (FLL)[(T)]   = flagI[c0s + (OFS) + (T)];                            \
    } }

__global__ __launch_bounds__(256) void chunk4_k(const float* __restrict__ adj,
                                                const float* __restrict__ x_act,
                                                const float* __restrict__ E,
                                                const float* __restrict__ Bm,
                                                const float* __restrict__ rdeg,
                                                const int* __restrict__ flagI,
                                                const float* __restrict__ Wr,
                                                const float* __restrict__ br,
                                                ushort16* __restrict__ Gall,
                                                ushort16* __restrict__ histT,
                                                float* __restrict__ hlast, int lc) {
    __shared__ __align__(16) char smem[94720];
    int tid = threadIdx.x;
    int c0 = 4 * lc;
    int c0s = c0 * CHUNK;
    const size_t SLOT = (size_t)B * DN * 32;
    int rp = lc & 1, wp = (lc + 1) & 1;

    if (blockIdx.x < 128) {
        // ---------------- scan role ----------------
        float* triA   = (float*)smem;                  // set1
        float* triB   = (float*)(smem + 4608);
        float* eLa    = (float*)(smem + 9216);
        float* xaLa   = (float*)(smem + 11264);
        float* BnLa   = (float*)(smem + 13312);
        float* rdegLa = (float*)(smem + 17408);
        int*   flLa   = (int*)  (smem + 17664);
        float* triC   = (float*)(smem + 17920);        // set2
        float* triD   = (float*)(smem + 22528);
        float* eLb    = (float*)(smem + 27136);
        float* xaLb   = (float*)(smem + 29184);
        float* BnLb   = (float*)(smem + 31232);
        float* rdegLb = (float*)(smem + 35328);
        int*   flLb   = (int*)  (smem + 35584);
        short* hTA    = (short*)(smem + 35840);
        short* hTB    = (short*)(smem + 44032);
        short* hTC    = (short*)(smem + 52224);
        short* hTD    = (short*)(smem + 60416);
        short* GmidB  = (short*)(smem + 68608);        // rotating exposed-mid buffer
        short* GmidC  = (short*)(smem + 77312);        // hidden C<-A
        short* GmidD  = (short*)(smem + 86016);        // hidden D<-{A,B}

        int b = blockIdx.x >> 6;
        int d0 = (blockIdx.x & 63) << 3;
        int n = tid & 15, grp = (tid >> 4) & 7;
        int d = d0 + grp;
        int dn = d * N + n;
        int dnbase = (blockIdx.x & 63) << 7;
        const short* hTarr[4] = {hTA, hTB, hTC, hTD};

        // ---- P1: stage set1 (A,B) by all 256 ----
        STAGEOPS(tid, 0, triA, triB, eLa, xaLa, BnLa, rdegLa, flLa)
        __syncthreads();

        float gs0[CHUNK], gs1[CHUNK];
        float wrr[16];
        float brn = 0.f, h = 0.f;
        float hreg[CHUNK];

        // ---- P2: scan A (tid<128)  ||  stage set2 (tid>=128) ----
        if (tid < 128) {
            #pragma unroll
            for (int j = 0; j < CHUNK; ++j) { gs0[j] = 0.f; gs1[j] = 0.f; }
            size_t tb = ((size_t)b * DN + dn) * 32;
            if (lc >= 2) {
                PRESUM(gs0, Gall + ((size_t)rp * NSLOT + 0) * SLOT + tb);
                PRESUM(gs1, Gall + ((size_t)rp * NSLOT + 1) * SLOT + tb);
            }
            if (lc >= 1) {
                PRESUM(gs0, Gall + ((size_t)rp * NSLOT + 4) * SLOT + tb);
                PRESUM(gs1, Gall + ((size_t)rp * NSLOT + 5) * SLOT + tb);
            }
            int probe = __builtin_amdgcn_mov_dpp((int)n, 0x121, 0xf, 0xf, false);
            bool plusdir = (probe == ((n + 1) & 15));
            #pragma unroll
            for (int k = 0; k < 16; ++k) {
                int ip = (n + k) & 15, im = (n - k + 16) & 15;
                wrr[k] = Wr[n * 16 + (plusdir ? ip : im)];
            }
            brn = br[n];
            h = (lc == 0) ? 0.0f : hlast[b * DN + dn];

            SCAN32(0, triA, gs0, eLa, xaLa, BnLa, rdegLa, flLa)   // chunk A
            HWRITE(c0 + 0, hTA)
        } else {
            #pragma unroll
            for (int rep = 0; rep < 2; ++rep) {
                int t2 = ((tid - 128) << 1) | rep;
                STAGEOPS(t2, 64, triC, triD, eLb, xaLb, BnLb, rdegLb, flLb)
            }
        }
        __syncthreads();

        // ---- P3: B<-A (exposed, waves 0-1) ----
        if (tid < 128) MIDSRC(1, 0, 1, GmidB)
        __syncthreads();

        // ---- P4: scan B (waves 0-1)  ||  C<-A hidden (waves 2-3) ----
        if (tid < 128) {
            GSADD1(gs1, GmidB)
            SCAN32(32, triB, gs1, eLa, xaLa, BnLa, rdegLa, flLa)  // chunk B
            HWRITE(c0 + 1, hTB)
        } else {
            MIDSRC(2, 0, 1, GmidC)
        }
        __syncthreads();

        // ---- P5: presum C/D + C<-B (waves 0-1)  ||  D<-{A,B} hidden (waves 2-3) ----
        if (tid < 128) {
            #pragma unroll
            for (int j = 0; j < CHUNK; ++j) { gs0[j] = 0.f; gs1[j] = 0.f; }
            size_t tb = ((size_t)b * DN + dn) * 32;
            if (lc >= 2) {
                PRESUM(gs0, Gall + ((size_t)rp * NSLOT + 2) * SLOT + tb);
                PRESUM(gs1, Gall + ((size_t)rp * NSLOT + 3) * SLOT + tb);
            }
            if (lc >= 1) {
                PRESUM(gs0, Gall + ((size_t)rp * NSLOT + 6) * SLOT + tb);
                PRESUM(gs1, Gall + ((size_t)rp * NSLOT + 7) * SLOT + tb);
            }
            MIDSRC(2, 1, 2, GmidB)        // C<-B
        } else {
            MIDSRC(3, 0, 2, GmidD)        // D<-{A,B}
        }
        __syncthreads();

        // ---- P6: scan C ----
        if (tid < 128) {
            GSADD2(gs0, GmidC, GmidB)
            SCAN32(0, triC, gs0, eLb, xaLb, BnLb, rdegLb, flLb)   // chunk C
            HWRITE(c0 + 2, hTC)
        }
        __syncthreads();

        // ---- P7: D<-C (exposed) ----
        if (tid < 128) MIDSRC(3, 2, 3, GmidB)
        __syncthreads();

        // ---- P8: scan D ----
        if (tid < 128) {
            GSADD2(gs1, GmidD, GmidB)
            SCAN32(32, triD, gs1, eLb, xaLb, BnLb, rdegLb, flLb)  // chunk D
            HWRITE(c0 + 3, hTD)
            hlast[b * DN + dn] = h;
        }
        __syncthreads();

        // ---- tails: accumulated over src -> 4 slots (all 256 threads) ----
        if (lc < NL2 - 1) {
            int half = tid >> 7;
            int lt = tid & 127;
            int w = lt >> 6, l = lt & 63;
            int ksg = (l >> 4) * 8;
            int jb0 = (l >> 4) * 4;
            #pragma unroll
            for (int tp = 0; tp < 2; ++tp) {
                int tgt = half * 2 + tp;
                f32x4 ac0[4] = {}, ac1[4] = {};
                #pragma unroll
                for (int src = 0; src < 4; ++src) {
                    const short* hTs = hTarr[src];
                    const float* p0 = adj + ((size_t)(b * S + (4 * (lc + 1) + tgt) * 32 + (l & 15))) * S
                                    + (4 * lc + src) * 32 + ksg;
                    const float* p1 = p0 + 16 * S;
                    float4 a00 = *(const float4*)p0, a01 = *(const float4*)(p0 + 4);
                    float4 a10 = *(const float4*)p1, a11 = *(const float4*)(p1 + 4);
                    uint4 qa, qb;
                    qa.x = pk2(a00.x, a00.y); qa.y = pk2(a00.z, a00.w);
                    qa.z = pk2(a01.x, a01.y); qa.w = pk2(a01.z, a01.w);
                    qb.x = pk2(a10.x, a10.y); qb.y = pk2(a10.z, a10.w);
                    qb.z = pk2(a11.x, a11.y); qb.w = pk2(a11.z, a11.w);
                    bf16x8 aF0, aF1;
                    *(uint4*)&aF0 = qa; *(uint4*)&aF1 = qb;
                    #pragma unroll
                    for (int dblk = 0; dblk < 4; ++dblk) {
                        int col = w * 64 + dblk * 16 + (l & 15);
                        bf16x8 bF = *(const bf16x8*)&hTs[(l >> 4) * 1024 + col * 8];
                        ac0[dblk] = __builtin_amdgcn_mfma_f32_16x16x32_bf16(aF0, bF, ac0[dblk], 0, 0, 0);
                        ac1[dblk] = __builtin_amdgcn_mfma_f32_16x16x32_bf16(aF1, bF, ac1[dblk], 0, 0, 0);
                    }
                }
                ushort16* gw = Gall + ((size_t)wp * NSLOT + (4 + tgt)) * SLOT;
                #pragma unroll
                for (int dblk = 0; dblk < 4; ++dblk) {
                    int col = w * 64 + dblk * 16 + (l & 15);
                    int dng = dnbase + col;
                    uint2 o0, o1;
                    o0.x = pk2(ac0[dblk][0], ac0[dblk][1]); o0.y = pk2(ac0[dblk][2], ac0[dblk][3]);
                    o1.x = pk2(ac1[dblk][0], ac1[dblk][1]); o1.y = pk2(ac1[dblk][2], ac1[dblk][3]);
                    *(uint2*)(gw + ((size_t)b * DN + dng) * 32 + jb0) = o0;
                    *(uint2*)(gw + ((size_t)b * DN + dng) * 32 + 16 + jb0) = o1;
                }
            }
        }
    } else {
        // -------- gpast role: 4 targets per block, histT read ONCE per fragment --------
        if (lc == 0 || lc >= NL2 - 1) return;
        int idx = blockIdx.x - 128;                // 0..127
        int tile = idx & 63;
        int b = idx >> 6;
        int dn0 = tile * 128;
        int w = tid >> 6, l = tid & 63;
        int jh = w & 1, dh = w >> 1;
        int ksg = (l >> 4) * 8;
        int dnrow = dn0 + dh * 64 + (l & 15);
        int K = 4 * lc;
        const float* abase0 = adj + ((size_t)(b * S + (4 * (lc + 1) + 0) * CHUNK + jh * 16 + (l & 15))) * S + ksg;
        const float* abase1 = abase0 + (size_t)CHUNK * S;
        const float* abase2 = abase1 + (size_t)CHUNK * S;
        const float* abase3 = abase2 + (size_t)CHUNK * S;
        f32x4 acc[4][4] = {};
        #pragma unroll 1
        for (int ks = 0; ks < K; ++ks) {
            bf16x8 bF[4];
            #pragma unroll
            for (int dblk = 0; dblk < 4; ++dblk) {
                uint4 bP = *(const uint4*)(histT + htIdx(b, dnrow + dblk * 16, ks) + ksg);
                *(uint4*)&bF[dblk] = bP;
            }
            #pragma unroll
            for (int tgt = 0; tgt < 4; ++tgt) {
                const float* ab = (tgt == 0) ? abase0 : (tgt == 1) ? abase1
                                : (tgt == 2) ? abase2 : abase3;
                float4 af0 = *(const float4*)(ab + ks * 32);
                float4 af1 = *(const float4*)(ab + ks * 32 + 4);
                uint4 aP;
                aP.x = pk2(af0.x, af0.y); aP.y = pk2(af0.z, af0.w);
                aP.z = pk2(af1.x, af1.y); aP.w = pk2(af1.z, af1.w);
                bf16x8 aF;
                *(uint4*)&aF = aP;
                #pragma unroll
                for (int dblk = 0; dblk < 4; ++dblk)
                    acc[tgt][dblk] = __builtin_amdgcn_mfma_f32_16x16x32_bf16(aF, bF[dblk], acc[tgt][dblk], 0, 0, 0);
            }
        }
        int jb = jh * 16 + (l >> 4) * 4;
        #pragma unroll
        for (int tgt = 0; tgt < 4; ++tgt) {
            ushort16* gbase = Gall + ((size_t)wp * NSLOT + tgt) * SLOT;
            #pragma unroll
            for (int dblk = 0; dblk < 4; ++dblk) {
                int dnc = dn0 + dh * 64 + dblk * 16 + (l & 15);
                uint2 o;
                o.x = pk2(acc[tgt][dblk][0], acc[tgt][dblk][1]);
                o.y = pk2(acc[tgt][dblk][2], acc[tgt][dblk][3]);
                *(uint2*)(gbase + ((size_t)b * DN + dnc) * 32 + jb) = o;
            }
        }
    }
}

// ---------------- y_k: y[b,t,d] = (sum_n histT[b][dn][t]*Cm[b,t,n]) * zs[b,t,d] -------
__global__ __launch_bounds__(256) void y_k(const ushort16* __restrict__ histT,
                                           const float* __restrict__ Cm,
                                           const float* __restrict__ zs,
                                           ushort16* __restrict__ yzb) {
    __shared__ float CmL[S * 17];
    int b = blockIdx.x >> 9;
    int d = blockIdx.x & (DI - 1);
    int tid = threadIdx.x;
    #pragma unroll
    for (int q = 0; q < 8; ++q) {
        int l0 = q * 1024 + tid * 4;
        int t = l0 >> 4, n0 = l0 & 15;
        float4 v = *(const float4*)(Cm + (size_t)b * S * N + l0);
        CmL[t * 17 + n0]     = v.x;
        CmL[t * 17 + n0 + 1] = v.y;
        CmL[t * 17 + n0 + 2] = v.z;
        CmL[t * 17 + n0 + 3] = v.w;
    }
    __syncthreads();
    #pragma unroll
    for (int pass = 0; pass < 2; ++pass) {
        int t = pass * 256 + tid;
        int sb = t >> 5, si = t & 31;
        const ushort16* hb = histT + htIdx(b, d * N, sb) + si;
        float a0 = 0.f, a1 = 0.f, a2 = 0.f, a3 = 0.f;
        #pragma unroll
        for (int n = 0; n < 16; n += 4) {
            a0 += bf2f(hb[(size_t)n * 32])       * CmL[t * 17 + n];
            a1 += bf2f(hb[(size_t)(n + 1) * 32]) * CmL[t * 17 + n + 1];
            a2 += bf2f(hb[(size_t)(n + 2) * 32]) * CmL[t * 17 + n + 2];
            a3 += bf2f(hb[(size_t)(n + 3) * 32]) * CmL[t * 17 + n + 3];
        }
        float acc = (a0 + a1) + (a2 + a3);
        float zv = zs[((size_t)(b * S + t)) * DI + d];
        yzb[((size_t)(b * S + t)) * DI + d] = f2bf(acc * zv);
    }
}

// ---------------- launch ----------------
extern "C" void kernel_launch(void* const* d_in, const int* in_sizes, int n_in,
                              void* d_out, int out_size, void* d_ws, size_t ws_size,
                              hipStream_t stream) {
    const float* x      = (const float*)d_in[0];
    const float* adj    = (const float*)d_in[1];
    const float* ln_w   = (const float*)d_in[2];
    const float* ln_b   = (const float*)d_in[3];
    const float* W_in   = (const float*)d_in[4];
    const float* conv_w = (const float*)d_in[5];
    const float* conv_b = (const float*)d_in[6];
    const float* W_xp   = (const float*)d_in[7];
    const float* W_dt   = (const float*)d_in[8];
    const float* b_dt   = (const float*)d_in[9];
    const float* Wr     = (const float*)d_in[10];
    const float* br     = (const float*)d_in[11];
    const float* W_out  = (const float*)d_in[12];
    float* out = (float*)d_out;

    float* ws = (float*)d_ws;
    size_t off = 0;
    float* x_act  = ws + off; off += (size_t)B * S * DI;
    float* Bmb    = ws + off; off += (size_t)B * S * N;
    float* Cmb    = ws + off; off += (size_t)B * S * N;
    float* rdegp  = ws + off; off += (size_t)B * S;
    int*   flagI  = (int*)(ws + off); off += S;
    float* Ebuf   = ws + off; off += (size_t)B * S * DI;
    float* zsbuf  = ws + off; off += (size_t)B * S * DI;
    float* hlast  = ws + off; off += (size_t)B * DN;
    ushort16* xnb    = (ushort16*)(ws + off); off += (size_t)B * S * D / 2;
    ushort16* yzb    = (ushort16*)(ws + off); off += (size_t)B * S * DI / 2;
    ushort16* histT  = (ushort16*)(ws + off); off += (size_t)B * DN * S / 2;
    ushort16* Gall   = (ushort16*)(ws + off); off += (size_t)2 * NSLOT * B * DN * 32 / 2;
    ushort16* xpb    = (ushort16*)(ws + off); off += (size_t)B * (S + 3) * DI / 2;

    hipMemsetAsync(flagI, 0, S * sizeof(int), stream);

    lndeg_k<<<2 * B * S, 64, 0, stream>>>(x, ln_w, ln_b, xnb, adj, rdegp, flagI, xpb);
    gemmb_k<1><<<dim3(2 * DI / 64, B * S / 64), 256, 0, stream>>>(
        xnb, W_in, nullptr, nullptr, xpb, zsbuf, B * S, 2 * DI, D);
    convm_k<<<dim3(DI / 32, B * S / 32), 256, 0, stream>>>(xpb, conv_w, conv_b, x_act);
    ssmE_k<<<B * S / 4, 256, 0, stream>>>(x_act, W_xp, W_dt, b_dt, Bmb, Cmb, Ebuf);

    for (int lc = 0; lc < NL2; ++lc)
        chunk4_k<<<256, 256, 0, stream>>>(adj, x_act, Ebuf, Bmb, rdegp, flagI,
                                          Wr, br, Gall, histT, hlast, lc);

    y_k<<<B * DI, 256, 0, stream>>>(histT, Cmb, zsbuf, yzb);

    gemmb_k<0><<<dim3(D / 64, B * S / 64), 256, 0, stream>>>(
        yzb, W_out, x, out, nullptr, nullptr, B * S, D, DI);
}